// Round 4
// baseline (1415.146 us; speedup 1.0000x reference)
//
#include <hip/hip_runtime.h>
#include <hip/hip_bf16.h>
#include <math.h>

typedef __hip_bfloat16 bf16;
typedef __bf16 bfv8 __attribute__((ext_vector_type(8)));
typedef float fv4 __attribute__((ext_vector_type(4)));

__device__ __forceinline__ float bff(const bf16 x){ return __bfloat162float(x); }
__device__ __forceinline__ float gelu_f(float v){
    return 0.5f * v * (1.f + erff(v * 0.70710678118654752f));
}
__device__ __forceinline__ float silu_f(float v){
    return v / (1.f + expf(-v));
}
// dtype-agnostic input read: f32 ? fp32 : bf16
__device__ __forceinline__ float rdf(const void* p, size_t i, bool f32){
    return f32 ? ((const float*)p)[i] : __bfloat162float(((const bf16*)p)[i]);
}
__device__ __forceinline__ unsigned int packbf2(float a, float b){
    __hip_bfloat162 v;
    v.x = __float2bfloat16(a);
    v.y = __float2bfloat16(b);
    return *reinterpret_cast<unsigned int*>(&v);
}
__device__ __forceinline__ float2 unpackbf2(unsigned int u){
    __hip_bfloat162 v = *reinterpret_cast<__hip_bfloat162*>(&u);
    return make_float2(__bfloat162float(v.x), __bfloat162float(v.y));
}
__device__ __forceinline__ float us2f(unsigned short u){
    unsigned int x = ((unsigned int)u) << 16;
    return __uint_as_float(x);
}
__device__ __forceinline__ unsigned short f2us(float f){
    bf16 v = __float2bfloat16(f);
    return *reinterpret_cast<unsigned short*>(&v);
}

// Geometry
// B=256, C=64, H=W=34 (padded), modes: ky in {0..11, 22..33} (24), kx in 0..11 (12)
// h layout (ws, bf16): [b][c][y][x], stride c = 1156, stride b = 73984
// hft layout: [cg<16][b<256][m<288][8 bf16] ; kappa = cg*8+u, u<4: Re(c=cg*4+u),
//             u>=4: Im(c=cg*4+u-4).  Writer (k_fwd) fully coalesced per block.
// mixed layout: [b<256][m<288][o<64] packed bf16x2 dwords (r,i); writer (k_mixm)
//             owns full 256B rows per (b,m).
// tabs: [0,1632) Wfy f32 | [1632,2448) Wfx f32 |
//       [2448,3536) invBT bf16 image (68x16 dw) | [3536,4624) invW2 bf16 image (34x32 dw)
// invBT/invW2 are fragment-ready: k_invm reads MFMA fragments DIRECTLY from them
// (rows 32/64-u16 stride, kappa pads pre-zeroed; OOB rows discarded by predicates).

// ---------------- dtype probe ----------------
__global__ __launch_bounds__(256) void k_probe(const void* x, float* flag){
    __shared__ int wild;
    int t = threadIdx.x;
    if (t == 0) wild = 0;
    __syncthreads();
    const bf16* xb = (const bf16*)x;
    for (int i = t; i < 1024; i += 256){
        float v = bff(xb[i]);
        if (!(fabsf(v) < 1e10f)) wild = 1;
    }
    __syncthreads();
    if (t == 0) flag[0] = wild ? 1.f : 0.f;
}

// ---------------- tables ----------------
__global__ __launch_bounds__(256) void k_tables(float* tabs){
    int t = threadIdx.x;
    float* Wfy = tabs;          // 24*34*2
    float* Wfx = tabs + 1632;   // 12*34*2
    unsigned int* gBT = (unsigned int*)(tabs + 2448);   // [n<68][kd<16] bf16x2
    unsigned int* gW2 = (unsigned int*)(tabs + 3536);   // [y<34][kd<32] bf16x2
    const float TWO_PI = 6.283185307179586f;
    for (int e = t; e < 24*34; e += 256){
        int kyi = e / 34, y = e % 34;
        int ky = (kyi < 12) ? kyi : kyi + 10;
        int ph = (ky * y) % 34;
        float ang = TWO_PI * (float)ph / 34.0f;
        float s, c;
        sincosf(ang, &s, &c);
        Wfy[e*2]   = c;   Wfy[e*2+1] = -s;           // e^{-i ang}
    }
    for (int e = t; e < 12*34; e += 256){
        int kx = e / 34, x = e % 34;
        int ph = (kx * x) % 34;
        float ang = TWO_PI * (float)ph / 34.0f;
        float s, c;
        sincosf(ang, &s, &c);
        Wfx[e*2] = c; Wfx[e*2+1] = -s;               // e^{-i ang}
    }
    // invBT image: n=2x+ri (x<34), k=2kx+ri2; v = ri==0 ? (ri2==0? C : -S) : (ri2==0? S : C)
    // where C = ck*cos(ang), S = ck*sin(ang), ang = +2pi*(kx*x mod 34)/34, ck = (kx==0?1:2)
    for (int i = t; i < 1088; i += 256){
        int n = i >> 4, kd = i & 15;
        int x = n >> 1, ri = n & 1;
        int kx = kd;
        float v0 = 0.f, v1 = 0.f;
        if (kx < 12){
            int ph = (kx * x) % 34;
            float ang = TWO_PI * (float)ph / 34.0f;
            float s, c;
            sincosf(ang, &s, &c);
            float ck = (kx == 0) ? 1.0f : 2.0f;
            float C = ck * c, S = ck * s;
            v0 = (ri == 0) ? C : S;       // ri2 = 0
            v1 = (ri == 0) ? -S : C;      // ri2 = 1
        }
        gBT[i] = packbf2(v0, v1);
    }
    // invW2 image: y<34, k=2kyi+ri; v = (1/1156)*(ri==0? cos : -sin), ang=+2pi*(ky*y mod 34)/34
    for (int i = t; i < 1088; i += 256){
        int y = i >> 5, kd = i & 31;
        int kyi = kd;
        float v0 = 0.f, v1 = 0.f;
        if (kyi < 24){
            int ky = (kyi < 12) ? kyi : kyi + 10;
            int ph = (ky * y) % 34;
            float ang = TWO_PI * (float)ph / 34.0f;
            float s, c;
            sincosf(ang, &s, &c);
            v0 = c * (1.0f/1156.0f);
            v1 = -s * (1.0f/1156.0f);
        }
        gW2[i] = packbf2(v0, v1);
    }
}

// ---------------- fc0 as MFMA GEMM: concat(x,grid) @ fc0_w + b ---------------
// grid 1024: B -> b = (B>>5)*8 + (B&7), q = (B>>3)&3  (4 quarters of b co-XCD)
// Block: px in [q*256, q*256+256) (input px = y*32+x); C[256px][64c], K=42 pad 64.
// Single-writer: block owns y-range [q*8,q*8+8) of all 64 c-planes of slab b
// (+ pads), packed dword stores -> full lines within one L2.
__global__ __launch_bounds__(256) void k_fc0(const void* __restrict__ xin,
                                             const void* __restrict__ grd,
                                             const void* __restrict__ w,
                                             const void* __restrict__ bias,
                                             bf16* __restrict__ h,
                                             const float* __restrict__ flg){
    __shared__ unsigned short sA[256*72];   // A[px][k], stride 72 u16 (2-way banks)
    __shared__ unsigned short sBT[64*72];   // BT[c][k], stride 72
    __shared__ float sb[64];
    const bool f32 = (flg[0] > 0.5f);
    int B = blockIdx.x;
    int b = (B >> 5)*8 + (B & 7);
    int q = (B >> 3) & 3;
    int t = threadIdx.x;
    unsigned int* hw = (unsigned int*)(h + (size_t)b*73984);
    // pads: x=32,33 for this quarter's y-rows; q==3 also zeroes rows y=32,33
    for (int i = t; i < 512; i += 256){
        int c = i >> 3, y = q*8 + (i & 7);
        hw[(c*1156 + y*34 + 32) >> 1] = 0;
    }
    if (q == 3){
        for (int i = t; i < 2176; i += 256){
            int c = i / 34, d = i - c*34;
            hw[((c*1156 + 1088) >> 1) + d] = 0;
        }
    }
    // stage BT[c][k]: w is [k=42][c=64]; k 42..63 zero
    for (int i = t; i < 4096; i += 256){
        int k = i >> 6, c = i & 63;
        sBT[c*72 + k] = f2us((k < 42) ? rdf(w, (size_t)k*64 + c, f32) : 0.f);
    }
    if (t < 64) sb[t] = rdf(bias, t, f32);
    // stage A: x rows (k<40), grid (k 40,41), zero k 42..63
    size_t xbase = ((size_t)b*1024 + q*256)*40;
    for (int i = t; i < 10240; i += 256){
        int p = i / 40, k = i - p*40;
        sA[p*72 + k] = f2us(rdf(xin, xbase + i, f32));
    }
    size_t gbase = ((size_t)b*1024 + q*256)*2;
    for (int i = t; i < 512; i += 256)
        sA[(i >> 1)*72 + 40 + (i & 1)] = f2us(rdf(grd, gbase + i, f32));
    for (int i = t; i < 5632; i += 256){
        int p = i / 22, k = 42 + (i - p*22);
        sA[p*72 + k] = 0;
    }
    __syncthreads();
    int ln = t & 15, qd = (t & 63) >> 4, wv = t >> 6;
    // B fragments hoisted: 4 n-tiles x 2 k-slices
    bfv8 bfr[4][2];
    #pragma unroll
    for (int nt = 0; nt < 4; ++nt)
        #pragma unroll
        for (int ks = 0; ks < 2; ++ks)
            bfr[nt][ks] = *reinterpret_cast<const bfv8*>(&sBT[(nt*16 + ln)*72 + ks*32 + qd*8]);
    // 16 m-tiles, 4 per wave
    #pragma unroll
    for (int mi = 0; mi < 4; ++mi){
        int mt = wv*4 + mi;
        bfv8 a0 = *reinterpret_cast<const bfv8*>(&sA[(mt*16 + ln)*72 + qd*8]);
        bfv8 a1 = *reinterpret_cast<const bfv8*>(&sA[(mt*16 + ln)*72 + 32 + qd*8]);
        #pragma unroll
        for (int nt = 0; nt < 4; ++nt){
            fv4 acc = (fv4){0.f,0.f,0.f,0.f};
            acc = __builtin_amdgcn_mfma_f32_16x16x32_bf16(a0, bfr[nt][0], acc, 0, 0, 0);
            acc = __builtin_amdgcn_mfma_f32_16x16x32_bf16(a1, bfr[nt][1], acc, 0, 0, 0);
            int c = nt*16 + ln;
            float bb = sb[c];
            int px0 = q*256 + mt*16 + qd*4;      // 4 consecutive px, same y
            int y = px0 >> 5, x = px0 & 31;
            int didx = (c*1156 + y*34 + x) >> 1; // even -> dword aligned
            hw[didx]     = packbf2(acc[0] + bb, acc[1] + bb);
            hw[didx + 1] = packbf2(acc[2] + bb, acc[3] + bb);
        }
    }
}

// ---------------- forward truncated DFT via MFMA, 4 channels per block -------
// grid 4096 = 256 b x 16 ch-groups; writes hft [cg][b][m][8bf16] (coalesced)
// F1 (x-DFT): C1[(c,y)][2kx+s] = sum_x h[c][y][x] * Wfx(s? ci : cr)  (K=64, x pad)
// F2 (y-DFT): C2[(c,kx)][2ky+s] = sum_{2y+p} Gx * B2-image             (K=96, pad)
// B2[2y+p][2ky+s]: (s,p)=(0,0)Wr (0,1)-Wi (1,0)Wi (1,1)Wr, W = e^{-i 2pi ky y/34}
__global__ __launch_bounds__(256) void k_fwd(const bf16* __restrict__ h,
                                             unsigned int* __restrict__ hft,
                                             const float* __restrict__ tabs){
    __shared__ unsigned short lds[22656];   // 45,312 B
    unsigned short* sA1 = lds;              // 144 rows x 72 (rows=(c*34+y), k=x pad 64)
    unsigned short* sB1 = lds + 10368;      // 32 x 72 (rows=2kx+s, k=x)
    unsigned short* sA2 = lds + 12672;      // 48 x 104 (rows=(c*12+kx), kappa=2y+p pad 96)
    unsigned short* sB2 = lds + 17664;      // 48 x 104 (rows=2ky+s)
    unsigned int* sA1w = (unsigned int*)sA1;
    unsigned int* sA2w = (unsigned int*)sA2;
    int blk = blockIdx.x;
    int b = blk >> 4, c0 = (blk & 15) * 4;
    int t = threadIdx.x;
    // stage h (4 planes) into sA1 rows (c*34+y), dword granularity (coalesced)
    const unsigned int* srcp = (const unsigned int*)(h + (size_t)b*73984 + (size_t)c0*1156);
    for (int i = t; i < 2312; i += 256){
        int c = i / 578; int rem = i - c*578;
        int y = rem / 17; int d = rem - y*17;
        sA1w[(c*34 + y)*36 + d] = srcp[i];
    }
    // zero x-pad dwords 17..31 of rows 0..135
    for (int i = t; i < 2040; i += 256){
        int r = i / 15, d = i - r*15;
        sA1w[r*36 + 17 + d] = 0;
    }
    // zero tail rows 136..143 entirely
    for (int i = t; i < 288; i += 256){
        int r = 136 + i / 36, d = i - (i/36)*36;
        sA1w[r*36 + d] = 0;
    }
    // build B1 image from Wfx floats: row=2kx+s (24, pad 32), k=x (34, pad 72)
    for (int i = t; i < 2304; i += 256){
        int row = i / 72, k = i - row*72;
        float v = 0.f;
        if (row < 24 && k < 34){
            int kx = row >> 1, s = row & 1;
            v = tabs[1632 + (kx*34 + k)*2 + s];
        }
        sB1[i] = f2us(v);
    }
    // build B2 image from Wfy floats: row=2ky+s (48), kappa=2y+p (68, pad 104)
    for (int i = t; i < 4992; i += 256){
        int row = i / 104, kk = i - row*104;
        float v = 0.f;
        if (kk < 68){
            int ky = row >> 1, s = row & 1;
            int y = kk >> 1, p = kk & 1;
            float wr = tabs[(ky*34 + y)*2];
            float wi = tabs[(ky*34 + y)*2 + 1];
            v = (s == 0) ? ((p == 0) ? wr : -wi) : ((p == 0) ? wi : wr);
        }
        sB2[i] = f2us(v);
    }
    // zero sA2 kappa pad [68,96) = dwords 34..47 of each row
    for (int i = t; i < 672; i += 256){
        int r = i / 14, d = i - r*14;
        sA2w[r*52 + 34 + d] = 0;
    }
    __syncthreads();
    int ln = t & 15, qd = (t & 63) >> 4, wv = t >> 6;
    // ---- F1: 9 M-tiles x 2 N-tiles, K=64; wave owns one nt (static frag idx) ----
    {
        int ntw = wv & 1;
        bfv8 b1f[2];
        #pragma unroll
        for (int ks = 0; ks < 2; ++ks)
            b1f[ks] = *reinterpret_cast<const bfv8*>(&sB1[(ntw*16 + ln)*72 + ks*32 + qd*8]);
        int col = ntw*16 + ln;
        int kx = col >> 1, s = col & 1;
        for (int mt = (wv >> 1); mt < 9; mt += 2){
            fv4 acc = (fv4){0.f,0.f,0.f,0.f};
            #pragma unroll
            for (int ks = 0; ks < 2; ++ks){
                bfv8 a = *reinterpret_cast<const bfv8*>(&sA1[(mt*16 + ln)*72 + ks*32 + qd*8]);
                acc = __builtin_amdgcn_mfma_f32_16x16x32_bf16(a, b1f[ks], acc, 0, 0, 0);
            }
            if (col < 24){
                #pragma unroll
                for (int rr = 0; rr < 4; ++rr){
                    int r = mt*16 + qd*4 + rr;
                    if (r < 136){
                        int c = r / 34, y = r - c*34;
                        sA2[(c*12 + kx)*104 + 2*y + s] = f2us(acc[rr]);
                    }
                }
            }
        }
    }
    __syncthreads();
    // ---- F2: 3 M-tiles x 3 N-tiles, K=96; scatter into sC (reuse sA1) ----
    unsigned short* sC = sA1;   // [m][9]: s*4+c at stride 9 (288*9 = 2592 u16)
    for (int tau = wv; tau < 9; tau += 4){
        int mt = tau / 3, nt = tau - (tau/3)*3;
        fv4 acc = (fv4){0.f,0.f,0.f,0.f};
        #pragma unroll
        for (int ks = 0; ks < 3; ++ks){
            bfv8 a  = *reinterpret_cast<const bfv8*>(&sA2[(mt*16 + ln)*104 + ks*32 + qd*8]);
            bfv8 bb = *reinterpret_cast<const bfv8*>(&sB2[(nt*16 + ln)*104 + ks*32 + qd*8]);
            acc = __builtin_amdgcn_mfma_f32_16x16x32_bf16(a, bb, acc, 0, 0, 0);
        }
        int col = nt*16 + ln;
        int ky = col >> 1, s = col & 1;
        #pragma unroll
        for (int rr = 0; rr < 4; ++rr){
            int r = mt*16 + qd*4 + rr;
            int c = r / 12, kxx = r - c*12;
            sC[(ky*12 + kxx)*9 + s*4 + c] = f2us(acc[rr]);
        }
    }
    __syncthreads();
    // ---- fully-coalesced writeback: block owns hft[cg][b][*] = 1152 dwords ----
    unsigned int* dst = hft + ((size_t)(c0 >> 2)*256 + b)*1152;
    for (int d = t; d < 1152; d += 256){
        int m = d >> 2, j = d & 3;
        unsigned int lo = sC[m*9 + 2*j];
        unsigned int hi = sC[m*9 + 2*j + 1];
        dst[d] = lo | (hi << 16);
    }
}

// ---------------- per-mode channel mix as bf16 MFMA GEMM ---------------------
// grid 576 = 288 modes x 2 M-halves of 128; C[128,128] = A[128,128] x B[128,128]
// A kappa order: kappa = cg*8+u (u<4: Re(c=cg*4+u), u>=4: Im), B staged to match.
// XCD line-mate swizzle: m-quads (same q=m>>2, same mh) get block ids differing
// by multiples of 8 -> same XCD L2 -> hft/weight 64B lines fetched once.
__global__ __launch_bounds__(256) void k_mixm(const unsigned short* __restrict__ hft,
                                              const void* __restrict__ sc_w1,
                                              const void* __restrict__ sc_w2,
                                              unsigned int* __restrict__ mixed, int layer,
                                              const float* __restrict__ flg){
    __shared__ unsigned short sB[128*136];   // BT[n][kappa], row stride 136
    const bool f32 = (flg[0] > 0.5f);
    int B = blockIdx.x;
    int x8 = B & 7, w8 = B >> 3;
    int r4 = w8 & 3, g = w8 >> 2;     // g < 18
    int u = g*8 + x8;                 // u < 144
    int mh = u & 1;
    int m  = (u >> 1)*4 + r4;         // m < 288
    int b0 = mh * 128;
    int t = threadIdx.x;
    int kyi = m / 12, kx = m - kyi*12;
    const void* w = (kyi < 12) ? sc_w1 : sc_w2;
    int r = (kyi < 12) ? kyi : kyi - 12;
    size_t wbase = (size_t)layer * 64*64*144*2;
    for (int idx = t; idx < 4096; idx += 256){     // idx = i*64+o
        int i = idx >> 6, o = idx & 63;
        size_t off = wbase + (((size_t)idx*12 + r)*12 + kx)*2;
        float wr = rdf(w, off, f32);
        float wi = rdf(w, off+1, f32);
        int kre = ((i >> 2) << 3) + (i & 3);       // kappa of Re(c=i)
        sB[o*136 + kre]          = f2us(wr);
        sB[(o+64)*136 + kre]     = f2us(wi);
        sB[o*136 + kre + 4]      = f2us(-wi);
        sB[(o+64)*136 + kre + 4] = f2us(wr);
    }
    __syncthreads();
    int ln = t & 15, qd = (t & 63) >> 4, wv = t >> 6;
    // A fragments: A[row][kappa=ks*32+qd*8 ..+7] = hft[g=ks*4+qd][row][m][0..7]
    bfv8 af[2][4];
    int arow = b0 + wv*32 + ln;
    #pragma unroll
    for (int tm = 0; tm < 2; ++tm)
        #pragma unroll
        for (int ks = 0; ks < 4; ++ks){
            int gg = ks*4 + qd;
            af[tm][ks] = *reinterpret_cast<const bfv8*>(
                hft + (((size_t)gg*256 + arow + tm*16)*288 + m)*8);
        }
    fv4 acc[2][8];
    #pragma unroll
    for (int tm=0;tm<2;++tm)
        #pragma unroll
        for (int tn=0;tn<8;++tn) acc[tm][tn] = (fv4){0.f,0.f,0.f,0.f};
    #pragma unroll
    for (int ks = 0; ks < 4; ++ks){
        bfv8 bfr[8];
        #pragma unroll
        for (int tn = 0; tn < 8; ++tn)
            bfr[tn] = *reinterpret_cast<const bfv8*>(&sB[(tn*16 + ln)*136 + ks*32 + qd*8]);
        #pragma unroll
        for (int tm = 0; tm < 2; ++tm)
            #pragma unroll
            for (int tn = 0; tn < 8; ++tn)
                acc[tm][tn] = __builtin_amdgcn_mfma_f32_16x16x32_bf16(af[tm][ks], bfr[tn], acc[tm][tn], 0, 0, 0);
    }
    __syncthreads();
    // C -> LDS (reuse sB): C[row][col], row stride 136; C/D map row=qd*4+r, col=ln
    #pragma unroll
    for (int tm = 0; tm < 2; ++tm)
        #pragma unroll
        for (int tn = 0; tn < 8; ++tn)
            #pragma unroll
            for (int rr = 0; rr < 4; ++rr){
                int row = wv*32 + tm*16 + qd*4 + rr;
                int col = tn*16 + ln;
                sB[row*136 + col] = f2us(acc[tm][tn][rr]);
            }
    __syncthreads();
    // pack (r,i) and write mixed[b][m][o] — 256B contiguous per (b,m), coalesced
    for (int idx = t; idx < 8192; idx += 256){
        int row = idx >> 6, o = idx & 63;
        unsigned int pr = ((unsigned int)sB[row*136 + o]) |
                          (((unsigned int)sB[row*136 + o + 64]) << 16);
        mixed[((size_t)(b0 + row)*288 + m)*64 + o] = pr;
    }
}

// ---------------- pointwise 64x64 channel GEMM (wc path), IN PLACE -----------
// grid 2304 = 256 b x 9 row-groups of 4; bf16-packed LDS
__global__ __launch_bounds__(256) void k_wc(bf16* __restrict__ h,
                                            const void* __restrict__ wc_w,
                                            const void* __restrict__ wc_b,
                                            int layer,
                                            const float* __restrict__ flg){
    __shared__ unsigned int shhp[4352];   // [c][68 dwords] = [c][136 u16 px]
    __shared__ unsigned int swp[2048];    // [c][oh] pairs (o even, o+1)
    __shared__ float sb[64];
    const bool f32 = (flg[0] > 0.5f);
    unsigned short* sh16 = (unsigned short*)shhp;
    int blk = blockIdx.x;
    int b = blk / 9, g = blk - b*9;
    int y0 = g*4;
    int nrow = 34 - y0; if (nrow > 4) nrow = 4;
    int t = threadIdx.x;
    size_t wbase = (size_t)layer*4096;
    for (int idx = t; idx < 2048; idx += 256){
        int oh = idx >> 6, c = idx & 63;
        swp[c*32 + oh] = packbf2(rdf(wc_w, wbase + (size_t)(2*oh)*64 + c, f32),
                                 rdf(wc_w, wbase + (size_t)(2*oh+1)*64 + c, f32));
    }
    if (t < 64) sb[t] = rdf(wc_b, layer*64 + t, f32);
    bf16* hb = h + (size_t)b*73984 + y0*34;
    for (int e = t; e < 4352; e += 256){
        int c = e / 68, d = e - c*68;
        shhp[e] = ((const unsigned int*)(hb + (size_t)c*1156))[d];  // trailing garbage unused
    }
    __syncthreads();
    for (int tau = t; tau < 272; tau += 256){
        int ot = tau / 34, pxt = tau - ot*34;
        int o0 = ot*8;
        float acc[4][8];
        #pragma unroll
        for (int j=0;j<4;++j)
            #pragma unroll
            for (int k=0;k<8;++k) acc[j][k] = sb[o0+k];
        for (int c = 0; c < 64; ++c){
            float hv[4], wv[8];
            #pragma unroll
            for (int j=0;j<4;++j) hv[j] = us2f(sh16[c*136 + pxt + j*34]);
            #pragma unroll
            for (int d=0;d<4;++d){
                float2 wp = unpackbf2(swp[c*32 + (o0>>1) + d]);
                wv[2*d] = wp.x; wv[2*d+1] = wp.y;
            }
            #pragma unroll
            for (int j=0;j<4;++j)
                #pragma unroll
                for (int k=0;k<8;++k) acc[j][k] += hv[j]*wv[k];
        }
        #pragma unroll
        for (int j=0;j<4;++j){
            if (j < nrow){
                #pragma unroll
                for (int k=0;k<8;++k)
                    hb[(size_t)(o0+k)*1156 + pxt + j*34] = __float2bfloat16(acc[j][k]);
            }
        }
    }
}

// ---------------- inverse truncated DFT as MFMA GEMMs; in-place add + gelu ---
// grid 4096 = 256 b x 16 o-groups of 4, XCD line-mate swizzled:
//   B = z*32 + s*8 + x  ->  b = (z>>2)*8 + x, og = (z&3)*4 + s
//   og-quads of the same b (which share each 64B line of mixed) land on the
//   same XCD (ids differ by 8/16/24) -> line fetched once into that L2.
// B operands (invBT/invW2) are read DIRECTLY from global images (L2-resident,
// fragment-ready layout); OOB rows give garbage discarded by col/y predicates.
// LDS 36.9 KB -> 4 blocks/CU.
__global__ __launch_bounds__(256) void k_invm(const unsigned int* __restrict__ mixed,
                                              const float* __restrict__ tabs,
                                              bf16* __restrict__ hio, int layer){
    __shared__ unsigned short lds[18448];   // 36,896 B total
    unsigned short* sA  = lds;              // 96*40 (step A only; overlaps htile)
    unsigned short* sG  = lds + 4624;       // 4*48*72 (htile = lds[0..4624))
    unsigned int* ldsw  = (unsigned int*)lds;
    int B = blockIdx.x;
    int x8 = B & 7, s4 = (B >> 3) & 3, z = B >> 5;
    int b  = (z >> 2)*8 + x8;
    int o0 = ((z & 3)*4 + s4)*4;
    int t = threadIdx.x;
    const unsigned short* gBT16 = (const unsigned short*)(tabs + 2448);  // [n][32 u16]
    const unsigned short* gW216 = (const unsigned short*)(tabs + 3536);  // [y][64 u16]
    // sA from mixed[b][m][o]: 16B per (m), stride 256B (lines shared intra-XCD)
    const unsigned int* msrc = mixed + (size_t)b*18432 + o0;
    for (int i = t; i < 1152; i += 256){
        int m = i >> 2, ch = i & 3;
        int kyi = m / 12, kx = m - kyi*12;
        ((unsigned int*)sA)[(ch*24 + kyi)*20 + kx] = msrc[(size_t)m*64 + ch];
    }
    for (int i = t; i < 384; i += 256)       // zero k 24..31 (dw 12..15)
        ((unsigned int*)sA)[(i >> 2)*20 + 12 + (i & 3)] = 0;
    // sG: zero only read pads — rows x in [34,48): dw 0..31; rows x<34: dw 24..31
    for (int i = t; i < 1792; i += 256){
        int r = i >> 5;
        int ch = r / 14, x = 34 + (r - (r/14)*14);
        ((unsigned int*)sG)[(ch*48 + x)*36 + (i & 31)] = 0;
    }
    for (int i = t; i < 1088; i += 256){
        int r = i >> 3;
        int ch = r / 34, x = r - (r/34)*34;
        ((unsigned int*)sG)[(ch*48 + x)*36 + 24 + (i & 7)] = 0;
    }
    __syncthreads();
    int ln = t & 15, qd = (t & 63) >> 4, wv = t >> 6;
    // ---- step A: 30 tiles (6 M x 5 N), K=32; B-frag direct from gBT image ----
    for (int tau = wv; tau < 30; tau += 4){
        int mt = tau / 5, nt = tau - mt*5;
        bfv8 a  = *reinterpret_cast<const bfv8*>(&sA[(mt*16 + ln)*40 + qd*8]);
        bfv8 bb = *reinterpret_cast<const bfv8*>(&gBT16[(nt*16 + ln)*32 + qd*8]);
        fv4 acc = (fv4){0.f,0.f,0.f,0.f};
        acc = __builtin_amdgcn_mfma_f32_16x16x32_bf16(a, bb, acc, 0, 0, 0);
        int col = nt*16 + ln;
        if (col < 68){
            int x = col >> 1, ri = col & 1;
            #pragma unroll
            for (int rr = 0; rr < 4; ++rr){
                int row = mt*16 + qd*4 + rr;
                int ch = row / 24, kyi = row - ch*24;
                sG[(ch*48 + x)*72 + 2*kyi + ri] = f2us(acc[rr]);
            }
        }
    }
    __syncthreads();
    // ---- stage htile (4 contiguous ch-planes) into lds[0..2312) dwords ----
    const unsigned int* hsrc = (const unsigned int*)(hio + (size_t)b*73984 + (size_t)o0*1156);
    for (int i = t; i < 2312; i += 256) ldsw[i] = hsrc[i];
    __syncthreads();
    // ---- step B: wave = ch; 3x3 tiles, K=64 (2 MFMAs); A-frag direct from gW2 ----
    int ch = wv;
    #pragma unroll
    for (int mt = 0; mt < 3; ++mt){
        bfv8 a0 = *reinterpret_cast<const bfv8*>(&gW216[(mt*16 + ln)*64 + qd*8]);
        bfv8 a1 = *reinterpret_cast<const bfv8*>(&gW216[(mt*16 + ln)*64 + 32 + qd*8]);
        #pragma unroll
        for (int nt = 0; nt < 3; ++nt){
            bfv8 b0 = *reinterpret_cast<const bfv8*>(&sG[(ch*48 + nt*16 + ln)*72 + qd*8]);
            bfv8 b1 = *reinterpret_cast<const bfv8*>(&sG[(ch*48 + nt*16 + ln)*72 + 32 + qd*8]);
            fv4 acc = (fv4){0.f,0.f,0.f,0.f};
            acc = __builtin_amdgcn_mfma_f32_16x16x32_bf16(a0, b0, acc, 0, 0, 0);
            acc = __builtin_amdgcn_mfma_f32_16x16x32_bf16(a1, b1, acc, 0, 0, 0);
            int x = nt*16 + ln;
            if (x < 34){
                #pragma unroll
                for (int rr = 0; rr < 4; ++rr){
                    int y = mt*16 + qd*4 + rr;
                    if (y < 34){
                        int off = ch*1156 + y*34 + x;
                        float v = acc[rr] + us2f(lds[off]);
                        if (layer < 3) v = gelu_f(v);
                        lds[off] = f2us(v);
                    }
                }
            }
        }
    }
    __syncthreads();
    // ---- coalesced dword writeback ----
    unsigned int* hdst = (unsigned int*)(hio + (size_t)b*73984 + (size_t)o0*1156);
    for (int i = t; i < 2312; i += 256) hdst[i] = ldsw[i];
}

// ---------------- 8x8/stride4 VALID conv -> gelu -> pe2 scale ----------------
__global__ __launch_bounds__(256) void k_pe(const bf16* __restrict__ h,
                                            const void* __restrict__ pw,
                                            const void* __restrict__ pb,
                                            const void* __restrict__ p2w,
                                            const void* __restrict__ p2b,
                                            float* __restrict__ p49,
                                            const float* __restrict__ flg){
    __shared__ float red[256];
    const bool f32 = (flg[0] > 0.5f);
    int bid = blockIdx.x;          // b*49 + py*7 + px
    int b = bid / 49, r = bid - b*49;
    int py = r / 7, px = r - py*7;
    int t = threadIdx.x;
    const bf16* hb = h + (size_t)b*73984 + (py*4)*34 + px*4;
    float partial = 0.f;
    for (int tt = t; tt < 4096; tt += 256){
        int c = tt >> 6, k = tt & 63, ky = k >> 3, kx = k & 7;
        partial += bff(hb[(size_t)c*1156 + ky*34 + kx]) * rdf(pw, tt, f32);
    }
    red[t] = partial;
    __syncthreads();
    for (int s = 128; s > 0; s >>= 1){
        if (t < s) red[t] += red[t + s];
        __syncthreads();
    }
    if (t == 0){
        float v = red[0] + rdf(pb, 0, f32);
        v = gelu_f(v);
        p49[bid] = v * rdf(p2w, 0, f32) + rdf(p2b, 0, f32);
    }
}

// ---------------- sentence MLP 384->32->32->16 (relu,relu,lin) ---------------
__global__ __launch_bounds__(64) void k_sent(const void* __restrict__ se,
                                             const void* __restrict__ w1, const void* __restrict__ b1,
                                             const void* __restrict__ w2, const void* __restrict__ b2,
                                             const void* __restrict__ w3, const void* __restrict__ b3,
                                             float* __restrict__ outv,
                                             const float* __restrict__ flg){
    __shared__ float s1[32], s2[32];
    const bool f32 = (flg[0] > 0.5f);
    int b = blockIdx.x, t = threadIdx.x;
    if (t < 32){
        float acc = rdf(b1, t, f32);
        size_t rbase = (size_t)b*384;
        for (int k = 0; k < 384; ++k) acc += rdf(se, rbase + k, f32) * rdf(w1, k*32 + t, f32);
        s1[t] = fmaxf(acc, 0.f);
    }
    __syncthreads();
    if (t < 32){
        float acc = rdf(b2, t, f32);
        for (int k = 0; k < 32; ++k) acc += s1[k] * rdf(w2, k*32 + t, f32);
        s2[t] = fmaxf(acc, 0.f);
    }
    __syncthreads();
    if (t < 16){
        float acc = rdf(b3, t, f32);
        for (int k = 0; k < 32; ++k) acc += s2[k] * rdf(w3, k*16 + t, f32);
        outv[b*16 + t] = acc;
    }
}

// ---------------- xp MLP 49->32->32->16 (silu,silu,lin) ----------------------
__global__ __launch_bounds__(64) void k_xp(const float* __restrict__ p49,
                                           const void* __restrict__ w1, const void* __restrict__ b1,
                                           const void* __restrict__ w2, const void* __restrict__ b2,
                                           const void* __restrict__ w3, const void* __restrict__ b3,
                                           float* __restrict__ outv,
                                           const float* __restrict__ flg){
    __shared__ float s1[32], s2[32];
    const bool f32 = (flg[0] > 0.5f);
    int b = blockIdx.x, t = threadIdx.x;
    if (t < 32){
        float acc = rdf(b1, t, f32);
        const float* row = p49 + b*49;
        for (int k = 0; k < 49; ++k) acc += row[k] * rdf(w1, k*32 + t, f32);
        s1[t] = silu_f(acc);
    }
    __syncthreads();
    if (t < 32){
        float acc = rdf(b2, t, f32);
        for (int k = 0; k < 32; ++k) acc += s1[k] * rdf(w2, k*32 + t, f32);
        s2[t] = silu_f(acc);
    }
    __syncthreads();
    if (t < 16){
        float acc = rdf(b3, t, f32);
        for (int k = 0; k < 32; ++k) acc += s2[k] * rdf(w3, k*16 + t, f32);
        outv[b*16 + t] = acc;
    }
}

// ---------------- pu MLP part A: 32->128->256 (silu,silu) --------------------
__global__ __launch_bounds__(256) void k_puA(const float* __restrict__ xemb,
                                             const float* __restrict__ semb,
                                             const void* __restrict__ w1, const void* __restrict__ b1,
                                             const void* __restrict__ w2, const void* __restrict__ b2,
                                             float* __restrict__ h2buf,
                                             const float* __restrict__ flg){
    __shared__ float ein[32];
    __shared__ float h1[128];
    const bool f32 = (flg[0] > 0.5f);
    int b = blockIdx.x, t = threadIdx.x;
    if (t < 16) ein[t] = xemb[b*16 + t];
    else if (t < 32) ein[t] = semb[b*16 + (t - 16)];
    __syncthreads();
    if (t < 128){
        float acc = rdf(b1, t, f32);
        for (int k = 0; k < 32; ++k) acc += ein[k] * rdf(w1, k*128 + t, f32);
        h1[t] = silu_f(acc);
    }
    __syncthreads();
    {
        float acc = rdf(b2, t, f32);
        for (int k = 0; k < 128; ++k) acc += h1[k] * rdf(w2, k*256 + t, f32);
        h2buf[(size_t)b*256 + t] = silu_f(acc);
    }
}

// ---------------- pu MLP part B: 256->1156 GEMM ------------------------------
// grid 1280 = 256 b (fast) x 5 n-chunks of 232
__global__ __launch_bounds__(256) void k_puB(const float* __restrict__ h2buf,
                                             const void* __restrict__ w3, const void* __restrict__ b3,
                                             float* __restrict__ emb,
                                             const float* __restrict__ flg){
    __shared__ float sh2[256];
    const bool f32 = (flg[0] > 0.5f);
    int blk = blockIdx.x;
    int b = blk & 255, nc = blk >> 8;
    int t = threadIdx.x;
    sh2[t] = h2buf[(size_t)b*256 + t];
    __syncthreads();
    int e = nc*232 + t;
    if (t < 232 && e < 1156){
        float acc = rdf(b3, e, f32);
        if (f32){
            const float* wp = (const float*)w3 + e;
            #pragma unroll 4
            for (int k = 0; k < 256; ++k) acc += sh2[k] * wp[(size_t)k*1156];
        } else {
            const bf16* wp = (const bf16*)w3 + e;
            #pragma unroll 4
            for (int k = 0; k < 256; ++k) acc += sh2[k] * bff(wp[(size_t)k*1156]);
        }
        emb[(size_t)b*1156 + e] = acc;
    }
}

// ---------------- final: crop, concat emb, fc1(MFMA)+gelu, fc2(MFMA) ---------
// grid 512 = 256 b x 2 halves; 8 iters of 2 rows (64 px).
// fc1: C[64px,128j] = A[px,c<64] x w1 (K=64) + rank-1 emb add; fc2: K=128, N=16(4)
__global__ __launch_bounds__(256, 3) void k_final(const bf16* __restrict__ h,
                                                  const float* __restrict__ emb,
                                                  const void* __restrict__ w1, const void* __restrict__ b1,
                                                  const void* __restrict__ w2, const void* __restrict__ b2,
                                                  void* __restrict__ out,
                                                  const float* __restrict__ flg){
    __shared__ unsigned short sw1t[128*72];   // w1T[j][c], stride 72 (16B-aligned rows)
    __shared__ unsigned short sw2t[16*136];   // w2T[n][j], rows 4..15 zero
    __shared__ float sw1e[128];               // w1[64][j] (emb channel)
    __shared__ float sb1[128];
    __shared__ float sb2[4];
    __shared__ unsigned short spx[64*66];     // input[c][px], stride 66 (odd dwords)
    __shared__ float sembp[64];               // emb[px]
    __shared__ unsigned short sh2[128*66];    // hid[j][px], stride 66
    const bool f32 = (flg[0] > 0.5f);
    int blk = blockIdx.x;
    int b = blk >> 1, half = blk & 1;
    int t = threadIdx.x;
    for (int i = t; i < 8320; i += 256){       // w1 [c=65][j=128]
        int c = i >> 7, j = i & 127;
        float v = rdf(w1, i, f32);
        if (c < 64) sw1t[j*72 + c] = f2us(v);
        else sw1e[j] = v;
    }
    if (t < 128) sb1[t] = rdf(b1, t, f32);
    for (int i = t; i < 2176; i += 256){       // w2 [j=128][k=4] -> w2T[n][j]
        int n = i / 136, j = i - n*136;
        float v = (n < 4 && j < 128) ? rdf(w2, j*4 + n, f32) : 0.f;
        sw2t[i] = f2us(v);
    }
    if (t < 4) sb2[t] = rdf(b2, t, f32);
    __syncthreads();
    int ln = t & 15, qd = (t & 63) >> 4, wv = t >> 6;
    // hoist B fragments (weights) into registers
    bfv8 bw1[8][2];
    #pragma unroll
    for (int tn = 0; tn < 8; ++tn)
        #pragma unroll
        for (int ks = 0; ks < 2; ++ks)
            bw1[tn][ks] = *reinterpret_cast<const bfv8*>(&sw1t[(tn*16 + ln)*72 + ks*32 + qd*8]);
    bfv8 bw2[4];
    #pragma unroll
    for (int ks = 0; ks < 4; ++ks)
        bw2[ks] = *reinterpret_cast<const bfv8*>(&sw2t[ln*136 + ks*32 + qd*8]);
    const bf16* hb = h + (size_t)b*73984;
    const float* eb = emb + (size_t)b*1156;
    for (int it = 0; it < 8; ++it){
        int y0 = half*16 + it*2;               // 2 rows = 64 px
        __syncthreads();
        for (int e = t; e < 2048; e += 256){   // stage spx[c][px] c-major
            int c = e >> 5, d = e & 31;
            int px = d*2;
            int y = y0 + (px >> 5), x = px & 31;
            float v0 = bff(hb[(size_t)c*1156 + y*34 + x]);
            int px1 = px + 1;
            int y1 = y0 + (px1 >> 5), x1 = px1 & 31;
            float v1 = bff(hb[(size_t)c*1156 + y1*34 + x1]);
            ((unsigned int*)spx)[c*33 + d] = packbf2(v0, v1);
        }
        if (t < 64){
            int y = y0 + (t >> 5), x = t & 31;
            sembp[t] = eb[y*34 + x];
        }
        __syncthreads();
        // fc1 MFMA: wave wv owns mtile wv (px = wv*16 + ...)
        fv4 acc[8];
        #pragma unroll
        for (int tn = 0; tn < 8; ++tn) acc[tn] = (fv4){0.f,0.f,0.f,0.f};
        #pragma unroll
        for (int ks = 0; ks < 2; ++ks){
            union { bfv8 v; unsigned short s[8]; } af;
            #pragma unroll
            for (int j = 0; j < 8; ++j)
                af.s[j] = spx[(ks*32 + qd*8 + j)*66 + wv*16 + ln];
            #pragma unroll
            for (int tn = 0; tn < 8; ++tn)
                acc[tn] = __builtin_amdgcn_mfma_f32_16x16x32_bf16(af.v, bw1[tn][ks], acc[tn], 0, 0, 0);
        }
        float ev[4];
        #pragma unroll
        for (int rr = 0; rr < 4; ++rr) ev[rr] = sembp[wv*16 + qd*4 + rr];
        #pragma unroll
        for (int tn = 0; tn < 8; ++tn){
            int col = tn*16 + ln;
            float we = sw1e[col];
            float bb1 = sb1[col];
            #pragma unroll
            for (int rr = 0; rr < 4; ++rr){
                float v = acc[tn][rr] + ev[rr]*we + bb1;
                sh2[col*66 + wv*16 + qd*4 + rr] = f2us(gelu_f(v));
            }
        }
        __syncthreads();
        // fc2 MFMA: K=128, N=16 (4 valid)
        fv4 a2 = (fv4){0.f,0.f,0.f,0.f};
        #pragma unroll
        for (int ks = 0; ks < 4; ++ks){
            union { bfv8 v; unsigned short s[8]; } af;
            #pragma unroll
            for (int j = 0; j < 8; ++j)
                af.s[j] = sh2[(ks*32 + qd*8 + j)*66 + wv*16 + ln];
            a2 = __builtin_amdgcn_mfma_f32_16x16x32_bf16(af.v, bw2[ks], a2, 0, 0, 0);
        }
        if (ln < 4){
            float bb2 = sb2[ln];
            #pragma unroll
            for (int rr = 0; rr < 4; ++rr){
                int pxl = wv*16 + qd*4 + rr;
                int y = y0 + (pxl >> 5), x = pxl & 31;
                size_t o = ((size_t)(b*32 + y)*32 + x)*4 + ln;
                float v = a2[rr] + bb2;
                if (f32) ((float*)out)[o] = v;
                else     ((bf16*)out)[o] = __float2bfloat16(v);
            }
        }
    }
}

extern "C" void kernel_launch(void* const* d_in, const int* in_sizes, int n_in,
                              void* d_out, int out_size, void* d_ws, size_t ws_size,
                              hipStream_t stream) {
    (void)in_sizes; (void)n_in; (void)out_size; (void)ws_size;
    const void* x     = d_in[0];
    const void* grd   = d_in[1];
    const void* se    = d_in[2];
    const void* fc0_w = d_in[3];
    const void* fc0_b = d_in[4];
    const void* sc_w1 = d_in[5];
    const void* sc_w2 = d_in[6];
    const void* wc_w  = d_in[7];
    const void* wc_b  = d_in[8];
    const void* pe1_w = d_in[9];
    const void* pe1_b = d_in[10];
    const void* pe2_w = d_in[11];
    const void* pe2_b = d_in[12];
    const void* sp_w1 = d_in[13];
    const void* sp_b1 = d_in[14];
    const void* sp_w2 = d_in[15];
    const void* sp_b2 = d_in[16];
    const void* sp_w3 = d_in[17];
    const void* sp_b3 = d_in[18];
    const void* xp_w1 = d_in[19];
    const void* xp_b1 = d_in[20];
    const void* xp_w2 = d_in[21];
    const void* xp_b2 = d_in[22];
    const void* xp_w3 = d_in[23];
    const void* xp_b3 = d_in[24];
    const void* pu_w1 = d_in[25];
    const void* pu_b1 = d_in[26];
    const void* pu_w2 = d_in[27];
    const void* pu_b2 = d_in[28];
    const void* pu_w3 = d_in[29];
    const void* pu_b3 = d_in[30];
    const void* fc1_w = d_in[31];
    const void* fc1_b = d_in[32];
    const void* fc2_w = d_in[33];
    const void* fc2_b = d_in[34];

    // workspace layout (float-unit offsets); total ~77 MB
    float* ws    = (float*)d_ws;
    bf16*  hA    = (bf16*)ws;                              // 18,939,904 bf16
    unsigned int* hft   = (unsigned int*)(ws + 9469952);   // 4,718,592 dwords (hft cg-panels)
    unsigned int* mixed = (unsigned int*)(ws + 14188544);  // 4,718,592 dwords ([b][m][o])
    float* tabs  = ws + 18907136;                          // 4,896 (DFT tables + inv images)
    float* p49   = ws + 18912032;                          // 12,544
    float* semb  = ws + 18924576;                          // 4,096
    float* xemb  = ws + 18928672;                          // 4,096
    float* emb   = ws + 18932768;                          // 295,936
    float* flag  = ws + 19228704;                          // 1
    float* h2buf = (float*)hft;                            // reuse: hft dead after layer loop

    k_probe<<<1, 256, 0, stream>>>(x, flag);
    k_tables<<<1, 256, 0, stream>>>(tabs);
    k_fc0<<<1024, 256, 0, stream>>>(x, grd, fc0_w, fc0_b, hA, flag);

    for (int l = 0; l < 4; ++l){
        k_fwd<<<4096, 256, 0, stream>>>(hA, hft, tabs);
        k_mixm<<<576, 256, 0, stream>>>((const unsigned short*)hft, sc_w1, sc_w2, mixed, l, flag);
        k_wc <<<2304, 256, 0, stream>>>(hA, wc_w, wc_b, l, flag);
        k_invm<<<4096, 256, 0, stream>>>(mixed, tabs, hA, l);
    }

    k_pe  <<<256*49, 256, 0, stream>>>(hA, pe1_w, pe1_b, pe2_w, pe2_b, p49, flag);
    k_sent<<<256, 64, 0, stream>>>(se, sp_w1, sp_b1, sp_w2, sp_b2, sp_w3, sp_b3, semb, flag);
    k_xp  <<<256, 64, 0, stream>>>(p49, xp_w1, xp_b1, xp_w2, xp_b2, xp_w3, xp_b3, xemb, flag);
    k_puA <<<256, 256, 0, stream>>>(xemb, semb, pu_w1, pu_b1, pu_w2, pu_b2, h2buf, flag);
    k_puB <<<1280, 256, 0, stream>>>(h2buf, pu_w3, pu_b3, emb, flag);
    k_final<<<512, 256, 0, stream>>>(hA, emb, fc1_w, fc1_b, fc2_w, fc2_b, d_out, flag);
}

// Round 5
// 1325.563 us; speedup vs baseline: 1.0676x; 1.0676x over previous
//
#include <hip/hip_runtime.h>
#include <hip/hip_bf16.h>
#include <math.h>

typedef __hip_bfloat16 bf16;
typedef __bf16 bfv8 __attribute__((ext_vector_type(8)));
typedef float fv4 __attribute__((ext_vector_type(4)));

__device__ __forceinline__ float bff(const bf16 x){ return __bfloat162float(x); }
__device__ __forceinline__ float gelu_f(float v){
    return 0.5f * v * (1.f + erff(v * 0.70710678118654752f));
}
__device__ __forceinline__ float silu_f(float v){
    return v / (1.f + expf(-v));
}
// dtype-agnostic input read: f32 ? fp32 : bf16
__device__ __forceinline__ float rdf(const void* p, size_t i, bool f32){
    return f32 ? ((const float*)p)[i] : __bfloat162float(((const bf16*)p)[i]);
}
__device__ __forceinline__ unsigned int packbf2(float a, float b){
    __hip_bfloat162 v;
    v.x = __float2bfloat16(a);
    v.y = __float2bfloat16(b);
    return *reinterpret_cast<unsigned int*>(&v);
}
__device__ __forceinline__ float2 unpackbf2(unsigned int u){
    __hip_bfloat162 v = *reinterpret_cast<__hip_bfloat162*>(&u);
    return make_float2(__bfloat162float(v.x), __bfloat162float(v.y));
}
__device__ __forceinline__ float us2f(unsigned short u){
    unsigned int x = ((unsigned int)u) << 16;
    return __uint_as_float(x);
}
__device__ __forceinline__ unsigned short f2us(float f){
    bf16 v = __float2bfloat16(f);
    return *reinterpret_cast<unsigned short*>(&v);
}

// Geometry
// B=256, C=64, H=W=34 (padded), modes: ky in {0..11, 22..33} (24), kx in 0..11 (12)
// h layout (ws, bf16): [b][c][y][x], stride c = 1156, stride b = 73984
// hft layout: [cg<16][b<256][m<288][8 bf16] ; kappa = cg*8+u, u<4: Re(c=cg*4+u),
//             u>=4: Im(c=cg*4+u-4).  Writer (k_fwd) fully coalesced per block.
// mixed layout: [b<256][m<288][o<64] packed bf16x2 dwords (r,i); writer (k_mixm)
//             owns full 256B rows per (b,m).
// tabs: [0,1632) Wfy f32 | [1632,2448) Wfx f32 |
//       [2448,3536) invBT bf16 image (68x16 dw) | [3536,4624) invW2 bf16 image (34x32 dw)
// invBT/invW2 are fragment-ready: k_invm reads MFMA fragments DIRECTLY from them
// (rows 32/64-u16 stride, kappa pads pre-zeroed; OOB rows discarded by predicates).

// ---------------- dtype probe ----------------
__global__ __launch_bounds__(256) void k_probe(const void* x, float* flag){
    __shared__ int wild;
    int t = threadIdx.x;
    if (t == 0) wild = 0;
    __syncthreads();
    const bf16* xb = (const bf16*)x;
    for (int i = t; i < 1024; i += 256){
        float v = bff(xb[i]);
        if (!(fabsf(v) < 1e10f)) wild = 1;
    }
    __syncthreads();
    if (t == 0) flag[0] = wild ? 1.f : 0.f;
}

// ---------------- tables ----------------
__global__ __launch_bounds__(256) void k_tables(float* tabs){
    int t = threadIdx.x;
    float* Wfy = tabs;          // 24*34*2
    float* Wfx = tabs + 1632;   // 12*34*2
    unsigned int* gBT = (unsigned int*)(tabs + 2448);   // [n<68][kd<16] bf16x2
    unsigned int* gW2 = (unsigned int*)(tabs + 3536);   // [y<34][kd<32] bf16x2
    const float TWO_PI = 6.283185307179586f;
    for (int e = t; e < 24*34; e += 256){
        int kyi = e / 34, y = e % 34;
        int ky = (kyi < 12) ? kyi : kyi + 10;
        int ph = (ky * y) % 34;
        float ang = TWO_PI * (float)ph / 34.0f;
        float s, c;
        sincosf(ang, &s, &c);
        Wfy[e*2]   = c;   Wfy[e*2+1] = -s;           // e^{-i ang}
    }
    for (int e = t; e < 12*34; e += 256){
        int kx = e / 34, x = e % 34;
        int ph = (kx * x) % 34;
        float ang = TWO_PI * (float)ph / 34.0f;
        float s, c;
        sincosf(ang, &s, &c);
        Wfx[e*2] = c; Wfx[e*2+1] = -s;               // e^{-i ang}
    }
    // invBT image: n=2x+ri (x<34), k=2kx+ri2; v = ri==0 ? (ri2==0? C : -S) : (ri2==0? S : C)
    // where C = ck*cos(ang), S = ck*sin(ang), ang = +2pi*(kx*x mod 34)/34, ck = (kx==0?1:2)
    for (int i = t; i < 1088; i += 256){
        int n = i >> 4, kd = i & 15;
        int x = n >> 1, ri = n & 1;
        int kx = kd;
        float v0 = 0.f, v1 = 0.f;
        if (kx < 12){
            int ph = (kx * x) % 34;
            float ang = TWO_PI * (float)ph / 34.0f;
            float s, c;
            sincosf(ang, &s, &c);
            float ck = (kx == 0) ? 1.0f : 2.0f;
            float C = ck * c, S = ck * s;
            v0 = (ri == 0) ? C : S;       // ri2 = 0
            v1 = (ri == 0) ? -S : C;      // ri2 = 1
        }
        gBT[i] = packbf2(v0, v1);
    }
    // invW2 image: y<34, k=2kyi+ri; v = (1/1156)*(ri==0? cos : -sin), ang=+2pi*(ky*y mod 34)/34
    for (int i = t; i < 1088; i += 256){
        int y = i >> 5, kd = i & 31;
        int kyi = kd;
        float v0 = 0.f, v1 = 0.f;
        if (kyi < 24){
            int ky = (kyi < 12) ? kyi : kyi + 10;
            int ph = (ky * y) % 34;
            float ang = TWO_PI * (float)ph / 34.0f;
            float s, c;
            sincosf(ang, &s, &c);
            v0 = c * (1.0f/1156.0f);
            v1 = -s * (1.0f/1156.0f);
        }
        gW2[i] = packbf2(v0, v1);
    }
}

// ---------------- fc0 as MFMA GEMM: concat(x,grid) @ fc0_w + b ---------------
// grid 1024: B -> b = (B>>5)*8 + (B&7), q = (B>>3)&3  (4 quarters of b co-XCD)
// Block: px in [q*256, q*256+256); C[256px][64c], K=42 pad 64.
// Epilogue: C transposed into LDS sC[c][8rows x 34] image (x-pads zeroed),
// then fully-coalesced dword writeback of the block-owned 544B run per c-plane.
__global__ __launch_bounds__(256) void k_fc0(const void* __restrict__ xin,
                                             const void* __restrict__ grd,
                                             const void* __restrict__ w,
                                             const void* __restrict__ bias,
                                             bf16* __restrict__ h,
                                             const float* __restrict__ flg){
    __shared__ unsigned short sA[256*72];   // A[px][k], stride 72 u16; reused as sC[64][272]
    __shared__ unsigned short sBT[64*72];   // BT[c][k], stride 72
    __shared__ float sb[64];
    const bool f32 = (flg[0] > 0.5f);
    int B = blockIdx.x;
    int b = (B >> 5)*8 + (B & 7);
    int q = (B >> 3) & 3;
    int t = threadIdx.x;
    // stage BT[c][k]: w is [k=42][c=64]; k 42..63 zero
    for (int i = t; i < 4096; i += 256){
        int k = i >> 6, c = i & 63;
        sBT[c*72 + k] = f2us((k < 42) ? rdf(w, (size_t)k*64 + c, f32) : 0.f);
    }
    if (t < 64) sb[t] = rdf(bias, t, f32);
    // stage A: x rows (k<40), grid (k 40,41), zero k 42..63
    size_t xbase = ((size_t)b*1024 + q*256)*40;
    for (int i = t; i < 10240; i += 256){
        int p = i / 40, k = i - p*40;
        sA[p*72 + k] = f2us(rdf(xin, xbase + i, f32));
    }
    size_t gbase = ((size_t)b*1024 + q*256)*2;
    for (int i = t; i < 512; i += 256)
        sA[(i >> 1)*72 + 40 + (i & 1)] = f2us(rdf(grd, gbase + i, f32));
    for (int i = t; i < 5632; i += 256){
        int p = i / 22, k = 42 + (i - p*22);
        sA[p*72 + k] = 0;
    }
    __syncthreads();
    int ln = t & 15, qd = (t & 63) >> 4, wv = t >> 6;
    // ---- phase 1: all frags + MFMA in registers (sA still live) ----
    bfv8 bfr[4][2];
    #pragma unroll
    for (int nt = 0; nt < 4; ++nt)
        #pragma unroll
        for (int ks = 0; ks < 2; ++ks)
            bfr[nt][ks] = *reinterpret_cast<const bfv8*>(&sBT[(nt*16 + ln)*72 + ks*32 + qd*8]);
    bfv8 a_[4][2];
    #pragma unroll
    for (int mi = 0; mi < 4; ++mi){
        int mt = wv*4 + mi;
        a_[mi][0] = *reinterpret_cast<const bfv8*>(&sA[(mt*16 + ln)*72 + qd*8]);
        a_[mi][1] = *reinterpret_cast<const bfv8*>(&sA[(mt*16 + ln)*72 + 32 + qd*8]);
    }
    fv4 acc[4][4];
    #pragma unroll
    for (int mi = 0; mi < 4; ++mi)
        #pragma unroll
        for (int nt = 0; nt < 4; ++nt){
            fv4 a = (fv4){0.f,0.f,0.f,0.f};
            a = __builtin_amdgcn_mfma_f32_16x16x32_bf16(a_[mi][0], bfr[nt][0], a, 0, 0, 0);
            a = __builtin_amdgcn_mfma_f32_16x16x32_bf16(a_[mi][1], bfr[nt][1], a, 0, 0, 0);
            acc[mi][nt] = a;
        }
    __syncthreads();
    // ---- phase 2: C -> sC[c][272] (8 rows x 34, x-pads zeroed) ----
    unsigned int* sCd = (unsigned int*)sA;   // [c][136 dw]
    for (int i = t; i < 512; i += 256)       // zero x=32,33 pad dword per (c,row)
        sCd[(i >> 3)*136 + (i & 7)*17 + 16] = 0;
    #pragma unroll
    for (int mi = 0; mi < 4; ++mi)
        #pragma unroll
        for (int nt = 0; nt < 4; ++nt){
            int c = nt*16 + ln;
            float bb = sb[c];
            int pl = (wv*4 + mi)*16 + qd*4;   // local px, 4 consecutive, same row
            int y = pl >> 5, x = pl & 31;
            int di = c*136 + y*17 + (x >> 1);
            sCd[di]     = packbf2(acc[mi][nt][0] + bb, acc[mi][nt][1] + bb);
            sCd[di + 1] = packbf2(acc[mi][nt][2] + bb, acc[mi][nt][3] + bb);
        }
    __syncthreads();
    // ---- phase 3: coalesced writeback of block-owned runs ----
    unsigned int* hw = (unsigned int*)(h + (size_t)b*73984);
    for (int i = t; i < 8704; i += 256){
        int c = i / 136, d = i - c*136;
        hw[c*578 + q*136 + d] = sCd[i];
    }
    if (q == 3){                              // rows y=32,33 zero (full pad rows)
        for (int i = t; i < 2176; i += 256){
            int c = i / 34, d = i - c*34;
            hw[c*578 + 544 + d] = 0;
        }
    }
}

// ---------------- forward truncated DFT via MFMA, 4 channels per block -------
// grid 4096 = 256 b x 16 ch-groups; writes hft [cg][b][m][8bf16] (coalesced)
// F1 (x-DFT): C1[(c,y)][2kx+s] = sum_x h[c][y][x] * Wfx(s? ci : cr)  (K=64, x pad)
// F2 (y-DFT): C2[(c,kx)][2ky+s] = sum_{2y+p} Gx * B2-image             (K=96, pad)
// B2[2y+p][2ky+s]: (s,p)=(0,0)Wr (0,1)-Wi (1,0)Wi (1,1)Wr, W = e^{-i 2pi ky y/34}
__global__ __launch_bounds__(256) void k_fwd(const bf16* __restrict__ h,
                                             unsigned int* __restrict__ hft,
                                             const float* __restrict__ tabs){
    __shared__ unsigned short lds[22656];   // 45,312 B
    unsigned short* sA1 = lds;              // 144 rows x 72 (rows=(c*34+y), k=x pad 64)
    unsigned short* sB1 = lds + 10368;      // 32 x 72 (rows=2kx+s, k=x)
    unsigned short* sA2 = lds + 12672;      // 48 x 104 (rows=(c*12+kx), kappa=2y+p pad 96)
    unsigned short* sB2 = lds + 17664;      // 48 x 104 (rows=2ky+s)
    unsigned int* sA1w = (unsigned int*)sA1;
    unsigned int* sA2w = (unsigned int*)sA2;
    int blk = blockIdx.x;
    int b = blk >> 4, c0 = (blk & 15) * 4;
    int t = threadIdx.x;
    // stage h (4 planes) into sA1 rows (c*34+y), dword granularity (coalesced)
    const unsigned int* srcp = (const unsigned int*)(h + (size_t)b*73984 + (size_t)c0*1156);
    for (int i = t; i < 2312; i += 256){
        int c = i / 578; int rem = i - c*578;
        int y = rem / 17; int d = rem - y*17;
        sA1w[(c*34 + y)*36 + d] = srcp[i];
    }
    // zero x-pad dwords 17..31 of rows 0..135
    for (int i = t; i < 2040; i += 256){
        int r = i / 15, d = i - r*15;
        sA1w[r*36 + 17 + d] = 0;
    }
    // zero tail rows 136..143 entirely
    for (int i = t; i < 288; i += 256){
        int r = 136 + i / 36, d = i - (i/36)*36;
        sA1w[r*36 + d] = 0;
    }
    // build B1 image from Wfx floats: row=2kx+s (24, pad 32), k=x (34, pad 72)
    for (int i = t; i < 2304; i += 256){
        int row = i / 72, k = i - row*72;
        float v = 0.f;
        if (row < 24 && k < 34){
            int kx = row >> 1, s = row & 1;
            v = tabs[1632 + (kx*34 + k)*2 + s];
        }
        sB1[i] = f2us(v);
    }
    // build B2 image from Wfy floats: row=2ky+s (48), kappa=2y+p (68, pad 104)
    for (int i = t; i < 4992; i += 256){
        int row = i / 104, kk = i - row*104;
        float v = 0.f;
        if (kk < 68){
            int ky = row >> 1, s = row & 1;
            int y = kk >> 1, p = kk & 1;
            float wr = tabs[(ky*34 + y)*2];
            float wi = tabs[(ky*34 + y)*2 + 1];
            v = (s == 0) ? ((p == 0) ? wr : -wi) : ((p == 0) ? wi : wr);
        }
        sB2[i] = f2us(v);
    }
    // zero sA2 kappa pad [68,96) = dwords 34..47 of each row
    for (int i = t; i < 672; i += 256){
        int r = i / 14, d = i - r*14;
        sA2w[r*52 + 34 + d] = 0;
    }
    __syncthreads();
    int ln = t & 15, qd = (t & 63) >> 4, wv = t >> 6;
    // ---- F1: 9 M-tiles x 2 N-tiles, K=64; wave owns one nt (static frag idx) ----
    {
        int ntw = wv & 1;
        bfv8 b1f[2];
        #pragma unroll
        for (int ks = 0; ks < 2; ++ks)
            b1f[ks] = *reinterpret_cast<const bfv8*>(&sB1[(ntw*16 + ln)*72 + ks*32 + qd*8]);
        int col = ntw*16 + ln;
        int kx = col >> 1, s = col & 1;
        for (int mt = (wv >> 1); mt < 9; mt += 2){
            fv4 acc = (fv4){0.f,0.f,0.f,0.f};
            #pragma unroll
            for (int ks = 0; ks < 2; ++ks){
                bfv8 a = *reinterpret_cast<const bfv8*>(&sA1[(mt*16 + ln)*72 + ks*32 + qd*8]);
                acc = __builtin_amdgcn_mfma_f32_16x16x32_bf16(a, b1f[ks], acc, 0, 0, 0);
            }
            if (col < 24){
                #pragma unroll
                for (int rr = 0; rr < 4; ++rr){
                    int r = mt*16 + qd*4 + rr;
                    if (r < 136){
                        int c = r / 34, y = r - c*34;
                        sA2[(c*12 + kx)*104 + 2*y + s] = f2us(acc[rr]);
                    }
                }
            }
        }
    }
    __syncthreads();
    // ---- F2: 3 M-tiles x 3 N-tiles, K=96; scatter into sC (reuse sA1) ----
    unsigned short* sC = sA1;   // [m][9]: s*4+c at stride 9 (288*9 = 2592 u16)
    for (int tau = wv; tau < 9; tau += 4){
        int mt = tau / 3, nt = tau - (tau/3)*3;
        fv4 acc = (fv4){0.f,0.f,0.f,0.f};
        #pragma unroll
        for (int ks = 0; ks < 3; ++ks){
            bfv8 a  = *reinterpret_cast<const bfv8*>(&sA2[(mt*16 + ln)*104 + ks*32 + qd*8]);
            bfv8 bb = *reinterpret_cast<const bfv8*>(&sB2[(nt*16 + ln)*104 + ks*32 + qd*8]);
            acc = __builtin_amdgcn_mfma_f32_16x16x32_bf16(a, bb, acc, 0, 0, 0);
        }
        int col = nt*16 + ln;
        int ky = col >> 1, s = col & 1;
        #pragma unroll
        for (int rr = 0; rr < 4; ++rr){
            int r = mt*16 + qd*4 + rr;
            int c = r / 12, kxx = r - c*12;
            sC[(ky*12 + kxx)*9 + s*4 + c] = f2us(acc[rr]);
        }
    }
    __syncthreads();
    // ---- fully-coalesced writeback: block owns hft[cg][b][*] = 1152 dwords ----
    unsigned int* dst = hft + ((size_t)(c0 >> 2)*256 + b)*1152;
    for (int d = t; d < 1152; d += 256){
        int m = d >> 2, j = d & 3;
        unsigned int lo = sC[m*9 + 2*j];
        unsigned int hi = sC[m*9 + 2*j + 1];
        dst[d] = lo | (hi << 16);
    }
}

// ---------------- per-mode channel mix as bf16 MFMA GEMM ---------------------
// grid 576 = 288 modes x 2 M-halves of 128; C[128,128] = A[128,128] x B[128,128]
// A kappa order: kappa = cg*8+u (u<4: Re(c=cg*4+u), u>=4: Im), B staged to match.
// XCD line-mate swizzle: m-quads (same q=m>>2, same mh) get block ids differing
// by multiples of 8 -> same XCD L2 -> hft/weight 64B lines fetched once.
__global__ __launch_bounds__(256) void k_mixm(const unsigned short* __restrict__ hft,
                                              const void* __restrict__ sc_w1,
                                              const void* __restrict__ sc_w2,
                                              unsigned int* __restrict__ mixed, int layer,
                                              const float* __restrict__ flg){
    __shared__ unsigned short sB[128*136];   // BT[n][kappa], row stride 136
    const bool f32 = (flg[0] > 0.5f);
    int B = blockIdx.x;
    int x8 = B & 7, w8 = B >> 3;
    int r4 = w8 & 3, g = w8 >> 2;     // g < 18
    int u = g*8 + x8;                 // u < 144
    int mh = u & 1;
    int m  = (u >> 1)*4 + r4;         // m < 288
    int b0 = mh * 128;
    int t = threadIdx.x;
    int kyi = m / 12, kx = m - kyi*12;
    const void* w = (kyi < 12) ? sc_w1 : sc_w2;
    int r = (kyi < 12) ? kyi : kyi - 12;
    size_t wbase = (size_t)layer * 64*64*144*2;
    for (int idx = t; idx < 4096; idx += 256){     // idx = i*64+o
        int i = idx >> 6, o = idx & 63;
        size_t off = wbase + (((size_t)idx*12 + r)*12 + kx)*2;
        float wr = rdf(w, off, f32);
        float wi = rdf(w, off+1, f32);
        int kre = ((i >> 2) << 3) + (i & 3);       // kappa of Re(c=i)
        sB[o*136 + kre]          = f2us(wr);
        sB[(o+64)*136 + kre]     = f2us(wi);
        sB[o*136 + kre + 4]      = f2us(-wi);
        sB[(o+64)*136 + kre + 4] = f2us(wr);
    }
    __syncthreads();
    int ln = t & 15, qd = (t & 63) >> 4, wv = t >> 6;
    // A fragments: A[row][kappa=ks*32+qd*8 ..+7] = hft[g=ks*4+qd][row][m][0..7]
    bfv8 af[2][4];
    int arow = b0 + wv*32 + ln;
    #pragma unroll
    for (int tm = 0; tm < 2; ++tm)
        #pragma unroll
        for (int ks = 0; ks < 4; ++ks){
            int gg = ks*4 + qd;
            af[tm][ks] = *reinterpret_cast<const bfv8*>(
                hft + (((size_t)gg*256 + arow + tm*16)*288 + m)*8);
        }
    fv4 acc[2][8];
    #pragma unroll
    for (int tm=0;tm<2;++tm)
        #pragma unroll
        for (int tn=0;tn<8;++tn) acc[tm][tn] = (fv4){0.f,0.f,0.f,0.f};
    #pragma unroll
    for (int ks = 0; ks < 4; ++ks){
        bfv8 bfr[8];
        #pragma unroll
        for (int tn = 0; tn < 8; ++tn)
            bfr[tn] = *reinterpret_cast<const bfv8*>(&sB[(tn*16 + ln)*136 + ks*32 + qd*8]);
        #pragma unroll
        for (int tm = 0; tm < 2; ++tm)
            #pragma unroll
            for (int tn = 0; tn < 8; ++tn)
                acc[tm][tn] = __builtin_amdgcn_mfma_f32_16x16x32_bf16(af[tm][ks], bfr[tn], acc[tm][tn], 0, 0, 0);
    }
    __syncthreads();
    // C -> LDS (reuse sB): C[row][col], row stride 136; C/D map row=qd*4+r, col=ln
    #pragma unroll
    for (int tm = 0; tm < 2; ++tm)
        #pragma unroll
        for (int tn = 0; tn < 8; ++tn)
            #pragma unroll
            for (int rr = 0; rr < 4; ++rr){
                int row = wv*32 + tm*16 + qd*4 + rr;
                int col = tn*16 + ln;
                sB[row*136 + col] = f2us(acc[tm][tn][rr]);
            }
    __syncthreads();
    // pack (r,i) and write mixed[b][m][o] — 256B contiguous per (b,m), coalesced
    for (int idx = t; idx < 8192; idx += 256){
        int row = idx >> 6, o = idx & 63;
        unsigned int pr = ((unsigned int)sB[row*136 + o]) |
                          (((unsigned int)sB[row*136 + o + 64]) << 16);
        mixed[((size_t)(b0 + row)*288 + m)*64 + o] = pr;
    }
}

// ---------------- pointwise 64x64 channel GEMM (wc path) as MFMA, IN PLACE ---
// grid 1280: b = blk&255, u = blk>>8 (5 px-chunks of 240; chunks of same b
// co-XCD: ids differ by 256). C[240px][64o] = A[240px][64c] x w[o][c]^T + bias.
// Per-chunk in-place: block reads/writes only its own px range (disjoint).
__global__ __launch_bounds__(256) void k_wc(bf16* __restrict__ h,
                                            const void* __restrict__ wc_w,
                                            const void* __restrict__ wc_b,
                                            int layer,
                                            const float* __restrict__ flg){
    __shared__ unsigned short sA[240*72];   // A[p][c], stride 72; reused as sC[64][240]
    __shared__ unsigned short sBT[64*72];   // BT[o][c], stride 72
    __shared__ float sb[64];
    const bool f32 = (flg[0] > 0.5f);
    int blk = blockIdx.x;
    int b = blk & 255, u = blk >> 8;
    int px0 = u*240;
    int npx = 1156 - px0; if (npx > 240) npx = 240;   // 240 or 196
    int ndp = npx >> 1;                                // 120 or 98
    int t = threadIdx.x;
    size_t wbase = (size_t)layer*4096;
    for (int i = t; i < 4096; i += 256){               // wc_w[l][o][c] -> BT[o][c]
        int o = i >> 6, c = i & 63;
        sBT[o*72 + c] = f2us(rdf(wc_w, wbase + i, f32));
    }
    if (t < 64) sb[t] = rdf(wc_b, layer*64 + t, f32);
    // stage A transposed: dword-granular reads of h (always bf16 workspace)
    const unsigned int* srcd = (const unsigned int*)(h + (size_t)b*73984);
    for (int i = t; i < 7680; i += 256){
        int c = i / 120, dp = i - c*120;
        unsigned int v = (dp < ndp) ? srcd[c*578 + (px0 >> 1) + dp] : 0u;
        sA[(2*dp)*72 + c]     = (unsigned short)(v & 0xffff);
        sA[(2*dp + 1)*72 + c] = (unsigned short)(v >> 16);
    }
    __syncthreads();
    int ln = t & 15, qd = (t & 63) >> 4, wv = t >> 6;
    bfv8 bfr[4][2];
    #pragma unroll
    for (int nt = 0; nt < 4; ++nt)
        #pragma unroll
        for (int ks = 0; ks < 2; ++ks)
            bfr[nt][ks] = *reinterpret_cast<const bfv8*>(&sBT[(nt*16 + ln)*72 + ks*32 + qd*8]);
    // 15 m-tiles: wave wv handles mt = wv + 4*mi (mi<4, skip mt>=15)
    bfv8 a_[4][2];
    #pragma unroll
    for (int mi = 0; mi < 4; ++mi){
        int mt = wv + mi*4;
        if (mt < 15){
            a_[mi][0] = *reinterpret_cast<const bfv8*>(&sA[(mt*16 + ln)*72 + qd*8]);
            a_[mi][1] = *reinterpret_cast<const bfv8*>(&sA[(mt*16 + ln)*72 + 32 + qd*8]);
        }
    }
    fv4 acc[4][4];
    #pragma unroll
    for (int mi = 0; mi < 4; ++mi){
        int mt = wv + mi*4;
        if (mt < 15){
            #pragma unroll
            for (int nt = 0; nt < 4; ++nt){
                fv4 a = (fv4){0.f,0.f,0.f,0.f};
                a = __builtin_amdgcn_mfma_f32_16x16x32_bf16(a_[mi][0], bfr[nt][0], a, 0, 0, 0);
                a = __builtin_amdgcn_mfma_f32_16x16x32_bf16(a_[mi][1], bfr[nt][1], a, 0, 0, 0);
                acc[mi][nt] = a;
            }
        }
    }
    __syncthreads();
    // C -> sC[o][240] (transpose back), bias added
    unsigned int* sCd = (unsigned int*)sA;   // [o][120 dw]
    #pragma unroll
    for (int mi = 0; mi < 4; ++mi){
        int mt = wv + mi*4;
        if (mt < 15){
            #pragma unroll
            for (int nt = 0; nt < 4; ++nt){
                int o = nt*16 + ln;
                float bb = sb[o];
                int p0 = mt*16 + qd*4;
                sCd[o*120 + (p0 >> 1)]     = packbf2(acc[mi][nt][0] + bb, acc[mi][nt][1] + bb);
                sCd[o*120 + (p0 >> 1) + 1] = packbf2(acc[mi][nt][2] + bb, acc[mi][nt][3] + bb);
            }
        }
    }
    __syncthreads();
    // coalesced in-place writeback (own px range only)
    unsigned int* dstd = (unsigned int*)(h + (size_t)b*73984);
    for (int i = t; i < 7680; i += 256){
        int o = i / 120, dp = i - o*120;
        if (dp < ndp) dstd[o*578 + (px0 >> 1) + dp] = sCd[o*120 + dp];
    }
}

// ---------------- inverse truncated DFT as MFMA GEMMs; in-place add + gelu ---
// grid 4096 = 256 b x 16 o-groups of 4, XCD line-mate swizzled:
//   B = z*32 + s*8 + x  ->  b = (z>>2)*8 + x, og = (z&3)*4 + s
//   og-quads of the same b (which share each 64B line of mixed) land on the
//   same XCD (ids differ by 8/16/24) -> line fetched once into that L2.
// B operands (invBT/invW2) are read DIRECTLY from global images (L2-resident,
// fragment-ready layout); OOB rows give garbage discarded by col/y predicates.
// LDS 36.9 KB -> 4 blocks/CU.
__global__ __launch_bounds__(256) void k_invm(const unsigned int* __restrict__ mixed,
                                              const float* __restrict__ tabs,
                                              bf16* __restrict__ hio, int layer){
    __shared__ unsigned short lds[18448];   // 36,896 B total
    unsigned short* sA  = lds;              // 96*40 (step A only; overlaps htile)
    unsigned short* sG  = lds + 4624;       // 4*48*72 (htile = lds[0..4624))
    unsigned int* ldsw  = (unsigned int*)lds;
    int B = blockIdx.x;
    int x8 = B & 7, s4 = (B >> 3) & 3, z = B >> 5;
    int b  = (z >> 2)*8 + x8;
    int o0 = ((z & 3)*4 + s4)*4;
    int t = threadIdx.x;
    const unsigned short* gBT16 = (const unsigned short*)(tabs + 2448);  // [n][32 u16]
    const unsigned short* gW216 = (const unsigned short*)(tabs + 3536);  // [y][64 u16]
    // sA from mixed[b][m][o]: 16B per (m), stride 256B (lines shared intra-XCD)
    const unsigned int* msrc = mixed + (size_t)b*18432 + o0;
    for (int i = t; i < 1152; i += 256){
        int m = i >> 2, ch = i & 3;
        int kyi = m / 12, kx = m - kyi*12;
        ((unsigned int*)sA)[(ch*24 + kyi)*20 + kx] = msrc[(size_t)m*64 + ch];
    }
    for (int i = t; i < 384; i += 256)       // zero k 24..31 (dw 12..15)
        ((unsigned int*)sA)[(i >> 2)*20 + 12 + (i & 3)] = 0;
    // sG: zero only read pads — rows x in [34,48): dw 0..31; rows x<34: dw 24..31
    for (int i = t; i < 1792; i += 256){
        int r = i >> 5;
        int ch = r / 14, x = 34 + (r - (r/14)*14);
        ((unsigned int*)sG)[(ch*48 + x)*36 + (i & 31)] = 0;
    }
    for (int i = t; i < 1088; i += 256){
        int r = i >> 3;
        int ch = r / 34, x = r - (r/34)*34;
        ((unsigned int*)sG)[(ch*48 + x)*36 + 24 + (i & 7)] = 0;
    }
    __syncthreads();
    int ln = t & 15, qd = (t & 63) >> 4, wv = t >> 6;
    // ---- step A: 30 tiles (6 M x 5 N), K=32; B-frag direct from gBT image ----
    for (int tau = wv; tau < 30; tau += 4){
        int mt = tau / 5, nt = tau - mt*5;
        bfv8 a  = *reinterpret_cast<const bfv8*>(&sA[(mt*16 + ln)*40 + qd*8]);
        bfv8 bb = *reinterpret_cast<const bfv8*>(&gBT16[(nt*16 + ln)*32 + qd*8]);
        fv4 acc = (fv4){0.f,0.f,0.f,0.f};
        acc = __builtin_amdgcn_mfma_f32_16x16x32_bf16(a, bb, acc, 0, 0, 0);
        int col = nt*16 + ln;
        if (col < 68){
            int x = col >> 1, ri = col & 1;
            #pragma unroll
            for (int rr = 0; rr < 4; ++rr){
                int row = mt*16 + qd*4 + rr;
                int ch = row / 24, kyi = row - ch*24;
                sG[(ch*48 + x)*72 + 2*kyi + ri] = f2us(acc[rr]);
            }
        }
    }
    __syncthreads();
    // ---- stage htile (4 contiguous ch-planes) into lds[0..2312) dwords ----
    const unsigned int* hsrc = (const unsigned int*)(hio + (size_t)b*73984 + (size_t)o0*1156);
    for (int i = t; i < 2312; i += 256) ldsw[i] = hsrc[i];
    __syncthreads();
    // ---- step B: wave = ch; 3x3 tiles, K=64 (2 MFMAs); A-frag direct from gW2 ----
    int ch = wv;
    #pragma unroll
    for (int mt = 0; mt < 3; ++mt){
        bfv8 a0 = *reinterpret_cast<const bfv8*>(&gW216[(mt*16 + ln)*64 + qd*8]);
        bfv8 a1 = *reinterpret_cast<const bfv8*>(&gW216[(mt*16 + ln)*64 + 32 + qd*8]);
        #pragma unroll
        for (int nt = 0; nt < 3; ++nt){
            bfv8 b0 = *reinterpret_cast<const bfv8*>(&sG[(ch*48 + nt*16 + ln)*72 + qd*8]);
            bfv8 b1 = *reinterpret_cast<const bfv8*>(&sG[(ch*48 + nt*16 + ln)*72 + 32 + qd*8]);
            fv4 acc = (fv4){0.f,0.f,0.f,0.f};
            acc = __builtin_amdgcn_mfma_f32_16x16x32_bf16(a0, b0, acc, 0, 0, 0);
            acc = __builtin_amdgcn_mfma_f32_16x16x32_bf16(a1, b1, acc, 0, 0, 0);
            int x = nt*16 + ln;
            if (x < 34){
                #pragma unroll
                for (int rr = 0; rr < 4; ++rr){
                    int y = mt*16 + qd*4 + rr;
                    if (y < 34){
                        int off = ch*1156 + y*34 + x;
                        float v = acc[rr] + us2f(lds[off]);
                        if (layer < 3) v = gelu_f(v);
                        lds[off] = f2us(v);
                    }
                }
            }
        }
    }
    __syncthreads();
    // ---- coalesced dword writeback ----
    unsigned int* hdst = (unsigned int*)(hio + (size_t)b*73984 + (size_t)o0*1156);
    for (int i = t; i < 2312; i += 256) hdst[i] = ldsw[i];
}

// ---------------- 8x8/stride4 VALID conv -> gelu -> pe2 scale ----------------
__global__ __launch_bounds__(256) void k_pe(const bf16* __restrict__ h,
                                            const void* __restrict__ pw,
                                            const void* __restrict__ pb,
                                            const void* __restrict__ p2w,
                                            const void* __restrict__ p2b,
                                            float* __restrict__ p49,
                                            const float* __restrict__ flg){
    __shared__ float red[256];
    const bool f32 = (flg[0] > 0.5f);
    int bid = blockIdx.x;          // b*49 + py*7 + px
    int b = bid / 49, r = bid - b*49;
    int py = r / 7, px = r - py*7;
    int t = threadIdx.x;
    const bf16* hb = h + (size_t)b*73984 + (py*4)*34 + px*4;
    float partial = 0.f;
    for (int tt = t; tt < 4096; tt += 256){
        int c = tt >> 6, k = tt & 63, ky = k >> 3, kx = k & 7;
        partial += bff(hb[(size_t)c*1156 + ky*34 + kx]) * rdf(pw, tt, f32);
    }
    red[t] = partial;
    __syncthreads();
    for (int s = 128; s > 0; s >>= 1){
        if (t < s) red[t] += red[t + s];
        __syncthreads();
    }
    if (t == 0){
        float v = red[0] + rdf(pb, 0, f32);
        v = gelu_f(v);
        p49[bid] = v * rdf(p2w, 0, f32) + rdf(p2b, 0, f32);
    }
}

// ---------------- sentence MLP 384->32->32->16 (relu,relu,lin) ---------------
__global__ __launch_bounds__(64) void k_sent(const void* __restrict__ se,
                                             const void* __restrict__ w1, const void* __restrict__ b1,
                                             const void* __restrict__ w2, const void* __restrict__ b2,
                                             const void* __restrict__ w3, const void* __restrict__ b3,
                                             float* __restrict__ outv,
                                             const float* __restrict__ flg){
    __shared__ float s1[32], s2[32];
    const bool f32 = (flg[0] > 0.5f);
    int b = blockIdx.x, t = threadIdx.x;
    if (t < 32){
        float acc = rdf(b1, t, f32);
        size_t rbase = (size_t)b*384;
        for (int k = 0; k < 384; ++k) acc += rdf(se, rbase + k, f32) * rdf(w1, k*32 + t, f32);
        s1[t] = fmaxf(acc, 0.f);
    }
    __syncthreads();
    if (t < 32){
        float acc = rdf(b2, t, f32);
        for (int k = 0; k < 32; ++k) acc += s1[k] * rdf(w2, k*32 + t, f32);
        s2[t] = fmaxf(acc, 0.f);
    }
    __syncthreads();
    if (t < 16){
        float acc = rdf(b3, t, f32);
        for (int k = 0; k < 32; ++k) acc += s2[k] * rdf(w3, k*16 + t, f32);
        outv[b*16 + t] = acc;
    }
}

// ---------------- xp MLP 49->32->32->16 (silu,silu,lin) ----------------------
__global__ __launch_bounds__(64) void k_xp(const float* __restrict__ p49,
                                           const void* __restrict__ w1, const void* __restrict__ b1,
                                           const void* __restrict__ w2, const void* __restrict__ b2,
                                           const void* __restrict__ w3, const void* __restrict__ b3,
                                           float* __restrict__ outv,
                                           const float* __restrict__ flg){
    __shared__ float s1[32], s2[32];
    const bool f32 = (flg[0] > 0.5f);
    int b = blockIdx.x, t = threadIdx.x;
    if (t < 32){
        float acc = rdf(b1, t, f32);
        const float* row = p49 + b*49;
        for (int k = 0; k < 49; ++k) acc += row[k] * rdf(w1, k*32 + t, f32);
        s1[t] = silu_f(acc);
    }
    __syncthreads();
    if (t < 32){
        float acc = rdf(b2, t, f32);
        for (int k = 0; k < 32; ++k) acc += s1[k] * rdf(w2, k*32 + t, f32);
        s2[t] = silu_f(acc);
    }
    __syncthreads();
    if (t < 16){
        float acc = rdf(b3, t, f32);
        for (int k = 0; k < 32; ++k) acc += s2[k] * rdf(w3, k*16 + t, f32);
        outv[b*16 + t] = acc;
    }
}

// ---------------- pu MLP part A: 32->128->256 (silu,silu) --------------------
__global__ __launch_bounds__(256) void k_puA(const float* __restrict__ xemb,
                                             const float* __restrict__ semb,
                                             const void* __restrict__ w1, const void* __restrict__ b1,
                                             const void* __restrict__ w2, const void* __restrict__ b2,
                                             float* __restrict__ h2buf,
                                             const float* __restrict__ flg){
    __shared__ float ein[32];
    __shared__ float h1[128];
    const bool f32 = (flg[0] > 0.5f);
    int b = blockIdx.x, t = threadIdx.x;
    if (t < 16) ein[t] = xemb[b*16 + t];
    else if (t < 32) ein[t] = semb[b*16 + (t - 16)];
    __syncthreads();
    if (t < 128){
        float acc = rdf(b1, t, f32);
        for (int k = 0; k < 32; ++k) acc += ein[k] * rdf(w1, k*128 + t, f32);
        h1[t] = silu_f(acc);
    }
    __syncthreads();
    {
        float acc = rdf(b2, t, f32);
        for (int k = 0; k < 128; ++k) acc += h1[k] * rdf(w2, k*256 + t, f32);
        h2buf[(size_t)b*256 + t] = silu_f(acc);
    }
}

// ---------------- pu MLP part B: 256->1156 GEMM ------------------------------
// grid 1280 = 256 b (fast) x 5 n-chunks of 232
__global__ __launch_bounds__(256) void k_puB(const float* __restrict__ h2buf,
                                             const void* __restrict__ w3, const void* __restrict__ b3,
                                             float* __restrict__ emb,
                                             const float* __restrict__ flg){
    __shared__ float sh2[256];
    const bool f32 = (flg[0] > 0.5f);
    int blk = blockIdx.x;
    int b = blk & 255, nc = blk >> 8;
    int t = threadIdx.x;
    sh2[t] = h2buf[(size_t)b*256 + t];
    __syncthreads();
    int e = nc*232 + t;
    if (t < 232 && e < 1156){
        float acc = rdf(b3, e, f32);
        if (f32){
            const float* wp = (const float*)w3 + e;
            #pragma unroll 4
            for (int k = 0; k < 256; ++k) acc += sh2[k] * wp[(size_t)k*1156];
        } else {
            const bf16* wp = (const bf16*)w3 + e;
            #pragma unroll 4
            for (int k = 0; k < 256; ++k) acc += sh2[k] * bff(wp[(size_t)k*1156]);
        }
        emb[(size_t)b*1156 + e] = acc;
    }
}

// ---------------- final: crop, concat emb, fc1(MFMA)+gelu, fc2(MFMA) ---------
// grid 512 = 256 b x 2 halves; 8 iters of 2 rows (64 px).
// fc1: C[64px,128j] = A[px,c<64] x w1 (K=64) + rank-1 emb add; fc2: K=128, N=16(4)
__global__ __launch_bounds__(256, 3) void k_final(const bf16* __restrict__ h,
                                                  const float* __restrict__ emb,
                                                  const void* __restrict__ w1, const void* __restrict__ b1,
                                                  const void* __restrict__ w2, const void* __restrict__ b2,
                                                  void* __restrict__ out,
                                                  const float* __restrict__ flg){
    __shared__ unsigned short sw1t[128*72];   // w1T[j][c], stride 72 (16B-aligned rows)
    __shared__ unsigned short sw2t[16*136];   // w2T[n][j], rows 4..15 zero
    __shared__ float sw1e[128];               // w1[64][j] (emb channel)
    __shared__ float sb1[128];
    __shared__ float sb2[4];
    __shared__ unsigned short spx[64*66];     // input[c][px], stride 66 (odd dwords)
    __shared__ float sembp[64];               // emb[px]
    __shared__ unsigned short sh2[128*66];    // hid[j][px], stride 66
    const bool f32 = (flg[0] > 0.5f);
    int blk = blockIdx.x;
    int b = blk >> 1, half = blk & 1;
    int t = threadIdx.x;
    for (int i = t; i < 8320; i += 256){       // w1 [c=65][j=128]
        int c = i >> 7, j = i & 127;
        float v = rdf(w1, i, f32);
        if (c < 64) sw1t[j*72 + c] = f2us(v);
        else sw1e[j] = v;
    }
    if (t < 128) sb1[t] = rdf(b1, t, f32);
    for (int i = t; i < 2176; i += 256){       // w2 [j=128][k=4] -> w2T[n][j]
        int n = i / 136, j = i - n*136;
        float v = (n < 4 && j < 128) ? rdf(w2, j*4 + n, f32) : 0.f;
        sw2t[i] = f2us(v);
    }
    if (t < 4) sb2[t] = rdf(b2, t, f32);
    __syncthreads();
    int ln = t & 15, qd = (t & 63) >> 4, wv = t >> 6;
    // hoist B fragments (weights) into registers
    bfv8 bw1[8][2];
    #pragma unroll
    for (int tn = 0; tn < 8; ++tn)
        #pragma unroll
        for (int ks = 0; ks < 2; ++ks)
            bw1[tn][ks] = *reinterpret_cast<const bfv8*>(&sw1t[(tn*16 + ln)*72 + ks*32 + qd*8]);
    bfv8 bw2[4];
    #pragma unroll
    for (int ks = 0; ks < 4; ++ks)
        bw2[ks] = *reinterpret_cast<const bfv8*>(&sw2t[ln*136 + ks*32 + qd*8]);
    const bf16* hb = h + (size_t)b*73984;
    const float* eb = emb + (size_t)b*1156;
    for (int it = 0; it < 8; ++it){
        int y0 = half*16 + it*2;               // 2 rows = 64 px
        __syncthreads();
        for (int e = t; e < 2048; e += 256){   // stage spx[c][px] c-major
            int c = e >> 5, d = e & 31;
            int px = d*2;
            int y = y0 + (px >> 5), x = px & 31;
            float v0 = bff(hb[(size_t)c*1156 + y*34 + x]);
            int px1 = px + 1;
            int y1 = y0 + (px1 >> 5), x1 = px1 & 31;
            float v1 = bff(hb[(size_t)c*1156 + y1*34 + x1]);
            ((unsigned int*)spx)[c*33 + d] = packbf2(v0, v1);
        }
        if (t < 64){
            int y = y0 + (t >> 5), x = t & 31;
            sembp[t] = eb[y*34 + x];
        }
        __syncthreads();
        // fc1 MFMA: wave wv owns mtile wv (px = wv*16 + ...)
        fv4 acc[8];
        #pragma unroll
        for (int tn = 0; tn < 8; ++tn) acc[tn] = (fv4){0.f,0.f,0.f,0.f};
        #pragma unroll
        for (int ks = 0; ks < 2; ++ks){
            union { bfv8 v; unsigned short s[8]; } af;
            #pragma unroll
            for (int j = 0; j < 8; ++j)
                af.s[j] = spx[(ks*32 + qd*8 + j)*66 + wv*16 + ln];
            #pragma unroll
            for (int tn = 0; tn < 8; ++tn)
                acc[tn] = __builtin_amdgcn_mfma_f32_16x16x32_bf16(af.v, bw1[tn][ks], acc[tn], 0, 0, 0);
        }
        float ev[4];
        #pragma unroll
        for (int rr = 0; rr < 4; ++rr) ev[rr] = sembp[wv*16 + qd*4 + rr];
        #pragma unroll
        for (int tn = 0; tn < 8; ++tn){
            int col = tn*16 + ln;
            float we = sw1e[col];
            float bb1 = sb1[col];
            #pragma unroll
            for (int rr = 0; rr < 4; ++rr){
                float v = acc[tn][rr] + ev[rr]*we + bb1;
                sh2[col*66 + wv*16 + qd*4 + rr] = f2us(gelu_f(v));
            }
        }
        __syncthreads();
        // fc2 MFMA: K=128, N=16 (4 valid)
        fv4 a2 = (fv4){0.f,0.f,0.f,0.f};
        #pragma unroll
        for (int ks = 0; ks < 4; ++ks){
            union { bfv8 v; unsigned short s[8]; } af;
            #pragma unroll
            for (int j = 0; j < 8; ++j)
                af.s[j] = sh2[(ks*32 + qd*8 + j)*66 + wv*16 + ln];
            a2 = __builtin_amdgcn_mfma_f32_16x16x32_bf16(af.v, bw2[ks], a2, 0, 0, 0);
        }
        if (ln < 4){
            float bb2 = sb2[ln];
            #pragma unroll
            for (int rr = 0; rr < 4; ++rr){
                int pxl = wv*16 + qd*4 + rr;
                int y = y0 + (pxl >> 5), x = pxl & 31;
                size_t o = ((size_t)(b*32 + y)*32 + x)*4 + ln;
                float v = a2[rr] + bb2;
                if (f32) ((float*)out)[o] = v;
                else     ((bf16*)out)[o] = __float2bfloat16(v);
            }
        }
    }
}

extern "C" void kernel_launch(void* const* d_in, const int* in_sizes, int n_in,
                              void* d_out, int out_size, void* d_ws, size_t ws_size,
                              hipStream_t stream) {
    (void)in_sizes; (void)n_in; (void)out_size; (void)ws_size;
    const void* x     = d_in[0];
    const void* grd   = d_in[1];
    const void* se    = d_in[2];
    const void* fc0_w = d_in[3];
    const void* fc0_b = d_in[4];
    const void* sc_w1 = d_in[5];
    const void* sc_w2 = d_in[6];
    const void* wc_w  = d_in[7];
    const void* wc_b  = d_in[8];
    const void* pe1_w = d_in[9];
    const void* pe1_b = d_in[10];
    const void* pe2_w = d_in[11];
    const void* pe2_b = d_in[12];
    const void* sp_w1 = d_in[13];
    const void* sp_b1 = d_in[14];
    const void* sp_w2 = d_in[15];
    const void* sp_b2 = d_in[16];
    const void* sp_w3 = d_in[17];
    const void* sp_b3 = d_in[18];
    const void* xp_w1 = d_in[19];
    const void* xp_b1 = d_in[20];
    const void* xp_w2 = d_in[21];
    const void* xp_b2 = d_in[22];
    const void* xp_w3 = d_in[23];
    const void* xp_b3 = d_in[24];
    const void* pu_w1 = d_in[25];
    const void* pu_b1 = d_in[26];
    const void* pu_w2 = d_in[27];
    const void* pu_b2 = d_in[28];
    const void* pu_w3 = d_in[29];
    const void* pu_b3 = d_in[30];
    const void* fc1_w = d_in[31];
    const void* fc1_b = d_in[32];
    const void* fc2_w = d_in[33];
    const void* fc2_b = d_in[34];

    // workspace layout (float-unit offsets); total ~77 MB
    float* ws    = (float*)d_ws;
    bf16*  hA    = (bf16*)ws;                              // 18,939,904 bf16
    unsigned int* hft   = (unsigned int*)(ws + 9469952);   // 4,718,592 dwords (hft cg-panels)
    unsigned int* mixed = (unsigned int*)(ws + 14188544);  // 4,718,592 dwords ([b][m][o])
    float* tabs  = ws + 18907136;                          // 4,896 (DFT tables + inv images)
    float* p49   = ws + 18912032;                          // 12,544
    float* semb  = ws + 18924576;                          // 4,096
    float* xemb  = ws + 18928672;                          // 4,096
    float* emb   = ws + 18932768;                          // 295,936
    float* flag  = ws + 19228704;                          // 1
    float* h2buf = (float*)hft;                            // reuse: hft dead after layer loop

    k_probe<<<1, 256, 0, stream>>>(x, flag);
    k_tables<<<1, 256, 0, stream>>>(tabs);
    k_fc0<<<1024, 256, 0, stream>>>(x, grd, fc0_w, fc0_b, hA, flag);

    for (int l = 0; l < 4; ++l){
        k_fwd<<<4096, 256, 0, stream>>>(hA, hft, tabs);
        k_mixm<<<576, 256, 0, stream>>>((const unsigned short*)hft, sc_w1, sc_w2, mixed, l, flag);
        k_wc <<<1280, 256, 0, stream>>>(hA, wc_w, wc_b, l, flag);
        k_invm<<<4096, 256, 0, stream>>>(mixed, tabs, hA, l);
    }

    k_pe  <<<256*49, 256, 0, stream>>>(hA, pe1_w, pe1_b, pe2_w, pe2_b, p49, flag);
    k_sent<<<256, 64, 0, stream>>>(se, sp_w1, sp_b1, sp_w2, sp_b2, sp_w3, sp_b3, semb, flag);
    k_xp  <<<256, 64, 0, stream>>>(p49, xp_w1, xp_b1, xp_w2, xp_b2, xp_w3, xp_b3, xemb, flag);
    k_puA <<<256, 256, 0, stream>>>(xemb, semb, pu_w1, pu_b1, pu_w2, pu_b2, h2buf, flag);
    k_puB <<<1280, 256, 0, stream>>>(h2buf, pu_w3, pu_b3, emb, flag);
    k_final<<<512, 256, 0, stream>>>(hA, emb, fc1_w, fc1_b, fc2_w, fc2_b, d_out, flag);
}

// Round 6
// 1164.521 us; speedup vs baseline: 1.2152x; 1.1383x over previous
//
#include <hip/hip_runtime.h>
#include <hip/hip_bf16.h>
#include <math.h>

typedef __hip_bfloat16 bf16;
typedef __bf16 bfv8 __attribute__((ext_vector_type(8)));
typedef float fv4 __attribute__((ext_vector_type(4)));

__device__ __forceinline__ float bff(const bf16 x){ return __bfloat162float(x); }
__device__ __forceinline__ float gelu_f(float v){
    return 0.5f * v * (1.f + erff(v * 0.70710678118654752f));
}
__device__ __forceinline__ float silu_f(float v){
    return v / (1.f + expf(-v));
}
// dtype-agnostic input read: f32 ? fp32 : bf16
__device__ __forceinline__ float rdf(const void* p, size_t i, bool f32){
    return f32 ? ((const float*)p)[i] : __bfloat162float(((const bf16*)p)[i]);
}
__device__ __forceinline__ unsigned int packbf2(float a, float b){
    __hip_bfloat162 v;
    v.x = __float2bfloat16(a);
    v.y = __float2bfloat16(b);
    return *reinterpret_cast<unsigned int*>(&v);
}
__device__ __forceinline__ float2 unpackbf2(unsigned int u){
    __hip_bfloat162 v = *reinterpret_cast<__hip_bfloat162*>(&u);
    return make_float2(__bfloat162float(v.x), __bfloat162float(v.y));
}
__device__ __forceinline__ float us2f(unsigned short u){
    unsigned int x = ((unsigned int)u) << 16;
    return __uint_as_float(x);
}
__device__ __forceinline__ unsigned short f2us(float f){
    bf16 v = __float2bfloat16(f);
    return *reinterpret_cast<unsigned short*>(&v);
}

// Geometry
// B=256, C=64, H=W=34 (padded), modes: ky in {0..11, 22..33} (24), kx in 0..11 (12)
// h layout (ws, bf16): [b][c][y][x], stride c = 1156, stride b = 73984
// hft layout: [cg<16][b<256][m<288][8 bf16] ; kappa = cg*8+u, u<4: Re(c=cg*4+u),
//             u>=4: Im(c=cg*4+u-4).  Writer (k_fwd) fully coalesced per block.
// mixed layout: [b<256][m<288][o<64] packed bf16x2 dwords (r,i); writer (k_mixm)
//             owns full 256B rows per (b,m).
// tabs: [0,1632) Wfy f32 | [1632,2448) Wfx f32 |
//       [2448,3536) invBT bf16 image (68x16 dw) | [3536,4624) invW2 bf16 image (34x32 dw)
// fwd images (in emb region, dead during layer loop):
//       gB1 [row<32][64 u16] (row=2kx+s, k=x) | gB2 [row<48][96 u16] (row=2ky+s, kk=2y+p)
// All images fragment-ready: k_fwd/k_invm read MFMA fragments DIRECTLY from global
// (16B-aligned rows, pads pre-zeroed; OOB rows discarded by predicates).

// ---------------- dtype probe ----------------
__global__ __launch_bounds__(256) void k_probe(const void* x, float* flag){
    __shared__ int wild;
    int t = threadIdx.x;
    if (t == 0) wild = 0;
    __syncthreads();
    const bf16* xb = (const bf16*)x;
    for (int i = t; i < 1024; i += 256){
        float v = bff(xb[i]);
        if (!(fabsf(v) < 1e10f)) wild = 1;
    }
    __syncthreads();
    if (t == 0) flag[0] = wild ? 1.f : 0.f;
}

// ---------------- tables ----------------
__global__ __launch_bounds__(256) void k_tables(float* tabs, float* fwdimg){
    int t = threadIdx.x;
    unsigned int* gBT = (unsigned int*)(tabs + 2448);   // [n<68][kd<16] bf16x2
    unsigned int* gW2 = (unsigned int*)(tabs + 3536);   // [y<34][kd<32] bf16x2
    unsigned short* gB1 = (unsigned short*)fwdimg;          // [row<32][64]
    unsigned short* gB2 = (unsigned short*)(fwdimg + 1024); // [row<48][96]
    const float TWO_PI = 6.283185307179586f;
    // gB1: row=2kx+s (kx<12), k=x<34: e^{-i ang} component (s=0: cos, s=1: -sin)
    for (int i = t; i < 2048; i += 256){
        int row = i >> 6, k = i & 63;
        float v = 0.f;
        if (row < 24 && k < 34){
            int kx = row >> 1, s = row & 1;
            int ph = (kx * k) % 34;
            float ang = TWO_PI * (float)ph / 34.0f;
            float sn, cs;
            sincosf(ang, &sn, &cs);
            v = (s == 0) ? cs : -sn;
        }
        gB1[i] = f2us(v);
    }
    // gB2: row=2ky+s (kyi<24), kk=2y+p<68: realified [[wr,-wi],[wi,wr]] of e^{-i ang}
    for (int i = t; i < 4608; i += 256){
        int row = i / 96, kk = i - row*96;
        float v = 0.f;
        if (kk < 68){
            int kyi = row >> 1, s = row & 1;
            int y = kk >> 1, p = kk & 1;
            int ky = (kyi < 12) ? kyi : kyi + 10;
            int ph = (ky * y) % 34;
            float ang = TWO_PI * (float)ph / 34.0f;
            float sn, cs;
            sincosf(ang, &sn, &cs);
            float wr = cs, wi = -sn;
            v = (s == 0) ? ((p == 0) ? wr : -wi) : ((p == 0) ? wi : wr);
        }
        gB2[i] = f2us(v);
    }
    // invBT image: n=2x+ri (x<34), k=2kx+ri2; v = ri==0 ? (ri2==0? C : -S) : (ri2==0? S : C)
    // where C = ck*cos(ang), S = ck*sin(ang), ang = +2pi*(kx*x mod 34)/34, ck = (kx==0?1:2)
    for (int i = t; i < 1088; i += 256){
        int n = i >> 4, kd = i & 15;
        int x = n >> 1, ri = n & 1;
        int kx = kd;
        float v0 = 0.f, v1 = 0.f;
        if (kx < 12){
            int ph = (kx * x) % 34;
            float ang = TWO_PI * (float)ph / 34.0f;
            float s, c;
            sincosf(ang, &s, &c);
            float ck = (kx == 0) ? 1.0f : 2.0f;
            float C = ck * c, S = ck * s;
            v0 = (ri == 0) ? C : S;       // ri2 = 0
            v1 = (ri == 0) ? -S : C;      // ri2 = 1
        }
        gBT[i] = packbf2(v0, v1);
    }
    // invW2 image: y<34, k=2kyi+ri; v = (1/1156)*(ri==0? cos : -sin), ang=+2pi*(ky*y mod 34)/34
    for (int i = t; i < 1088; i += 256){
        int y = i >> 5, kd = i & 31;
        int kyi = kd;
        float v0 = 0.f, v1 = 0.f;
        if (kyi < 24){
            int ky = (kyi < 12) ? kyi : kyi + 10;
            int ph = (ky * y) % 34;
            float ang = TWO_PI * (float)ph / 34.0f;
            float s, c;
            sincosf(ang, &s, &c);
            v0 = c * (1.0f/1156.0f);
            v1 = -s * (1.0f/1156.0f);
        }
        gW2[i] = packbf2(v0, v1);
    }
}

// ---------------- fc0 as MFMA GEMM: concat(x,grid) @ fc0_w + b ---------------
// grid 1024: B -> b = (B>>5)*8 + (B&7), q = (B>>3)&3  (4 quarters of b co-XCD)
// Block: px in [q*256, q*256+256); C[256px][64c], K=42 pad 64.
// Epilogue: C transposed into LDS sC[c][8rows x 34] image (x-pads zeroed),
// then fully-coalesced dword writeback of the block-owned 544B run per c-plane.
__global__ __launch_bounds__(256) void k_fc0(const void* __restrict__ xin,
                                             const void* __restrict__ grd,
                                             const void* __restrict__ w,
                                             const void* __restrict__ bias,
                                             bf16* __restrict__ h,
                                             const float* __restrict__ flg){
    __shared__ unsigned short sA[256*72];   // A[px][k], stride 72 u16; reused as sC[64][272]
    __shared__ unsigned short sBT[64*72];   // BT[c][k], stride 72
    __shared__ float sb[64];
    const bool f32 = (flg[0] > 0.5f);
    int B = blockIdx.x;
    int b = (B >> 5)*8 + (B & 7);
    int q = (B >> 3) & 3;
    int t = threadIdx.x;
    // stage BT[c][k]: w is [k=42][c=64]; k 42..63 zero
    for (int i = t; i < 4096; i += 256){
        int k = i >> 6, c = i & 63;
        sBT[c*72 + k] = f2us((k < 42) ? rdf(w, (size_t)k*64 + c, f32) : 0.f);
    }
    if (t < 64) sb[t] = rdf(bias, t, f32);
    // stage A: x rows (k<40), grid (k 40,41), zero k 42..63
    size_t xbase = ((size_t)b*1024 + q*256)*40;
    for (int i = t; i < 10240; i += 256){
        int p = i / 40, k = i - p*40;
        sA[p*72 + k] = f2us(rdf(xin, xbase + i, f32));
    }
    size_t gbase = ((size_t)b*1024 + q*256)*2;
    for (int i = t; i < 512; i += 256)
        sA[(i >> 1)*72 + 40 + (i & 1)] = f2us(rdf(grd, gbase + i, f32));
    for (int i = t; i < 5632; i += 256){
        int p = i / 22, k = 42 + (i - p*22);
        sA[p*72 + k] = 0;
    }
    __syncthreads();
    int ln = t & 15, qd = (t & 63) >> 4, wv = t >> 6;
    // ---- phase 1: all frags + MFMA in registers (sA still live) ----
    bfv8 bfr[4][2];
    #pragma unroll
    for (int nt = 0; nt < 4; ++nt)
        #pragma unroll
        for (int ks = 0; ks < 2; ++ks)
            bfr[nt][ks] = *reinterpret_cast<const bfv8*>(&sBT[(nt*16 + ln)*72 + ks*32 + qd*8]);
    bfv8 a_[4][2];
    #pragma unroll
    for (int mi = 0; mi < 4; ++mi){
        int mt = wv*4 + mi;
        a_[mi][0] = *reinterpret_cast<const bfv8*>(&sA[(mt*16 + ln)*72 + qd*8]);
        a_[mi][1] = *reinterpret_cast<const bfv8*>(&sA[(mt*16 + ln)*72 + 32 + qd*8]);
    }
    fv4 acc[4][4];
    #pragma unroll
    for (int mi = 0; mi < 4; ++mi)
        #pragma unroll
        for (int nt = 0; nt < 4; ++nt){
            fv4 a = (fv4){0.f,0.f,0.f,0.f};
            a = __builtin_amdgcn_mfma_f32_16x16x32_bf16(a_[mi][0], bfr[nt][0], a, 0, 0, 0);
            a = __builtin_amdgcn_mfma_f32_16x16x32_bf16(a_[mi][1], bfr[nt][1], a, 0, 0, 0);
            acc[mi][nt] = a;
        }
    __syncthreads();
    // ---- phase 2: C -> sC[c][272] (8 rows x 34, x-pads zeroed) ----
    unsigned int* sCd = (unsigned int*)sA;   // [c][136 dw]
    for (int i = t; i < 512; i += 256)       // zero x=32,33 pad dword per (c,row)
        sCd[(i >> 3)*136 + (i & 7)*17 + 16] = 0;
    #pragma unroll
    for (int mi = 0; mi < 4; ++mi)
        #pragma unroll
        for (int nt = 0; nt < 4; ++nt){
            int c = nt*16 + ln;
            float bb = sb[c];
            int pl = (wv*4 + mi)*16 + qd*4;   // local px, 4 consecutive, same row
            int y = pl >> 5, x = pl & 31;
            int di = c*136 + y*17 + (x >> 1);
            sCd[di]     = packbf2(acc[mi][nt][0] + bb, acc[mi][nt][1] + bb);
            sCd[di + 1] = packbf2(acc[mi][nt][2] + bb, acc[mi][nt][3] + bb);
        }
    __syncthreads();
    // ---- phase 3: coalesced writeback of block-owned runs ----
    unsigned int* hw = (unsigned int*)(h + (size_t)b*73984);
    for (int i = t; i < 8704; i += 256){
        int c = i / 136, d = i - c*136;
        hw[c*578 + q*136 + d] = sCd[i];
    }
    if (q == 3){                              // rows y=32,33 zero (full pad rows)
        for (int i = t; i < 2176; i += 256){
            int c = i / 34, d = i - c*34;
            hw[c*578 + 544 + d] = 0;
        }
    }
}

// ---------------- forward truncated DFT via MFMA, 4 channels per block -------
// grid 4096 = 256 b x 16 ch-groups; writes hft [cg][b][m][8bf16] (coalesced)
// F1 (x-DFT): C1[(c,y)][2kx+s] = sum_x h[c][y][x] * gB1  (K=64, x pad)
// F2 (y-DFT): C2[(c,kx)][2ky+s] = sum_{2y+p} Gx * gB2    (K=96, pad)
// B operands read DIRECTLY from global images (L2-resident, fragment-ready) —
// no per-block image rebuild; LDS 30.7 KB -> 5 blocks/CU.
__global__ __launch_bounds__(256) void k_fwd(const bf16* __restrict__ h,
                                             unsigned int* __restrict__ hft,
                                             const unsigned short* __restrict__ fwdimg){
    __shared__ unsigned short lds[15360];   // 30,720 B
    unsigned short* sA1 = lds;              // 144 rows x 72 (rows=(c*34+y), k=x pad 64)
    unsigned short* sA2 = lds + 10368;      // 48 x 104 (rows=(c*12+kx), kappa=2y+p pad 96)
    unsigned int* sA1w = (unsigned int*)sA1;
    unsigned int* sA2w = (unsigned int*)sA2;
    const unsigned short* gB1 = fwdimg;          // [row<32][64 u16]
    const unsigned short* gB2 = fwdimg + 2048;   // [row<48][96 u16]
    int blk = blockIdx.x;
    int b = blk >> 4, c0 = (blk & 15) * 4;
    int t = threadIdx.x;
    // stage h (4 planes) into sA1 rows (c*34+y), dword granularity (coalesced)
    const unsigned int* srcp = (const unsigned int*)(h + (size_t)b*73984 + (size_t)c0*1156);
    for (int i = t; i < 2312; i += 256){
        int c = i / 578; int rem = i - c*578;
        int y = rem / 17; int d = rem - y*17;
        sA1w[(c*34 + y)*36 + d] = srcp[i];
    }
    // zero x-pad dwords 17..31 of rows 0..135
    for (int i = t; i < 2040; i += 256){
        int r = i / 15, d = i - r*15;
        sA1w[r*36 + 17 + d] = 0;
    }
    // zero tail rows 136..143 entirely
    for (int i = t; i < 288; i += 256){
        int r = 136 + i / 36, d = i - (i/36)*36;
        sA1w[r*36 + d] = 0;
    }
    // zero sA2 kappa pad [68,96) = dwords 34..47 of each row
    for (int i = t; i < 672; i += 256){
        int r = i / 14, d = i - r*14;
        sA2w[r*52 + 34 + d] = 0;
    }
    __syncthreads();
    int ln = t & 15, qd = (t & 63) >> 4, wv = t >> 6;
    // ---- F1: 9 M-tiles x 2 N-tiles, K=64; wave owns one nt (static frag idx) ----
    {
        int ntw = wv & 1;
        bfv8 b1f[2];
        #pragma unroll
        for (int ks = 0; ks < 2; ++ks)
            b1f[ks] = *reinterpret_cast<const bfv8*>(&gB1[(ntw*16 + ln)*64 + ks*32 + qd*8]);
        int col = ntw*16 + ln;
        int kx = col >> 1, s = col & 1;
        for (int mt = (wv >> 1); mt < 9; mt += 2){
            fv4 acc = (fv4){0.f,0.f,0.f,0.f};
            #pragma unroll
            for (int ks = 0; ks < 2; ++ks){
                bfv8 a = *reinterpret_cast<const bfv8*>(&sA1[(mt*16 + ln)*72 + ks*32 + qd*8]);
                acc = __builtin_amdgcn_mfma_f32_16x16x32_bf16(a, b1f[ks], acc, 0, 0, 0);
            }
            if (col < 24){
                #pragma unroll
                for (int rr = 0; rr < 4; ++rr){
                    int r = mt*16 + qd*4 + rr;
                    if (r < 136){
                        int c = r / 34, y = r - c*34;
                        sA2[(c*12 + kx)*104 + 2*y + s] = f2us(acc[rr]);
                    }
                }
            }
        }
    }
    __syncthreads();
    // ---- F2: 3 M-tiles x 3 N-tiles, K=96; scatter into sC (reuse sA1) ----
    unsigned short* sC = sA1;   // [m][9]: s*4+c at stride 9 (288*9 = 2592 u16)
    for (int tau = wv; tau < 9; tau += 4){
        int mt = tau / 3, nt = tau - (tau/3)*3;
        fv4 acc = (fv4){0.f,0.f,0.f,0.f};
        #pragma unroll
        for (int ks = 0; ks < 3; ++ks){
            bfv8 a  = *reinterpret_cast<const bfv8*>(&sA2[(mt*16 + ln)*104 + ks*32 + qd*8]);
            bfv8 bb = *reinterpret_cast<const bfv8*>(&gB2[(nt*16 + ln)*96 + ks*32 + qd*8]);
            acc = __builtin_amdgcn_mfma_f32_16x16x32_bf16(a, bb, acc, 0, 0, 0);
        }
        int col = nt*16 + ln;
        int ky = col >> 1, s = col & 1;
        #pragma unroll
        for (int rr = 0; rr < 4; ++rr){
            int r = mt*16 + qd*4 + rr;
            int c = r / 12, kxx = r - c*12;
            sC[(ky*12 + kxx)*9 + s*4 + c] = f2us(acc[rr]);
        }
    }
    __syncthreads();
    // ---- fully-coalesced writeback: block owns hft[cg][b][*] = 1152 dwords ----
    unsigned int* dst = hft + ((size_t)(c0 >> 2)*256 + b)*1152;
    for (int d = t; d < 1152; d += 256){
        int m = d >> 2, j = d & 3;
        unsigned int lo = sC[m*9 + 2*j];
        unsigned int hi = sC[m*9 + 2*j + 1];
        dst[d] = lo | (hi << 16);
    }
}

// ---------------- per-mode channel mix as bf16 MFMA GEMM ---------------------
// grid 576 = 288 modes x 2 M-halves of 128; C[128,128] = A[128,128] x B[128,128]
// A kappa order: kappa = cg*8+u (u<4: Re(c=cg*4+u), u>=4: Im), B staged to match.
// XCD line-mate swizzle: m-quads (same q=m>>2, same mh) get block ids differing
// by multiples of 8 -> same XCD L2 -> hft/weight 64B lines fetched once.
__global__ __launch_bounds__(256) void k_mixm(const unsigned short* __restrict__ hft,
                                              const void* __restrict__ sc_w1,
                                              const void* __restrict__ sc_w2,
                                              unsigned int* __restrict__ mixed, int layer,
                                              const float* __restrict__ flg){
    __shared__ unsigned short sB[128*136];   // BT[n][kappa], row stride 136
    const bool f32 = (flg[0] > 0.5f);
    int B = blockIdx.x;
    int x8 = B & 7, w8 = B >> 3;
    int r4 = w8 & 3, g = w8 >> 2;     // g < 18
    int u = g*8 + x8;                 // u < 144
    int mh = u & 1;
    int m  = (u >> 1)*4 + r4;         // m < 288
    int b0 = mh * 128;
    int t = threadIdx.x;
    int kyi = m / 12, kx = m - kyi*12;
    const void* w = (kyi < 12) ? sc_w1 : sc_w2;
    int r = (kyi < 12) ? kyi : kyi - 12;
    size_t wbase = (size_t)layer * 64*64*144*2;
    for (int idx = t; idx < 4096; idx += 256){     // idx = i*64+o
        int i = idx >> 6, o = idx & 63;
        size_t off = wbase + (((size_t)idx*12 + r)*12 + kx)*2;
        float wr = rdf(w, off, f32);
        float wi = rdf(w, off+1, f32);
        int kre = ((i >> 2) << 3) + (i & 3);       // kappa of Re(c=i)
        sB[o*136 + kre]          = f2us(wr);
        sB[(o+64)*136 + kre]     = f2us(wi);
        sB[o*136 + kre + 4]      = f2us(-wi);
        sB[(o+64)*136 + kre + 4] = f2us(wr);
    }
    __syncthreads();
    int ln = t & 15, qd = (t & 63) >> 4, wv = t >> 6;
    // A fragments: A[row][kappa=ks*32+qd*8 ..+7] = hft[g=ks*4+qd][row][m][0..7]
    bfv8 af[2][4];
    int arow = b0 + wv*32 + ln;
    #pragma unroll
    for (int tm = 0; tm < 2; ++tm)
        #pragma unroll
        for (int ks = 0; ks < 4; ++ks){
            int gg = ks*4 + qd;
            af[tm][ks] = *reinterpret_cast<const bfv8*>(
                hft + (((size_t)gg*256 + arow + tm*16)*288 + m)*8);
        }
    fv4 acc[2][8];
    #pragma unroll
    for (int tm=0;tm<2;++tm)
        #pragma unroll
        for (int tn=0;tn<8;++tn) acc[tm][tn] = (fv4){0.f,0.f,0.f,0.f};
    #pragma unroll
    for (int ks = 0; ks < 4; ++ks){
        bfv8 bfr[8];
        #pragma unroll
        for (int tn = 0; tn < 8; ++tn)
            bfr[tn] = *reinterpret_cast<const bfv8*>(&sB[(tn*16 + ln)*136 + ks*32 + qd*8]);
        #pragma unroll
        for (int tm = 0; tm < 2; ++tm)
            #pragma unroll
            for (int tn = 0; tn < 8; ++tn)
                acc[tm][tn] = __builtin_amdgcn_mfma_f32_16x16x32_bf16(af[tm][ks], bfr[tn], acc[tm][tn], 0, 0, 0);
    }
    __syncthreads();
    // C -> LDS (reuse sB): C[row][col], row stride 136; C/D map row=qd*4+r, col=ln
    #pragma unroll
    for (int tm = 0; tm < 2; ++tm)
        #pragma unroll
        for (int tn = 0; tn < 8; ++tn)
            #pragma unroll
            for (int rr = 0; rr < 4; ++rr){
                int row = wv*32 + tm*16 + qd*4 + rr;
                int col = tn*16 + ln;
                sB[row*136 + col] = f2us(acc[tm][tn][rr]);
            }
    __syncthreads();
    // pack (r,i) and write mixed[b][m][o] — 256B contiguous per (b,m), coalesced
    for (int idx = t; idx < 8192; idx += 256){
        int row = idx >> 6, o = idx & 63;
        unsigned int pr = ((unsigned int)sB[row*136 + o]) |
                          (((unsigned int)sB[row*136 + o + 64]) << 16);
        mixed[((size_t)(b0 + row)*288 + m)*64 + o] = pr;
    }
}

// ---------------- pointwise 64x64 channel GEMM (wc path) as MFMA, IN PLACE ---
// grid 1280: b = blk&255, u = blk>>8 (5 px-chunks of 240; chunks of same b
// co-XCD: ids differ by 256). C[240px][64o] = A[240px][64c] x w[o][c]^T + bias.
// Per-chunk in-place: block reads/writes only its own px range (disjoint).
__global__ __launch_bounds__(256) void k_wc(bf16* __restrict__ h,
                                            const void* __restrict__ wc_w,
                                            const void* __restrict__ wc_b,
                                            int layer,
                                            const float* __restrict__ flg){
    __shared__ unsigned short sA[240*72];   // A[p][c], stride 72; reused as sC[64][240]
    __shared__ unsigned short sBT[64*72];   // BT[o][c], stride 72
    __shared__ float sb[64];
    const bool f32 = (flg[0] > 0.5f);
    int blk = blockIdx.x;
    int b = blk & 255, u = blk >> 8;
    int px0 = u*240;
    int npx = 1156 - px0; if (npx > 240) npx = 240;   // 240 or 196
    int ndp = npx >> 1;                                // 120 or 98
    int t = threadIdx.x;
    size_t wbase = (size_t)layer*4096;
    for (int i = t; i < 4096; i += 256){               // wc_w[l][o][c] -> BT[o][c]
        int o = i >> 6, c = i & 63;
        sBT[o*72 + c] = f2us(rdf(wc_w, wbase + i, f32));
    }
    if (t < 64) sb[t] = rdf(wc_b, layer*64 + t, f32);
    // stage A transposed: dword-granular reads of h (always bf16 workspace)
    const unsigned int* srcd = (const unsigned int*)(h + (size_t)b*73984);
    for (int i = t; i < 7680; i += 256){
        int c = i / 120, dp = i - c*120;
        unsigned int v = (dp < ndp) ? srcd[c*578 + (px0 >> 1) + dp] : 0u;
        sA[(2*dp)*72 + c]     = (unsigned short)(v & 0xffff);
        sA[(2*dp + 1)*72 + c] = (unsigned short)(v >> 16);
    }
    __syncthreads();
    int ln = t & 15, qd = (t & 63) >> 4, wv = t >> 6;
    bfv8 bfr[4][2];
    #pragma unroll
    for (int nt = 0; nt < 4; ++nt)
        #pragma unroll
        for (int ks = 0; ks < 2; ++ks)
            bfr[nt][ks] = *reinterpret_cast<const bfv8*>(&sBT[(nt*16 + ln)*72 + ks*32 + qd*8]);
    // 15 m-tiles: wave wv handles mt = wv + 4*mi (mi<4, skip mt>=15)
    bfv8 a_[4][2];
    #pragma unroll
    for (int mi = 0; mi < 4; ++mi){
        int mt = wv + mi*4;
        if (mt < 15){
            a_[mi][0] = *reinterpret_cast<const bfv8*>(&sA[(mt*16 + ln)*72 + qd*8]);
            a_[mi][1] = *reinterpret_cast<const bfv8*>(&sA[(mt*16 + ln)*72 + 32 + qd*8]);
        }
    }
    fv4 acc[4][4];
    #pragma unroll
    for (int mi = 0; mi < 4; ++mi){
        int mt = wv + mi*4;
        if (mt < 15){
            #pragma unroll
            for (int nt = 0; nt < 4; ++nt){
                fv4 a = (fv4){0.f,0.f,0.f,0.f};
                a = __builtin_amdgcn_mfma_f32_16x16x32_bf16(a_[mi][0], bfr[nt][0], a, 0, 0, 0);
                a = __builtin_amdgcn_mfma_f32_16x16x32_bf16(a_[mi][1], bfr[nt][1], a, 0, 0, 0);
                acc[mi][nt] = a;
            }
        }
    }
    __syncthreads();
    // C -> sC[o][240] (transpose back), bias added
    unsigned int* sCd = (unsigned int*)sA;   // [o][120 dw]
    #pragma unroll
    for (int mi = 0; mi < 4; ++mi){
        int mt = wv + mi*4;
        if (mt < 15){
            #pragma unroll
            for (int nt = 0; nt < 4; ++nt){
                int o = nt*16 + ln;
                float bb = sb[o];
                int p0 = mt*16 + qd*4;
                sCd[o*120 + (p0 >> 1)]     = packbf2(acc[mi][nt][0] + bb, acc[mi][nt][1] + bb);
                sCd[o*120 + (p0 >> 1) + 1] = packbf2(acc[mi][nt][2] + bb, acc[mi][nt][3] + bb);
            }
        }
    }
    __syncthreads();
    // coalesced in-place writeback (own px range only)
    unsigned int* dstd = (unsigned int*)(h + (size_t)b*73984);
    for (int i = t; i < 7680; i += 256){
        int o = i / 120, dp = i - o*120;
        if (dp < ndp) dstd[o*578 + (px0 >> 1) + dp] = sCd[o*120 + dp];
    }
}

// ---------------- inverse truncated DFT as MFMA GEMMs; in-place add + gelu ---
// grid 4096 = 256 b x 16 o-groups of 4, XCD line-mate swizzled:
//   B = z*32 + s*8 + x  ->  b = (z>>2)*8 + x, og = (z&3)*4 + s
//   og-quads of the same b (which share each 64B line of mixed) land on the
//   same XCD (ids differ by 8/16/24) -> line fetched once into that L2.
// B operands (invBT/invW2) are read DIRECTLY from global images (L2-resident,
// fragment-ready layout); OOB rows give garbage discarded by col/y predicates.
// LDS 36.9 KB -> 4 blocks/CU.
__global__ __launch_bounds__(256) void k_invm(const unsigned int* __restrict__ mixed,
                                              const float* __restrict__ tabs,
                                              bf16* __restrict__ hio, int layer){
    __shared__ unsigned short lds[18448];   // 36,896 B total
    unsigned short* sA  = lds;              // 96*40 (step A only; overlaps htile)
    unsigned short* sG  = lds + 4624;       // 4*48*72 (htile = lds[0..4624))
    unsigned int* ldsw  = (unsigned int*)lds;
    int B = blockIdx.x;
    int x8 = B & 7, s4 = (B >> 3) & 3, z = B >> 5;
    int b  = (z >> 2)*8 + x8;
    int o0 = ((z & 3)*4 + s4)*4;
    int t = threadIdx.x;
    const unsigned short* gBT16 = (const unsigned short*)(tabs + 2448);  // [n][32 u16]
    const unsigned short* gW216 = (const unsigned short*)(tabs + 3536);  // [y][64 u16]
    // sA from mixed[b][m][o]: 16B per (m), stride 256B (lines shared intra-XCD)
    const unsigned int* msrc = mixed + (size_t)b*18432 + o0;
    for (int i = t; i < 1152; i += 256){
        int m = i >> 2, ch = i & 3;
        int kyi = m / 12, kx = m - kyi*12;
        ((unsigned int*)sA)[(ch*24 + kyi)*20 + kx] = msrc[(size_t)m*64 + ch];
    }
    for (int i = t; i < 384; i += 256)       // zero k 24..31 (dw 12..15)
        ((unsigned int*)sA)[(i >> 2)*20 + 12 + (i & 3)] = 0;
    // sG: zero only read pads — rows x in [34,48): dw 0..31; rows x<34: dw 24..31
    for (int i = t; i < 1792; i += 256){
        int r = i >> 5;
        int ch = r / 14, x = 34 + (r - (r/14)*14);
        ((unsigned int*)sG)[(ch*48 + x)*36 + (i & 31)] = 0;
    }
    for (int i = t; i < 1088; i += 256){
        int r = i >> 3;
        int ch = r / 34, x = r - (r/34)*34;
        ((unsigned int*)sG)[(ch*48 + x)*36 + 24 + (i & 7)] = 0;
    }
    __syncthreads();
    int ln = t & 15, qd = (t & 63) >> 4, wv = t >> 6;
    // ---- step A: 30 tiles (6 M x 5 N), K=32; B-frag direct from gBT image ----
    for (int tau = wv; tau < 30; tau += 4){
        int mt = tau / 5, nt = tau - mt*5;
        bfv8 a  = *reinterpret_cast<const bfv8*>(&sA[(mt*16 + ln)*40 + qd*8]);
        bfv8 bb = *reinterpret_cast<const bfv8*>(&gBT16[(nt*16 + ln)*32 + qd*8]);
        fv4 acc = (fv4){0.f,0.f,0.f,0.f};
        acc = __builtin_amdgcn_mfma_f32_16x16x32_bf16(a, bb, acc, 0, 0, 0);
        int col = nt*16 + ln;
        if (col < 68){
            int x = col >> 1, ri = col & 1;
            #pragma unroll
            for (int rr = 0; rr < 4; ++rr){
                int row = mt*16 + qd*4 + rr;
                int ch = row / 24, kyi = row - ch*24;
                sG[(ch*48 + x)*72 + 2*kyi + ri] = f2us(acc[rr]);
            }
        }
    }
    __syncthreads();
    // ---- stage htile (4 contiguous ch-planes) into lds[0..2312) dwords ----
    const unsigned int* hsrc = (const unsigned int*)(hio + (size_t)b*73984 + (size_t)o0*1156);
    for (int i = t; i < 2312; i += 256) ldsw[i] = hsrc[i];
    __syncthreads();
    // ---- step B: wave = ch; 3x3 tiles, K=64 (2 MFMAs); A-frag direct from gW2 ----
    int ch = wv;
    #pragma unroll
    for (int mt = 0; mt < 3; ++mt){
        bfv8 a0 = *reinterpret_cast<const bfv8*>(&gW216[(mt*16 + ln)*64 + qd*8]);
        bfv8 a1 = *reinterpret_cast<const bfv8*>(&gW216[(mt*16 + ln)*64 + 32 + qd*8]);
        #pragma unroll
        for (int nt = 0; nt < 3; ++nt){
            bfv8 b0 = *reinterpret_cast<const bfv8*>(&sG[(ch*48 + nt*16 + ln)*72 + qd*8]);
            bfv8 b1 = *reinterpret_cast<const bfv8*>(&sG[(ch*48 + nt*16 + ln)*72 + 32 + qd*8]);
            fv4 acc = (fv4){0.f,0.f,0.f,0.f};
            acc = __builtin_amdgcn_mfma_f32_16x16x32_bf16(a0, b0, acc, 0, 0, 0);
            acc = __builtin_amdgcn_mfma_f32_16x16x32_bf16(a1, b1, acc, 0, 0, 0);
            int x = nt*16 + ln;
            if (x < 34){
                #pragma unroll
                for (int rr = 0; rr < 4; ++rr){
                    int y = mt*16 + qd*4 + rr;
                    if (y < 34){
                        int off = ch*1156 + y*34 + x;
                        float v = acc[rr] + us2f(lds[off]);
                        if (layer < 3) v = gelu_f(v);
                        lds[off] = f2us(v);
                    }
                }
            }
        }
    }
    __syncthreads();
    // ---- coalesced dword writeback ----
    unsigned int* hdst = (unsigned int*)(hio + (size_t)b*73984 + (size_t)o0*1156);
    for (int i = t; i < 2312; i += 256) hdst[i] = ldsw[i];
}

// ---------------- 8x8/stride4 VALID conv -> gelu -> pe2 scale ----------------
__global__ __launch_bounds__(256) void k_pe(const bf16* __restrict__ h,
                                            const void* __restrict__ pw,
                                            const void* __restrict__ pb,
                                            const void* __restrict__ p2w,
                                            const void* __restrict__ p2b,
                                            float* __restrict__ p49,
                                            const float* __restrict__ flg){
    __shared__ float red[256];
    const bool f32 = (flg[0] > 0.5f);
    int bid = blockIdx.x;          // b*49 + py*7 + px
    int b = bid / 49, r = bid - b*49;
    int py = r / 7, px = r - py*7;
    int t = threadIdx.x;
    const bf16* hb = h + (size_t)b*73984 + (py*4)*34 + px*4;
    float partial = 0.f;
    for (int tt = t; tt < 4096; tt += 256){
        int c = tt >> 6, k = tt & 63, ky = k >> 3, kx = k & 7;
        partial += bff(hb[(size_t)c*1156 + ky*34 + kx]) * rdf(pw, tt, f32);
    }
    red[t] = partial;
    __syncthreads();
    for (int s = 128; s > 0; s >>= 1){
        if (t < s) red[t] += red[t + s];
        __syncthreads();
    }
    if (t == 0){
        float v = red[0] + rdf(pb, 0, f32);
        v = gelu_f(v);
        p49[bid] = v * rdf(p2w, 0, f32) + rdf(p2b, 0, f32);
    }
}

// ---------------- sentence MLP 384->32->32->16 (relu,relu,lin) ---------------
__global__ __launch_bounds__(64) void k_sent(const void* __restrict__ se,
                                             const void* __restrict__ w1, const void* __restrict__ b1,
                                             const void* __restrict__ w2, const void* __restrict__ b2,
                                             const void* __restrict__ w3, const void* __restrict__ b3,
                                             float* __restrict__ outv,
                                             const float* __restrict__ flg){
    __shared__ float s1[32], s2[32];
    const bool f32 = (flg[0] > 0.5f);
    int b = blockIdx.x, t = threadIdx.x;
    if (t < 32){
        float acc = rdf(b1, t, f32);
        size_t rbase = (size_t)b*384;
        for (int k = 0; k < 384; ++k) acc += rdf(se, rbase + k, f32) * rdf(w1, k*32 + t, f32);
        s1[t] = fmaxf(acc, 0.f);
    }
    __syncthreads();
    if (t < 32){
        float acc = rdf(b2, t, f32);
        for (int k = 0; k < 32; ++k) acc += s1[k] * rdf(w2, k*32 + t, f32);
        s2[t] = fmaxf(acc, 0.f);
    }
    __syncthreads();
    if (t < 16){
        float acc = rdf(b3, t, f32);
        for (int k = 0; k < 32; ++k) acc += s2[k] * rdf(w3, k*16 + t, f32);
        outv[b*16 + t] = acc;
    }
}

// ---------------- xp MLP 49->32->32->16 (silu,silu,lin) ----------------------
__global__ __launch_bounds__(64) void k_xp(const float* __restrict__ p49,
                                           const void* __restrict__ w1, const void* __restrict__ b1,
                                           const void* __restrict__ w2, const void* __restrict__ b2,
                                           const void* __restrict__ w3, const void* __restrict__ b3,
                                           float* __restrict__ outv,
                                           const float* __restrict__ flg){
    __shared__ float s1[32], s2[32];
    const bool f32 = (flg[0] > 0.5f);
    int b = blockIdx.x, t = threadIdx.x;
    if (t < 32){
        float acc = rdf(b1, t, f32);
        const float* row = p49 + b*49;
        for (int k = 0; k < 49; ++k) acc += row[k] * rdf(w1, k*32 + t, f32);
        s1[t] = silu_f(acc);
    }
    __syncthreads();
    if (t < 32){
        float acc = rdf(b2, t, f32);
        for (int k = 0; k < 32; ++k) acc += s1[k] * rdf(w2, k*32 + t, f32);
        s2[t] = silu_f(acc);
    }
    __syncthreads();
    if (t < 16){
        float acc = rdf(b3, t, f32);
        for (int k = 0; k < 32; ++k) acc += s2[k] * rdf(w3, k*16 + t, f32);
        outv[b*16 + t] = acc;
    }
}

// ---------------- pu MLP part A: 32->128->256 (silu,silu) --------------------
__global__ __launch_bounds__(256) void k_puA(const float* __restrict__ xemb,
                                             const float* __restrict__ semb,
                                             const void* __restrict__ w1, const void* __restrict__ b1,
                                             const void* __restrict__ w2, const void* __restrict__ b2,
                                             float* __restrict__ h2buf,
                                             const float* __restrict__ flg){
    __shared__ float ein[32];
    __shared__ float h1[128];
    const bool f32 = (flg[0] > 0.5f);
    int b = blockIdx.x, t = threadIdx.x;
    if (t < 16) ein[t] = xemb[b*16 + t];
    else if (t < 32) ein[t] = semb[b*16 + (t - 16)];
    __syncthreads();
    if (t < 128){
        float acc = rdf(b1, t, f32);
        for (int k = 0; k < 32; ++k) acc += ein[k] * rdf(w1, k*128 + t, f32);
        h1[t] = silu_f(acc);
    }
    __syncthreads();
    {
        float acc = rdf(b2, t, f32);
        for (int k = 0; k < 128; ++k) acc += h1[k] * rdf(w2, k*256 + t, f32);
        h2buf[(size_t)b*256 + t] = silu_f(acc);
    }
}

// ---------------- pu MLP part B: 256->1156 GEMM ------------------------------
// grid 1280 = 256 b (fast) x 5 n-chunks of 232
__global__ __launch_bounds__(256) void k_puB(const float* __restrict__ h2buf,
                                             const void* __restrict__ w3, const void* __restrict__ b3,
                                             float* __restrict__ emb,
                                             const float* __restrict__ flg){
    __shared__ float sh2[256];
    const bool f32 = (flg[0] > 0.5f);
    int blk = blockIdx.x;
    int b = blk & 255, nc = blk >> 8;
    int t = threadIdx.x;
    sh2[t] = h2buf[(size_t)b*256 + t];
    __syncthreads();
    int e = nc*232 + t;
    if (t < 232 && e < 1156){
        float acc = rdf(b3, e, f32);
        if (f32){
            const float* wp = (const float*)w3 + e;
            #pragma unroll 4
            for (int k = 0; k < 256; ++k) acc += sh2[k] * wp[(size_t)k*1156];
        } else {
            const bf16* wp = (const bf16*)w3 + e;
            #pragma unroll 4
            for (int k = 0; k < 256; ++k) acc += sh2[k] * bff(wp[(size_t)k*1156]);
        }
        emb[(size_t)b*1156 + e] = acc;
    }
}

// ---------------- final: crop, concat emb, fc1(MFMA)+gelu, fc2(MFMA) ---------
// grid 512 = 256 b x 2 halves; 8 iters of 2 rows (64 px).
// fc1: C[64px,128j] = A[px,c<64] x w1 (K=64) + rank-1 emb add; fc2: K=128, N=16(4)
__global__ __launch_bounds__(256, 3) void k_final(const bf16* __restrict__ h,
                                                  const float* __restrict__ emb,
                                                  const void* __restrict__ w1, const void* __restrict__ b1,
                                                  const void* __restrict__ w2, const void* __restrict__ b2,
                                                  void* __restrict__ out,
                                                  const float* __restrict__ flg){
    __shared__ unsigned short sw1t[128*72];   // w1T[j][c], stride 72 (16B-aligned rows)
    __shared__ unsigned short sw2t[16*136];   // w2T[n][j], rows 4..15 zero
    __shared__ float sw1e[128];               // w1[64][j] (emb channel)
    __shared__ float sb1[128];
    __shared__ float sb2[4];
    __shared__ unsigned short spx[64*66];     // input[c][px], stride 66 (odd dwords)
    __shared__ float sembp[64];               // emb[px]
    __shared__ unsigned short sh2[128*66];    // hid[j][px], stride 66
    const bool f32 = (flg[0] > 0.5f);
    int blk = blockIdx.x;
    int b = blk >> 1, half = blk & 1;
    int t = threadIdx.x;
    for (int i = t; i < 8320; i += 256){       // w1 [c=65][j=128]
        int c = i >> 7, j = i & 127;
        float v = rdf(w1, i, f32);
        if (c < 64) sw1t[j*72 + c] = f2us(v);
        else sw1e[j] = v;
    }
    if (t < 128) sb1[t] = rdf(b1, t, f32);
    for (int i = t; i < 2176; i += 256){       // w2 [j=128][k=4] -> w2T[n][j]
        int n = i / 136, j = i - n*136;
        float v = (n < 4 && j < 128) ? rdf(w2, j*4 + n, f32) : 0.f;
        sw2t[i] = f2us(v);
    }
    if (t < 4) sb2[t] = rdf(b2, t, f32);
    __syncthreads();
    int ln = t & 15, qd = (t & 63) >> 4, wv = t >> 6;
    // hoist B fragments (weights) into registers
    bfv8 bw1[8][2];
    #pragma unroll
    for (int tn = 0; tn < 8; ++tn)
        #pragma unroll
        for (int ks = 0; ks < 2; ++ks)
            bw1[tn][ks] = *reinterpret_cast<const bfv8*>(&sw1t[(tn*16 + ln)*72 + ks*32 + qd*8]);
    bfv8 bw2[4];
    #pragma unroll
    for (int ks = 0; ks < 4; ++ks)
        bw2[ks] = *reinterpret_cast<const bfv8*>(&sw2t[ln*136 + ks*32 + qd*8]);
    const bf16* hb = h + (size_t)b*73984;
    const float* eb = emb + (size_t)b*1156;
    for (int it = 0; it < 8; ++it){
        int y0 = half*16 + it*2;               // 2 rows = 64 px
        __syncthreads();
        for (int e = t; e < 2048; e += 256){   // stage spx[c][px] c-major
            int c = e >> 5, d = e & 31;
            int px = d*2;
            int y = y0 + (px >> 5), x = px & 31;
            float v0 = bff(hb[(size_t)c*1156 + y*34 + x]);
            int px1 = px + 1;
            int y1 = y0 + (px1 >> 5), x1 = px1 & 31;
            float v1 = bff(hb[(size_t)c*1156 + y1*34 + x1]);
            ((unsigned int*)spx)[c*33 + d] = packbf2(v0, v1);
        }
        if (t < 64){
            int y = y0 + (t >> 5), x = t & 31;
            sembp[t] = eb[y*34 + x];
        }
        __syncthreads();
        // fc1 MFMA: wave wv owns mtile wv (px = wv*16 + ...)
        fv4 acc[8];
        #pragma unroll
        for (int tn = 0; tn < 8; ++tn) acc[tn] = (fv4){0.f,0.f,0.f,0.f};
        #pragma unroll
        for (int ks = 0; ks < 2; ++ks){
            union { bfv8 v; unsigned short s[8]; } af;
            #pragma unroll
            for (int j = 0; j < 8; ++j)
                af.s[j] = spx[(ks*32 + qd*8 + j)*66 + wv*16 + ln];
            #pragma unroll
            for (int tn = 0; tn < 8; ++tn)
                acc[tn] = __builtin_amdgcn_mfma_f32_16x16x32_bf16(af.v, bw1[tn][ks], acc[tn], 0, 0, 0);
        }
        float ev[4];
        #pragma unroll
        for (int rr = 0; rr < 4; ++rr) ev[rr] = sembp[wv*16 + qd*4 + rr];
        #pragma unroll
        for (int tn = 0; tn < 8; ++tn){
            int col = tn*16 + ln;
            float we = sw1e[col];
            float bb1 = sb1[col];
            #pragma unroll
            for (int rr = 0; rr < 4; ++rr){
                float v = acc[tn][rr] + ev[rr]*we + bb1;
                sh2[col*66 + wv*16 + qd*4 + rr] = f2us(gelu_f(v));
            }
        }
        __syncthreads();
        // fc2 MFMA: K=128, N=16 (4 valid)
        fv4 a2 = (fv4){0.f,0.f,0.f,0.f};
        #pragma unroll
        for (int ks = 0; ks < 4; ++ks){
            union { bfv8 v; unsigned short s[8]; } af;
            #pragma unroll
            for (int j = 0; j < 8; ++j)
                af.s[j] = sh2[(ks*32 + qd*8 + j)*66 + wv*16 + ln];
            a2 = __builtin_amdgcn_mfma_f32_16x16x32_bf16(af.v, bw2[ks], a2, 0, 0, 0);
        }
        if (ln < 4){
            float bb2 = sb2[ln];
            #pragma unroll
            for (int rr = 0; rr < 4; ++rr){
                int pxl = wv*16 + qd*4 + rr;
                int y = y0 + (pxl >> 5), x = pxl & 31;
                size_t o = ((size_t)(b*32 + y)*32 + x)*4 + ln;
                float v = a2[rr] + bb2;
                if (f32) ((float*)out)[o] = v;
                else     ((bf16*)out)[o] = __float2bfloat16(v);
            }
        }
    }
}

extern "C" void kernel_launch(void* const* d_in, const int* in_sizes, int n_in,
                              void* d_out, int out_size, void* d_ws, size_t ws_size,
                              hipStream_t stream) {
    (void)in_sizes; (void)n_in; (void)out_size; (void)ws_size;
    const void* x     = d_in[0];
    const void* grd   = d_in[1];
    const void* se    = d_in[2];
    const void* fc0_w = d_in[3];
    const void* fc0_b = d_in[4];
    const void* sc_w1 = d_in[5];
    const void* sc_w2 = d_in[6];
    const void* wc_w  = d_in[7];
    const void* wc_b  = d_in[8];
    const void* pe1_w = d_in[9];
    const void* pe1_b = d_in[10];
    const void* pe2_w = d_in[11];
    const void* pe2_b = d_in[12];
    const void* sp_w1 = d_in[13];
    const void* sp_b1 = d_in[14];
    const void* sp_w2 = d_in[15];
    const void* sp_b2 = d_in[16];
    const void* sp_w3 = d_in[17];
    const void* sp_b3 = d_in[18];
    const void* xp_w1 = d_in[19];
    const void* xp_b1 = d_in[20];
    const void* xp_w2 = d_in[21];
    const void* xp_b2 = d_in[22];
    const void* xp_w3 = d_in[23];
    const void* xp_b3 = d_in[24];
    const void* pu_w1 = d_in[25];
    const void* pu_b1 = d_in[26];
    const void* pu_w2 = d_in[27];
    const void* pu_b2 = d_in[28];
    const void* pu_w3 = d_in[29];
    const void* pu_b3 = d_in[30];
    const void* fc1_w = d_in[31];
    const void* fc1_b = d_in[32];
    const void* fc2_w = d_in[33];
    const void* fc2_b = d_in[34];

    // workspace layout (float-unit offsets); total ~77 MB
    float* ws    = (float*)d_ws;
    bf16*  hA    = (bf16*)ws;                              // 18,939,904 bf16
    unsigned int* hft   = (unsigned int*)(ws + 9469952);   // 4,718,592 dwords (hft cg-panels)
    unsigned int* mixed = (unsigned int*)(ws + 14188544);  // 4,718,592 dwords ([b][m][o])
    float* tabs  = ws + 18907136;                          // 4,896 (DFT tables + inv images)
    float* p49   = ws + 18912032;                          // 12,544
    float* semb  = ws + 18924576;                          // 4,096
    float* xemb  = ws + 18928672;                          // 4,096
    float* emb   = ws + 18932768;                          // 295,936
    float* flag  = ws + 19228704;                          // 1
    float* h2buf = (float*)hft;                            // reuse: hft dead after layer loop
    // fwd B-images live in emb region (dead during layer loop; k_puB writes emb
    // only after the last k_invm; k_tables rebuilds images each replay)
    float* fwdimg = emb;                                   // 3,328 floats

    k_probe<<<1, 256, 0, stream>>>(x, flag);
    k_tables<<<1, 256, 0, stream>>>(tabs, fwdimg);
    k_fc0<<<1024, 256, 0, stream>>>(x, grd, fc0_w, fc0_b, hA, flag);

    for (int l = 0; l < 4; ++l){
        k_fwd<<<4096, 256, 0, stream>>>(hA, hft, (const unsigned short*)fwdimg);
        k_mixm<<<576, 256, 0, stream>>>((const unsigned short*)hft, sc_w1, sc_w2, mixed, l, flag);
        k_wc <<<1280, 256, 0, stream>>>(hA, wc_w, wc_b, l, flag);
        k_invm<<<4096, 256, 0, stream>>>(mixed, tabs, hA, l);
    }

    k_pe  <<<256*49, 256, 0, stream>>>(hA, pe1_w, pe1_b, pe2_w, pe2_b, p49, flag);
    k_sent<<<256, 64, 0, stream>>>(se, sp_w1, sp_b1, sp_w2, sp_b2, sp_w3, sp_b3, semb, flag);
    k_xp  <<<256, 64, 0, stream>>>(p49, xp_w1, xp_b1, xp_w2, xp_b2, xp_w3, xp_b3, xemb, flag);
    k_puA <<<256, 256, 0, stream>>>(xemb, semb, pu_w1, pu_b1, pu_w2, pu_b2, h2buf, flag);
    k_puB <<<1280, 256, 0, stream>>>(h2buf, pu_w3, pu_b3, emb, flag);
    k_final<<<512, 256, 0, stream>>>(hA, emb, fc1_w, fc1_b, fc2_w, fc2_b, d_out, flag);
}

// Round 7
// 1138.568 us; speedup vs baseline: 1.2429x; 1.0228x over previous
//
#include <hip/hip_runtime.h>
#include <hip/hip_bf16.h>
#include <math.h>

typedef __hip_bfloat16 bf16;
typedef __bf16 bfv8 __attribute__((ext_vector_type(8)));
typedef float fv4 __attribute__((ext_vector_type(4)));

__device__ __forceinline__ float bff(const bf16 x){ return __bfloat162float(x); }
__device__ __forceinline__ float gelu_f(float v){
    return 0.5f * v * (1.f + erff(v * 0.70710678118654752f));
}
__device__ __forceinline__ float silu_f(float v){
    return v / (1.f + expf(-v));
}
// dtype-agnostic input read: f32 ? fp32 : bf16
__device__ __forceinline__ float rdf(const void* p, size_t i, bool f32){
    return f32 ? ((const float*)p)[i] : __bfloat162float(((const bf16*)p)[i]);
}
__device__ __forceinline__ unsigned int packbf2(float a, float b){
    __hip_bfloat162 v;
    v.x = __float2bfloat16(a);
    v.y = __float2bfloat16(b);
    return *reinterpret_cast<unsigned int*>(&v);
}
__device__ __forceinline__ float2 unpackbf2(unsigned int u){
    __hip_bfloat162 v = *reinterpret_cast<__hip_bfloat162*>(&u);
    return make_float2(__bfloat162float(v.x), __bfloat162float(v.y));
}
__device__ __forceinline__ float us2f(unsigned short u){
    unsigned int x = ((unsigned int)u) << 16;
    return __uint_as_float(x);
}
__device__ __forceinline__ unsigned short f2us(float f){
    bf16 v = __float2bfloat16(f);
    return *reinterpret_cast<unsigned short*>(&v);
}

// Geometry
// B=256, C=64, H=W=34 (padded), modes: ky in {0..11, 22..33} (24), kx in 0..11 (12)
// h layout (ws, bf16): [b][c][y][x], stride c = 1156, stride b = 73984
// hft layout: [cg<16][b<256][m<288][8 bf16] ; kappa = cg*8+u, u<4: Re(c=cg*4+u),
//             u>=4: Im(c=cg*4+u-4).  Writer (k_fwd) fully coalesced per block.
// mixed layout: [b<256][m<288][o<64] packed bf16x2 dwords (r,i); writer (k_mixm)
//             owns full 256B rows per (b,m).
// tabs: [0,1632) Wfy f32 | [1632,2448) Wfx f32 |
//       [2448,3536) invBT bf16 image (68x16 dw) | [3536,4624) invW2 bf16 image (34x32 dw)
// fwd images (in emb region, dead during layer loop):
//   gB1 [row<32][64 u16] | gB2 [row<48][96 u16] | gFC0 [c<64][72 u16] @ +3328 fl |
//   gFC0b [64 f32] @ +5632 fl
// All images fragment-ready: k_fwd/k_invm/k_fc0 read MFMA fragments DIRECTLY from
// global (16B-aligned rows, pads pre-zeroed; OOB rows discarded by predicates).

// ---------------- dtype probe ----------------
__global__ __launch_bounds__(256) void k_probe(const void* x, float* flag){
    __shared__ int wild;
    int t = threadIdx.x;
    if (t == 0) wild = 0;
    __syncthreads();
    const bf16* xb = (const bf16*)x;
    for (int i = t; i < 1024; i += 256){
        float v = bff(xb[i]);
        if (!(fabsf(v) < 1e10f)) wild = 1;
    }
    __syncthreads();
    if (t == 0) flag[0] = wild ? 1.f : 0.f;
}

// ---------------- tables ----------------
__global__ __launch_bounds__(256) void k_tables(float* tabs, float* fwdimg,
                                                const void* __restrict__ fc0w,
                                                const void* __restrict__ fc0b,
                                                const float* __restrict__ flg){
    int t = threadIdx.x;
    const bool f32 = (flg[0] > 0.5f);
    unsigned int* gBT = (unsigned int*)(tabs + 2448);   // [n<68][kd<16] bf16x2
    unsigned int* gW2 = (unsigned int*)(tabs + 3536);   // [y<34][kd<32] bf16x2
    unsigned short* gB1 = (unsigned short*)fwdimg;          // [row<32][64]
    unsigned short* gB2 = (unsigned short*)(fwdimg + 1024); // [row<48][96]
    unsigned short* gF  = (unsigned short*)(fwdimg + 3328); // [c<64][72]
    float* gFb = fwdimg + 5632;                             // [64]
    const float TWO_PI = 6.283185307179586f;
    // gFC0 image: BT[c][k] from fc0_w [k=42][c=64], k-pads zeroed
    for (int i = t; i < 4608; i += 256){
        int c = i / 72, k = i - c*72;
        float v = (k < 42) ? rdf(fc0w, (size_t)k*64 + c, f32) : 0.f;
        gF[i] = f2us(v);
    }
    if (t < 64) gFb[t] = rdf(fc0b, t, f32);
    // gB1: row=2kx+s (kx<12), k=x<34: e^{-i ang} component (s=0: cos, s=1: -sin)
    for (int i = t; i < 2048; i += 256){
        int row = i >> 6, k = i & 63;
        float v = 0.f;
        if (row < 24 && k < 34){
            int kx = row >> 1, s = row & 1;
            int ph = (kx * k) % 34;
            float ang = TWO_PI * (float)ph / 34.0f;
            float sn, cs;
            sincosf(ang, &sn, &cs);
            v = (s == 0) ? cs : -sn;
        }
        gB1[i] = f2us(v);
    }
    // gB2: row=2ky+s (kyi<24), kk=2y+p<68: realified [[wr,-wi],[wi,wr]] of e^{-i ang}
    for (int i = t; i < 4608; i += 256){
        int row = i / 96, kk = i - row*96;
        float v = 0.f;
        if (kk < 68){
            int kyi = row >> 1, s = row & 1;
            int y = kk >> 1, p = kk & 1;
            int ky = (kyi < 12) ? kyi : kyi + 10;
            int ph = (ky * y) % 34;
            float ang = TWO_PI * (float)ph / 34.0f;
            float sn, cs;
            sincosf(ang, &sn, &cs);
            float wr = cs, wi = -sn;
            v = (s == 0) ? ((p == 0) ? wr : -wi) : ((p == 0) ? wi : wr);
        }
        gB2[i] = f2us(v);
    }
    // invBT image: n=2x+ri (x<34), k=2kx+ri2; v = ri==0 ? (ri2==0? C : -S) : (ri2==0? S : C)
    // where C = ck*cos(ang), S = ck*sin(ang), ang = +2pi*(kx*x mod 34)/34, ck = (kx==0?1:2)
    for (int i = t; i < 1088; i += 256){
        int n = i >> 4, kd = i & 15;
        int x = n >> 1, ri = n & 1;
        int kx = kd;
        float v0 = 0.f, v1 = 0.f;
        if (kx < 12){
            int ph = (kx * x) % 34;
            float ang = TWO_PI * (float)ph / 34.0f;
            float s, c;
            sincosf(ang, &s, &c);
            float ck = (kx == 0) ? 1.0f : 2.0f;
            float C = ck * c, S = ck * s;
            v0 = (ri == 0) ? C : S;       // ri2 = 0
            v1 = (ri == 0) ? -S : C;      // ri2 = 1
        }
        gBT[i] = packbf2(v0, v1);
    }
    // invW2 image: y<34, k=2kyi+ri; v = (1/1156)*(ri==0? cos : -sin), ang=+2pi*(ky*y mod 34)/34
    for (int i = t; i < 1088; i += 256){
        int y = i >> 5, kd = i & 31;
        int kyi = kd;
        float v0 = 0.f, v1 = 0.f;
        if (kyi < 24){
            int ky = (kyi < 12) ? kyi : kyi + 10;
            int ph = (ky * y) % 34;
            float ang = TWO_PI * (float)ph / 34.0f;
            float s, c;
            sincosf(ang, &s, &c);
            v0 = c * (1.0f/1156.0f);
            v1 = -s * (1.0f/1156.0f);
        }
        gW2[i] = packbf2(v0, v1);
    }
}

// ---------------- fc0 as MFMA GEMM: concat(x,grid) @ fc0_w + b ---------------
// grid 2048: B -> b = (B>>6)*8 + (B&7), u = (B>>3)&7  (8 chunks of b co-XCD)
// Block: px in [u*128, u*128+128); C[128px][64c], K=42 pad 64.
// Weights read DIRECTLY from gFC0 image (L2-resident, fragment-ready).
// LDS = sA only (18.4 KB) -> 8 blocks/CU. x staged as dwords (bf16 path).
// Epilogue: C -> sC[c][4rows x 34] image, coalesced 272B-run writeback per c.
__global__ __launch_bounds__(256) void k_fc0(const void* __restrict__ xin,
                                             const void* __restrict__ grd,
                                             const unsigned short* __restrict__ img,
                                             bf16* __restrict__ h,
                                             const float* __restrict__ flg){
    __shared__ unsigned short sA[128*72];   // A[p][k] stride 72; reused as sC[64][68 dw]
    const bool f32 = (flg[0] > 0.5f);
    int B = blockIdx.x;
    int b = (B >> 6)*8 + (B & 7);
    int u = (B >> 3) & 7;
    int t = threadIdx.x;
    unsigned int* sAw = (unsigned int*)sA;
    if (!f32){
        const unsigned int* xd = (const unsigned int*)xin;
        size_t base = ((size_t)b*1024 + u*128)*20;
        for (int i = t; i < 2560; i += 256){      // x rows: 20 dw/px, linear
            int p = i / 20, kd = i - p*20;
            sAw[p*36 + kd] = xd[base + i];
        }
        const unsigned int* gd = (const unsigned int*)grd;
        size_t gb = (size_t)b*1024 + (size_t)u*128;
        if (t < 128) sAw[t*36 + 20] = gd[gb + t]; // grid: 1 dw/px (k 40,41)
    } else {
        const float* xf = (const float*)xin;
        size_t base = ((size_t)b*1024 + u*128)*40;
        for (int i = t; i < 2560; i += 256){
            int p = i / 20, kd = i - p*20;
            sAw[p*36 + kd] = packbf2(xf[base + 2*i], xf[base + 2*i + 1]);
        }
        const float* gf = (const float*)grd;
        size_t gb = ((size_t)b*1024 + u*128)*2;
        if (t < 128) sAw[t*36 + 20] = packbf2(gf[gb + 2*t], gf[gb + 2*t + 1]);
    }
    for (int i = t; i < 1920; i += 256){          // zero k 42..63 (dw 21..35)
        int p = i / 15, j = i - p*15;
        sAw[p*36 + 21 + j] = 0;
    }
    __syncthreads();
    int ln = t & 15, qd = (t & 63) >> 4, wv = t >> 6;
    const float* gbias = (const float*)(img + 4608);
    // B fragments direct from gFC0 image
    bfv8 bfr[4][2];
    #pragma unroll
    for (int nt = 0; nt < 4; ++nt)
        #pragma unroll
        for (int ks = 0; ks < 2; ++ks)
            bfr[nt][ks] = *reinterpret_cast<const bfv8*>(&img[(nt*16 + ln)*72 + ks*32 + qd*8]);
    // 8 m-tiles, 2 per wave
    bfv8 a_[2][2];
    #pragma unroll
    for (int mi = 0; mi < 2; ++mi){
        int mt = wv*2 + mi;
        a_[mi][0] = *reinterpret_cast<const bfv8*>(&sA[(mt*16 + ln)*72 + qd*8]);
        a_[mi][1] = *reinterpret_cast<const bfv8*>(&sA[(mt*16 + ln)*72 + 32 + qd*8]);
    }
    fv4 acc[2][4];
    #pragma unroll
    for (int mi = 0; mi < 2; ++mi)
        #pragma unroll
        for (int nt = 0; nt < 4; ++nt){
            fv4 a = (fv4){0.f,0.f,0.f,0.f};
            a = __builtin_amdgcn_mfma_f32_16x16x32_bf16(a_[mi][0], bfr[nt][0], a, 0, 0, 0);
            a = __builtin_amdgcn_mfma_f32_16x16x32_bf16(a_[mi][1], bfr[nt][1], a, 0, 0, 0);
            acc[mi][nt] = a;
        }
    __syncthreads();
    // ---- C -> sC[c][68 dw] (4 rows x 34, x-pads zeroed) ----
    unsigned int* sCd = (unsigned int*)sA;   // [c][68 dw]
    {
        int c = t >> 2, r = t & 3;           // zero x=32,33 pad dword per (c,row)
        sCd[c*68 + r*17 + 16] = 0;
    }
    #pragma unroll
    for (int mi = 0; mi < 2; ++mi)
        #pragma unroll
        for (int nt = 0; nt < 4; ++nt){
            int c = nt*16 + ln;
            float bb = gbias[c];
            int pl = (wv*2 + mi)*16 + qd*4;  // local px, 4 consecutive, same row
            int y = pl >> 5, x = pl & 31;
            int di = c*68 + y*17 + (x >> 1);
            sCd[di]     = packbf2(acc[mi][nt][0] + bb, acc[mi][nt][1] + bb);
            sCd[di + 1] = packbf2(acc[mi][nt][2] + bb, acc[mi][nt][3] + bb);
        }
    __syncthreads();
    // ---- coalesced writeback of block-owned 272B runs ----
    unsigned int* hw = (unsigned int*)(h + (size_t)b*73984);
    for (int i = t; i < 4352; i += 256){
        int c = i / 68, d = i - c*68;
        hw[c*578 + u*68 + d] = sCd[i];
    }
    if (u == 7){                              // rows y=32,33 zero (full pad rows)
        for (int i = t; i < 2176; i += 256){
            int c = i / 34, d = i - c*34;
            hw[c*578 + 544 + d] = 0;
        }
    }
}

// ---------------- forward truncated DFT via MFMA, 4 channels per block -------
// grid 4096 = 256 b x 16 ch-groups; writes hft [cg][b][m][8bf16] (coalesced)
// F1 (x-DFT): C1[(c,y)][2kx+s] = sum_x h[c][y][x] * gB1  (K=64, x pad)
// F2 (y-DFT): C2[(c,kx)][2ky+s] = sum_{2y+p} Gx * gB2    (K=96, pad)
// B operands read DIRECTLY from global images (L2-resident, fragment-ready) —
// no per-block image rebuild; LDS 30.7 KB -> 5 blocks/CU.
__global__ __launch_bounds__(256) void k_fwd(const bf16* __restrict__ h,
                                             unsigned int* __restrict__ hft,
                                             const unsigned short* __restrict__ fwdimg){
    __shared__ unsigned short lds[15360];   // 30,720 B
    unsigned short* sA1 = lds;              // 144 rows x 72 (rows=(c*34+y), k=x pad 64)
    unsigned short* sA2 = lds + 10368;      // 48 x 104 (rows=(c*12+kx), kappa=2y+p pad 96)
    unsigned int* sA1w = (unsigned int*)sA1;
    unsigned int* sA2w = (unsigned int*)sA2;
    const unsigned short* gB1 = fwdimg;          // [row<32][64 u16]
    const unsigned short* gB2 = fwdimg + 2048;   // [row<48][96 u16]
    int blk = blockIdx.x;
    int b = blk >> 4, c0 = (blk & 15) * 4;
    int t = threadIdx.x;
    // stage h (4 planes) into sA1 rows (c*34+y), dword granularity (coalesced)
    const unsigned int* srcp = (const unsigned int*)(h + (size_t)b*73984 + (size_t)c0*1156);
    for (int i = t; i < 2312; i += 256){
        int c = i / 578; int rem = i - c*578;
        int y = rem / 17; int d = rem - y*17;
        sA1w[(c*34 + y)*36 + d] = srcp[i];
    }
    // zero x-pad dwords 17..31 of rows 0..135
    for (int i = t; i < 2040; i += 256){
        int r = i / 15, d = i - r*15;
        sA1w[r*36 + 17 + d] = 0;
    }
    // zero tail rows 136..143 entirely
    for (int i = t; i < 288; i += 256){
        int r = 136 + i / 36, d = i - (i/36)*36;
        sA1w[r*36 + d] = 0;
    }
    // zero sA2 kappa pad [68,96) = dwords 34..47 of each row
    for (int i = t; i < 672; i += 256){
        int r = i / 14, d = i - r*14;
        sA2w[r*52 + 34 + d] = 0;
    }
    __syncthreads();
    int ln = t & 15, qd = (t & 63) >> 4, wv = t >> 6;
    // ---- F1: 9 M-tiles x 2 N-tiles, K=64; wave owns one nt (static frag idx) ----
    {
        int ntw = wv & 1;
        bfv8 b1f[2];
        #pragma unroll
        for (int ks = 0; ks < 2; ++ks)
            b1f[ks] = *reinterpret_cast<const bfv8*>(&gB1[(ntw*16 + ln)*64 + ks*32 + qd*8]);
        int col = ntw*16 + ln;
        int kx = col >> 1, s = col & 1;
        for (int mt = (wv >> 1); mt < 9; mt += 2){
            fv4 acc = (fv4){0.f,0.f,0.f,0.f};
            #pragma unroll
            for (int ks = 0; ks < 2; ++ks){
                bfv8 a = *reinterpret_cast<const bfv8*>(&sA1[(mt*16 + ln)*72 + ks*32 + qd*8]);
                acc = __builtin_amdgcn_mfma_f32_16x16x32_bf16(a, b1f[ks], acc, 0, 0, 0);
            }
            if (col < 24){
                #pragma unroll
                for (int rr = 0; rr < 4; ++rr){
                    int r = mt*16 + qd*4 + rr;
                    if (r < 136){
                        int c = r / 34, y = r - c*34;
                        sA2[(c*12 + kx)*104 + 2*y + s] = f2us(acc[rr]);
                    }
                }
            }
        }
    }
    __syncthreads();
    // ---- F2: 3 M-tiles x 3 N-tiles, K=96; scatter into sC (reuse sA1) ----
    unsigned short* sC = sA1;   // [m][9]: s*4+c at stride 9 (288*9 = 2592 u16)
    for (int tau = wv; tau < 9; tau += 4){
        int mt = tau / 3, nt = tau - (tau/3)*3;
        fv4 acc = (fv4){0.f,0.f,0.f,0.f};
        #pragma unroll
        for (int ks = 0; ks < 3; ++ks){
            bfv8 a  = *reinterpret_cast<const bfv8*>(&sA2[(mt*16 + ln)*104 + ks*32 + qd*8]);
            bfv8 bb = *reinterpret_cast<const bfv8*>(&gB2[(nt*16 + ln)*96 + ks*32 + qd*8]);
            acc = __builtin_amdgcn_mfma_f32_16x16x32_bf16(a, bb, acc, 0, 0, 0);
        }
        int col = nt*16 + ln;
        int ky = col >> 1, s = col & 1;
        #pragma unroll
        for (int rr = 0; rr < 4; ++rr){
            int r = mt*16 + qd*4 + rr;
            int c = r / 12, kxx = r - c*12;
            sC[(ky*12 + kxx)*9 + s*4 + c] = f2us(acc[rr]);
        }
    }
    __syncthreads();
    // ---- fully-coalesced writeback: block owns hft[cg][b][*] = 1152 dwords ----
    unsigned int* dst = hft + ((size_t)(c0 >> 2)*256 + b)*1152;
    for (int d = t; d < 1152; d += 256){
        int m = d >> 2, j = d & 3;
        unsigned int lo = sC[m*9 + 2*j];
        unsigned int hi = sC[m*9 + 2*j + 1];
        dst[d] = lo | (hi << 16);
    }
}

// ---------------- per-mode channel mix as bf16 MFMA GEMM ---------------------
// grid 576 = 288 modes x 2 M-halves of 128; C[128,128] = A[128,128] x B[128,128]
// A kappa order: kappa = cg*8+u (u<4: Re(c=cg*4+u), u>=4: Im), B staged to match.
// XCD line-mate swizzle: m-quads (same q=m>>2, same mh) get block ids differing
// by multiples of 8 -> same XCD L2 -> hft/weight 64B lines fetched once.
__global__ __launch_bounds__(256) void k_mixm(const unsigned short* __restrict__ hft,
                                              const void* __restrict__ sc_w1,
                                              const void* __restrict__ sc_w2,
                                              unsigned int* __restrict__ mixed, int layer,
                                              const float* __restrict__ flg){
    __shared__ unsigned short sB[128*136];   // BT[n][kappa], row stride 136
    const bool f32 = (flg[0] > 0.5f);
    int B = blockIdx.x;
    int x8 = B & 7, w8 = B >> 3;
    int r4 = w8 & 3, g = w8 >> 2;     // g < 18
    int u = g*8 + x8;                 // u < 144
    int mh = u & 1;
    int m  = (u >> 1)*4 + r4;         // m < 288
    int b0 = mh * 128;
    int t = threadIdx.x;
    int kyi = m / 12, kx = m - kyi*12;
    const void* w = (kyi < 12) ? sc_w1 : sc_w2;
    int r = (kyi < 12) ? kyi : kyi - 12;
    size_t wbase = (size_t)layer * 64*64*144*2;
    for (int idx = t; idx < 4096; idx += 256){     // idx = i*64+o
        int i = idx >> 6, o = idx & 63;
        size_t off = wbase + (((size_t)idx*12 + r)*12 + kx)*2;
        float wr = rdf(w, off, f32);
        float wi = rdf(w, off+1, f32);
        int kre = ((i >> 2) << 3) + (i & 3);       // kappa of Re(c=i)
        sB[o*136 + kre]          = f2us(wr);
        sB[(o+64)*136 + kre]     = f2us(wi);
        sB[o*136 + kre + 4]      = f2us(-wi);
        sB[(o+64)*136 + kre + 4] = f2us(wr);
    }
    __syncthreads();
    int ln = t & 15, qd = (t & 63) >> 4, wv = t >> 6;
    // A fragments: A[row][kappa=ks*32+qd*8 ..+7] = hft[g=ks*4+qd][row][m][0..7]
    bfv8 af[2][4];
    int arow = b0 + wv*32 + ln;
    #pragma unroll
    for (int tm = 0; tm < 2; ++tm)
        #pragma unroll
        for (int ks = 0; ks < 4; ++ks){
            int gg = ks*4 + qd;
            af[tm][ks] = *reinterpret_cast<const bfv8*>(
                hft + (((size_t)gg*256 + arow + tm*16)*288 + m)*8);
        }
    fv4 acc[2][8];
    #pragma unroll
    for (int tm=0;tm<2;++tm)
        #pragma unroll
        for (int tn=0;tn<8;++tn) acc[tm][tn] = (fv4){0.f,0.f,0.f,0.f};
    #pragma unroll
    for (int ks = 0; ks < 4; ++ks){
        bfv8 bfr[8];
        #pragma unroll
        for (int tn = 0; tn < 8; ++tn)
            bfr[tn] = *reinterpret_cast<const bfv8*>(&sB[(tn*16 + ln)*136 + ks*32 + qd*8]);
        #pragma unroll
        for (int tm = 0; tm < 2; ++tm)
            #pragma unroll
            for (int tn = 0; tn < 8; ++tn)
                acc[tm][tn] = __builtin_amdgcn_mfma_f32_16x16x32_bf16(af[tm][ks], bfr[tn], acc[tm][tn], 0, 0, 0);
    }
    __syncthreads();
    // C -> LDS (reuse sB): C[row][col], row stride 136; C/D map row=qd*4+r, col=ln
    #pragma unroll
    for (int tm = 0; tm < 2; ++tm)
        #pragma unroll
        for (int tn = 0; tn < 8; ++tn)
            #pragma unroll
            for (int rr = 0; rr < 4; ++rr){
                int row = wv*32 + tm*16 + qd*4 + rr;
                int col = tn*16 + ln;
                sB[row*136 + col] = f2us(acc[tm][tn][rr]);
            }
    __syncthreads();
    // pack (r,i) and write mixed[b][m][o] — 256B contiguous per (b,m), coalesced
    for (int idx = t; idx < 8192; idx += 256){
        int row = idx >> 6, o = idx & 63;
        unsigned int pr = ((unsigned int)sB[row*136 + o]) |
                          (((unsigned int)sB[row*136 + o + 64]) << 16);
        mixed[((size_t)(b0 + row)*288 + m)*64 + o] = pr;
    }
}

// ---------------- pointwise 64x64 channel GEMM (wc path) as MFMA, IN PLACE ---
// grid 1280: b = blk&255, u = blk>>8 (5 px-chunks of 240; chunks of same b
// co-XCD: ids differ by 256). C[240px][64o] = A[240px][64c] x w[o][c]^T + bias.
// Per-chunk in-place: block reads/writes only its own px range (disjoint).
__global__ __launch_bounds__(256) void k_wc(bf16* __restrict__ h,
                                            const void* __restrict__ wc_w,
                                            const void* __restrict__ wc_b,
                                            int layer,
                                            const float* __restrict__ flg){
    __shared__ unsigned short sA[240*72];   // A[p][c], stride 72; reused as sC[64][240]
    __shared__ unsigned short sBT[64*72];   // BT[o][c], stride 72
    __shared__ float sb[64];
    const bool f32 = (flg[0] > 0.5f);
    int blk = blockIdx.x;
    int b = blk & 255, u = blk >> 8;
    int px0 = u*240;
    int npx = 1156 - px0; if (npx > 240) npx = 240;   // 240 or 196
    int ndp = npx >> 1;                                // 120 or 98
    int t = threadIdx.x;
    size_t wbase = (size_t)layer*4096;
    for (int i = t; i < 4096; i += 256){               // wc_w[l][o][c] -> BT[o][c]
        int o = i >> 6, c = i & 63;
        sBT[o*72 + c] = f2us(rdf(wc_w, wbase + i, f32));
    }
    if (t < 64) sb[t] = rdf(wc_b, layer*64 + t, f32);
    // stage A transposed: dword-granular reads of h (always bf16 workspace)
    const unsigned int* srcd = (const unsigned int*)(h + (size_t)b*73984);
    for (int i = t; i < 7680; i += 256){
        int c = i / 120, dp = i - c*120;
        unsigned int v = (dp < ndp) ? srcd[c*578 + (px0 >> 1) + dp] : 0u;
        sA[(2*dp)*72 + c]     = (unsigned short)(v & 0xffff);
        sA[(2*dp + 1)*72 + c] = (unsigned short)(v >> 16);
    }
    __syncthreads();
    int ln = t & 15, qd = (t & 63) >> 4, wv = t >> 6;
    bfv8 bfr[4][2];
    #pragma unroll
    for (int nt = 0; nt < 4; ++nt)
        #pragma unroll
        for (int ks = 0; ks < 2; ++ks)
            bfr[nt][ks] = *reinterpret_cast<const bfv8*>(&sBT[(nt*16 + ln)*72 + ks*32 + qd*8]);
    // 15 m-tiles: wave wv handles mt = wv + 4*mi (mi<4, skip mt>=15)
    bfv8 a_[4][2];
    #pragma unroll
    for (int mi = 0; mi < 4; ++mi){
        int mt = wv + mi*4;
        if (mt < 15){
            a_[mi][0] = *reinterpret_cast<const bfv8*>(&sA[(mt*16 + ln)*72 + qd*8]);
            a_[mi][1] = *reinterpret_cast<const bfv8*>(&sA[(mt*16 + ln)*72 + 32 + qd*8]);
        }
    }
    fv4 acc[4][4];
    #pragma unroll
    for (int mi = 0; mi < 4; ++mi){
        int mt = wv + mi*4;
        if (mt < 15){
            #pragma unroll
            for (int nt = 0; nt < 4; ++nt){
                fv4 a = (fv4){0.f,0.f,0.f,0.f};
                a = __builtin_amdgcn_mfma_f32_16x16x32_bf16(a_[mi][0], bfr[nt][0], a, 0, 0, 0);
                a = __builtin_amdgcn_mfma_f32_16x16x32_bf16(a_[mi][1], bfr[nt][1], a, 0, 0, 0);
                acc[mi][nt] = a;
            }
        }
    }
    __syncthreads();
    // C -> sC[o][240] (transpose back), bias added
    unsigned int* sCd = (unsigned int*)sA;   // [o][120 dw]
    #pragma unroll
    for (int mi = 0; mi < 4; ++mi){
        int mt = wv + mi*4;
        if (mt < 15){
            #pragma unroll
            for (int nt = 0; nt < 4; ++nt){
                int o = nt*16 + ln;
                float bb = sb[o];
                int p0 = mt*16 + qd*4;
                sCd[o*120 + (p0 >> 1)]     = packbf2(acc[mi][nt][0] + bb, acc[mi][nt][1] + bb);
                sCd[o*120 + (p0 >> 1) + 1] = packbf2(acc[mi][nt][2] + bb, acc[mi][nt][3] + bb);
            }
        }
    }
    __syncthreads();
    // coalesced in-place writeback (own px range only)
    unsigned int* dstd = (unsigned int*)(h + (size_t)b*73984);
    for (int i = t; i < 7680; i += 256){
        int o = i / 120, dp = i - o*120;
        if (dp < ndp) dstd[o*578 + (px0 >> 1) + dp] = sCd[o*120 + dp];
    }
}

// ---------------- inverse truncated DFT as MFMA GEMMs; in-place add + gelu ---
// grid 4096 = 256 b x 16 o-groups of 4, XCD line-mate swizzled:
//   B = z*32 + s*8 + x  ->  b = (z>>2)*8 + x, og = (z&3)*4 + s
//   og-quads of the same b (which share each 64B line of mixed) land on the
//   same XCD (ids differ by 8/16/24) -> line fetched once into that L2.
// B operands (invBT/invW2) are read DIRECTLY from global images (L2-resident,
// fragment-ready layout); OOB rows give garbage discarded by col/y predicates.
// LDS 36.9 KB -> 4 blocks/CU.
__global__ __launch_bounds__(256) void k_invm(const unsigned int* __restrict__ mixed,
                                              const float* __restrict__ tabs,
                                              bf16* __restrict__ hio, int layer){
    __shared__ unsigned short lds[18448];   // 36,896 B total
    unsigned short* sA  = lds;              // 96*40 (step A only; overlaps htile)
    unsigned short* sG  = lds + 4624;       // 4*48*72 (htile = lds[0..4624))
    unsigned int* ldsw  = (unsigned int*)lds;
    int B = blockIdx.x;
    int x8 = B & 7, s4 = (B >> 3) & 3, z = B >> 5;
    int b  = (z >> 2)*8 + x8;
    int o0 = ((z & 3)*4 + s4)*4;
    int t = threadIdx.x;
    const unsigned short* gBT16 = (const unsigned short*)(tabs + 2448);  // [n][32 u16]
    const unsigned short* gW216 = (const unsigned short*)(tabs + 3536);  // [y][64 u16]
    // sA from mixed[b][m][o]: 16B per (m), stride 256B (lines shared intra-XCD)
    const unsigned int* msrc = mixed + (size_t)b*18432 + o0;
    for (int i = t; i < 1152; i += 256){
        int m = i >> 2, ch = i & 3;
        int kyi = m / 12, kx = m - kyi*12;
        ((unsigned int*)sA)[(ch*24 + kyi)*20 + kx] = msrc[(size_t)m*64 + ch];
    }
    for (int i = t; i < 384; i += 256)       // zero k 24..31 (dw 12..15)
        ((unsigned int*)sA)[(i >> 2)*20 + 12 + (i & 3)] = 0;
    // sG: zero only read pads — rows x in [34,48): dw 0..31; rows x<34: dw 24..31
    for (int i = t; i < 1792; i += 256){
        int r = i >> 5;
        int ch = r / 14, x = 34 + (r - (r/14)*14);
        ((unsigned int*)sG)[(ch*48 + x)*36 + (i & 31)] = 0;
    }
    for (int i = t; i < 1088; i += 256){
        int r = i >> 3;
        int ch = r / 34, x = r - (r/34)*34;
        ((unsigned int*)sG)[(ch*48 + x)*36 + 24 + (i & 7)] = 0;
    }
    __syncthreads();
    int ln = t & 15, qd = (t & 63) >> 4, wv = t >> 6;
    // ---- step A: 30 tiles (6 M x 5 N), K=32; B-frag direct from gBT image ----
    for (int tau = wv; tau < 30; tau += 4){
        int mt = tau / 5, nt = tau - mt*5;
        bfv8 a  = *reinterpret_cast<const bfv8*>(&sA[(mt*16 + ln)*40 + qd*8]);
        bfv8 bb = *reinterpret_cast<const bfv8*>(&gBT16[(nt*16 + ln)*32 + qd*8]);
        fv4 acc = (fv4){0.f,0.f,0.f,0.f};
        acc = __builtin_amdgcn_mfma_f32_16x16x32_bf16(a, bb, acc, 0, 0, 0);
        int col = nt*16 + ln;
        if (col < 68){
            int x = col >> 1, ri = col & 1;
            #pragma unroll
            for (int rr = 0; rr < 4; ++rr){
                int row = mt*16 + qd*4 + rr;
                int ch = row / 24, kyi = row - ch*24;
                sG[(ch*48 + x)*72 + 2*kyi + ri] = f2us(acc[rr]);
            }
        }
    }
    __syncthreads();
    // ---- stage htile (4 contiguous ch-planes) into lds[0..2312) dwords ----
    const unsigned int* hsrc = (const unsigned int*)(hio + (size_t)b*73984 + (size_t)o0*1156);
    for (int i = t; i < 2312; i += 256) ldsw[i] = hsrc[i];
    __syncthreads();
    // ---- step B: wave = ch; 3x3 tiles, K=64 (2 MFMAs); A-frag direct from gW2 ----
    int ch = wv;
    #pragma unroll
    for (int mt = 0; mt < 3; ++mt){
        bfv8 a0 = *reinterpret_cast<const bfv8*>(&gW216[(mt*16 + ln)*64 + qd*8]);
        bfv8 a1 = *reinterpret_cast<const bfv8*>(&gW216[(mt*16 + ln)*64 + 32 + qd*8]);
        #pragma unroll
        for (int nt = 0; nt < 3; ++nt){
            bfv8 b0 = *reinterpret_cast<const bfv8*>(&sG[(ch*48 + nt*16 + ln)*72 + qd*8]);
            bfv8 b1 = *reinterpret_cast<const bfv8*>(&sG[(ch*48 + nt*16 + ln)*72 + 32 + qd*8]);
            fv4 acc = (fv4){0.f,0.f,0.f,0.f};
            acc = __builtin_amdgcn_mfma_f32_16x16x32_bf16(a0, b0, acc, 0, 0, 0);
            acc = __builtin_amdgcn_mfma_f32_16x16x32_bf16(a1, b1, acc, 0, 0, 0);
            int x = nt*16 + ln;
            if (x < 34){
                #pragma unroll
                for (int rr = 0; rr < 4; ++rr){
                    int y = mt*16 + qd*4 + rr;
                    if (y < 34){
                        int off = ch*1156 + y*34 + x;
                        float v = acc[rr] + us2f(lds[off]);
                        if (layer < 3) v = gelu_f(v);
                        lds[off] = f2us(v);
                    }
                }
            }
        }
    }
    __syncthreads();
    // ---- coalesced dword writeback ----
    unsigned int* hdst = (unsigned int*)(hio + (size_t)b*73984 + (size_t)o0*1156);
    for (int i = t; i < 2312; i += 256) hdst[i] = ldsw[i];
}

// ---------------- 8x8/stride4 VALID conv -> gelu -> pe2 scale ----------------
__global__ __launch_bounds__(256) void k_pe(const bf16* __restrict__ h,
                                            const void* __restrict__ pw,
                                            const void* __restrict__ pb,
                                            const void* __restrict__ p2w,
                                            const void* __restrict__ p2b,
                                            float* __restrict__ p49,
                                            const float* __restrict__ flg){
    __shared__ float red[256];
    const bool f32 = (flg[0] > 0.5f);
    int bid = blockIdx.x;          // b*49 + py*7 + px
    int b = bid / 49, r = bid - b*49;
    int py = r / 7, px = r - py*7;
    int t = threadIdx.x;
    const bf16* hb = h + (size_t)b*73984 + (py*4)*34 + px*4;
    float partial = 0.f;
    for (int tt = t; tt < 4096; tt += 256){
        int c = tt >> 6, k = tt & 63, ky = k >> 3, kx = k & 7;
        partial += bff(hb[(size_t)c*1156 + ky*34 + kx]) * rdf(pw, tt, f32);
    }
    red[t] = partial;
    __syncthreads();
    for (int s = 128; s > 0; s >>= 1){
        if (t < s) red[t] += red[t + s];
        __syncthreads();
    }
    if (t == 0){
        float v = red[0] + rdf(pb, 0, f32);
        v = gelu_f(v);
        p49[bid] = v * rdf(p2w, 0, f32) + rdf(p2b, 0, f32);
    }
}

// ---------------- sentence MLP 384->32->32->16 (relu,relu,lin) ---------------
__global__ __launch_bounds__(64) void k_sent(const void* __restrict__ se,
                                             const void* __restrict__ w1, const void* __restrict__ b1,
                                             const void* __restrict__ w2, const void* __restrict__ b2,
                                             const void* __restrict__ w3, const void* __restrict__ b3,
                                             float* __restrict__ outv,
                                             const float* __restrict__ flg){
    __shared__ float s1[32], s2[32];
    const bool f32 = (flg[0] > 0.5f);
    int b = blockIdx.x, t = threadIdx.x;
    if (t < 32){
        float acc = rdf(b1, t, f32);
        size_t rbase = (size_t)b*384;
        for (int k = 0; k < 384; ++k) acc += rdf(se, rbase + k, f32) * rdf(w1, k*32 + t, f32);
        s1[t] = fmaxf(acc, 0.f);
    }
    __syncthreads();
    if (t < 32){
        float acc = rdf(b2, t, f32);
        for (int k = 0; k < 32; ++k) acc += s1[k] * rdf(w2, k*32 + t, f32);
        s2[t] = fmaxf(acc, 0.f);
    }
    __syncthreads();
    if (t < 16){
        float acc = rdf(b3, t, f32);
        for (int k = 0; k < 32; ++k) acc += s2[k] * rdf(w3, k*16 + t, f32);
        outv[b*16 + t] = acc;
    }
}

// ---------------- xp MLP 49->32->32->16 (silu,silu,lin) ----------------------
__global__ __launch_bounds__(64) void k_xp(const float* __restrict__ p49,
                                           const void* __restrict__ w1, const void* __restrict__ b1,
                                           const void* __restrict__ w2, const void* __restrict__ b2,
                                           const void* __restrict__ w3, const void* __restrict__ b3,
                                           float* __restrict__ outv,
                                           const float* __restrict__ flg){
    __shared__ float s1[32], s2[32];
    const bool f32 = (flg[0] > 0.5f);
    int b = blockIdx.x, t = threadIdx.x;
    if (t < 32){
        float acc = rdf(b1, t, f32);
        const float* row = p49 + b*49;
        for (int k = 0; k < 49; ++k) acc += row[k] * rdf(w1, k*32 + t, f32);
        s1[t] = silu_f(acc);
    }
    __syncthreads();
    if (t < 32){
        float acc = rdf(b2, t, f32);
        for (int k = 0; k < 32; ++k) acc += s1[k] * rdf(w2, k*32 + t, f32);
        s2[t] = silu_f(acc);
    }
    __syncthreads();
    if (t < 16){
        float acc = rdf(b3, t, f32);
        for (int k = 0; k < 32; ++k) acc += s2[k] * rdf(w3, k*16 + t, f32);
        outv[b*16 + t] = acc;
    }
}

// ---------------- pu MLP part A: 32->128->256 (silu,silu) --------------------
__global__ __launch_bounds__(256) void k_puA(const float* __restrict__ xemb,
                                             const float* __restrict__ semb,
                                             const void* __restrict__ w1, const void* __restrict__ b1,
                                             const void* __restrict__ w2, const void* __restrict__ b2,
                                             float* __restrict__ h2buf,
                                             const float* __restrict__ flg){
    __shared__ float ein[32];
    __shared__ float h1[128];
    const bool f32 = (flg[0] > 0.5f);
    int b = blockIdx.x, t = threadIdx.x;
    if (t < 16) ein[t] = xemb[b*16 + t];
    else if (t < 32) ein[t] = semb[b*16 + (t - 16)];
    __syncthreads();
    if (t < 128){
        float acc = rdf(b1, t, f32);
        for (int k = 0; k < 32; ++k) acc += ein[k] * rdf(w1, k*128 + t, f32);
        h1[t] = silu_f(acc);
    }
    __syncthreads();
    {
        float acc = rdf(b2, t, f32);
        for (int k = 0; k < 128; ++k) acc += h1[k] * rdf(w2, k*256 + t, f32);
        h2buf[(size_t)b*256 + t] = silu_f(acc);
    }
}

// ---------------- pu MLP part B: 256->1156 GEMM ------------------------------
// grid 1280 = 256 b (fast) x 5 n-chunks of 232
__global__ __launch_bounds__(256) void k_puB(const float* __restrict__ h2buf,
                                             const void* __restrict__ w3, const void* __restrict__ b3,
                                             float* __restrict__ emb,
                                             const float* __restrict__ flg){
    __shared__ float sh2[256];
    const bool f32 = (flg[0] > 0.5f);
    int blk = blockIdx.x;
    int b = blk & 255, nc = blk >> 8;
    int t = threadIdx.x;
    sh2[t] = h2buf[(size_t)b*256 + t];
    __syncthreads();
    int e = nc*232 + t;
    if (t < 232 && e < 1156){
        float acc = rdf(b3, e, f32);
        if (f32){
            const float* wp = (const float*)w3 + e;
            #pragma unroll 4
            for (int k = 0; k < 256; ++k) acc += sh2[k] * wp[(size_t)k*1156];
        } else {
            const bf16* wp = (const bf16*)w3 + e;
            #pragma unroll 4
            for (int k = 0; k < 256; ++k) acc += sh2[k] * bff(wp[(size_t)k*1156]);
        }
        emb[(size_t)b*1156 + e] = acc;
    }
}

// ---------------- final: crop, concat emb, fc1(MFMA)+gelu, fc2(MFMA) ---------
// grid 512 = 256 b x 2 halves; 8 iters of 2 rows (64 px).
// fc1: C[64px,128j] = A[px,c<64] x w1 (K=64) + rank-1 emb add; fc2: K=128, N=16(4)
__global__ __launch_bounds__(256, 3) void k_final(const bf16* __restrict__ h,
                                                  const float* __restrict__ emb,
                                                  const void* __restrict__ w1, const void* __restrict__ b1,
                                                  const void* __restrict__ w2, const void* __restrict__ b2,
                                                  void* __restrict__ out,
                                                  const float* __restrict__ flg){
    __shared__ unsigned short sw1t[128*72];   // w1T[j][c], stride 72 (16B-aligned rows)
    __shared__ unsigned short sw2t[16*136];   // w2T[n][j], rows 4..15 zero
    __shared__ float sw1e[128];               // w1[64][j] (emb channel)
    __shared__ float sb1[128];
    __shared__ float sb2[4];
    __shared__ unsigned short spx[64*66];     // input[c][px], stride 66 (odd dwords)
    __shared__ float sembp[64];               // emb[px]
    __shared__ unsigned short sh2[128*66];    // hid[j][px], stride 66
    const bool f32 = (flg[0] > 0.5f);
    int blk = blockIdx.x;
    int b = blk >> 1, half = blk & 1;
    int t = threadIdx.x;
    for (int i = t; i < 8320; i += 256){       // w1 [c=65][j=128]
        int c = i >> 7, j = i & 127;
        float v = rdf(w1, i, f32);
        if (c < 64) sw1t[j*72 + c] = f2us(v);
        else sw1e[j] = v;
    }
    if (t < 128) sb1[t] = rdf(b1, t, f32);
    for (int i = t; i < 2176; i += 256){       // w2 [j=128][k=4] -> w2T[n][j]
        int n = i / 136, j = i - n*136;
        float v = (n < 4 && j < 128) ? rdf(w2, j*4 + n, f32) : 0.f;
        sw2t[i] = f2us(v);
    }
    if (t < 4) sb2[t] = rdf(b2, t, f32);
    __syncthreads();
    int ln = t & 15, qd = (t & 63) >> 4, wv = t >> 6;
    // hoist B fragments (weights) into registers
    bfv8 bw1[8][2];
    #pragma unroll
    for (int tn = 0; tn < 8; ++tn)
        #pragma unroll
        for (int ks = 0; ks < 2; ++ks)
            bw1[tn][ks] = *reinterpret_cast<const bfv8*>(&sw1t[(tn*16 + ln)*72 + ks*32 + qd*8]);
    bfv8 bw2[4];
    #pragma unroll
    for (int ks = 0; ks < 4; ++ks)
        bw2[ks] = *reinterpret_cast<const bfv8*>(&sw2t[ln*136 + ks*32 + qd*8]);
    const bf16* hb = h + (size_t)b*73984;
    const float* eb = emb + (size_t)b*1156;
    for (int it = 0; it < 8; ++it){
        int y0 = half*16 + it*2;               // 2 rows = 64 px
        __syncthreads();
        for (int e = t; e < 2048; e += 256){   // stage spx[c][px] c-major
            int c = e >> 5, d = e & 31;
            int px = d*2;
            int y = y0 + (px >> 5), x = px & 31;
            float v0 = bff(hb[(size_t)c*1156 + y*34 + x]);
            int px1 = px + 1;
            int y1 = y0 + (px1 >> 5), x1 = px1 & 31;
            float v1 = bff(hb[(size_t)c*1156 + y1*34 + x1]);
            ((unsigned int*)spx)[c*33 + d] = packbf2(v0, v1);
        }
        if (t < 64){
            int y = y0 + (t >> 5), x = t & 31;
            sembp[t] = eb[y*34 + x];
        }
        __syncthreads();
        // fc1 MFMA: wave wv owns mtile wv (px = wv*16 + ...)
        fv4 acc[8];
        #pragma unroll
        for (int tn = 0; tn < 8; ++tn) acc[tn] = (fv4){0.f,0.f,0.f,0.f};
        #pragma unroll
        for (int ks = 0; ks < 2; ++ks){
            union { bfv8 v; unsigned short s[8]; } af;
            #pragma unroll
            for (int j = 0; j < 8; ++j)
                af.s[j] = spx[(ks*32 + qd*8 + j)*66 + wv*16 + ln];
            #pragma unroll
            for (int tn = 0; tn < 8; ++tn)
                acc[tn] = __builtin_amdgcn_mfma_f32_16x16x32_bf16(af.v, bw1[tn][ks], acc[tn], 0, 0, 0);
        }
        float ev[4];
        #pragma unroll
        for (int rr = 0; rr < 4; ++rr) ev[rr] = sembp[wv*16 + qd*4 + rr];
        #pragma unroll
        for (int tn = 0; tn < 8; ++tn){
            int col = tn*16 + ln;
            float we = sw1e[col];
            float bb1 = sb1[col];
            #pragma unroll
            for (int rr = 0; rr < 4; ++rr){
                float v = acc[tn][rr] + ev[rr]*we + bb1;
                sh2[col*66 + wv*16 + qd*4 + rr] = f2us(gelu_f(v));
            }
        }
        __syncthreads();
        // fc2 MFMA: K=128, N=16 (4 valid)
        fv4 a2 = (fv4){0.f,0.f,0.f,0.f};
        #pragma unroll
        for (int ks = 0; ks < 4; ++ks){
            union { bfv8 v; unsigned short s[8]; } af;
            #pragma unroll
            for (int j = 0; j < 8; ++j)
                af.s[j] = sh2[(ks*32 + qd*8 + j)*66 + wv*16 + ln];
            a2 = __builtin_amdgcn_mfma_f32_16x16x32_bf16(af.v, bw2[ks], a2, 0, 0, 0);
        }
        if (ln < 4){
            float bb2 = sb2[ln];
            #pragma unroll
            for (int rr = 0; rr < 4; ++rr){
                int pxl = wv*16 + qd*4 + rr;
                int y = y0 + (pxl >> 5), x = pxl & 31;
                size_t o = ((size_t)(b*32 + y)*32 + x)*4 + ln;
                float v = a2[rr] + bb2;
                if (f32) ((float*)out)[o] = v;
                else     ((bf16*)out)[o] = __float2bfloat16(v);
            }
        }
    }
}

extern "C" void kernel_launch(void* const* d_in, const int* in_sizes, int n_in,
                              void* d_out, int out_size, void* d_ws, size_t ws_size,
                              hipStream_t stream) {
    (void)in_sizes; (void)n_in; (void)out_size; (void)ws_size;
    const void* x     = d_in[0];
    const void* grd   = d_in[1];
    const void* se    = d_in[2];
    const void* fc0_w = d_in[3];
    const void* fc0_b = d_in[4];
    const void* sc_w1 = d_in[5];
    const void* sc_w2 = d_in[6];
    const void* wc_w  = d_in[7];
    const void* wc_b  = d_in[8];
    const void* pe1_w = d_in[9];
    const void* pe1_b = d_in[10];
    const void* pe2_w = d_in[11];
    const void* pe2_b = d_in[12];
    const void* sp_w1 = d_in[13];
    const void* sp_b1 = d_in[14];
    const void* sp_w2 = d_in[15];
    const void* sp_b2 = d_in[16];
    const void* sp_w3 = d_in[17];
    const void* sp_b3 = d_in[18];
    const void* xp_w1 = d_in[19];
    const void* xp_b1 = d_in[20];
    const void* xp_w2 = d_in[21];
    const void* xp_b2 = d_in[22];
    const void* xp_w3 = d_in[23];
    const void* xp_b3 = d_in[24];
    const void* pu_w1 = d_in[25];
    const void* pu_b1 = d_in[26];
    const void* pu_w2 = d_in[27];
    const void* pu_b2 = d_in[28];
    const void* pu_w3 = d_in[29];
    const void* pu_b3 = d_in[30];
    const void* fc1_w = d_in[31];
    const void* fc1_b = d_in[32];
    const void* fc2_w = d_in[33];
    const void* fc2_b = d_in[34];

    // workspace layout (float-unit offsets); total ~77 MB
    float* ws    = (float*)d_ws;
    bf16*  hA    = (bf16*)ws;                              // 18,939,904 bf16
    unsigned int* hft   = (unsigned int*)(ws + 9469952);   // 4,718,592 dwords (hft cg-panels)
    unsigned int* mixed = (unsigned int*)(ws + 14188544);  // 4,718,592 dwords ([b][m][o])
    float* tabs  = ws + 18907136;                          // 4,896 (DFT tables + inv images)
    float* p49   = ws + 18912032;                          // 12,544
    float* semb  = ws + 18924576;                          // 4,096
    float* xemb  = ws + 18928672;                          // 4,096
    float* emb   = ws + 18932768;                          // 295,936
    float* flag  = ws + 19228704;                          // 1
    float* h2buf = (float*)hft;                            // reuse: hft dead after layer loop
    // fwd B-images + fc0 weight image live in emb region (dead during layer
    // loop; k_puB writes emb only after the last k_invm; rebuilt each replay)
    float* fwdimg = emb;                                   // 5,696 floats

    k_probe<<<1, 256, 0, stream>>>(x, flag);
    k_tables<<<1, 256, 0, stream>>>(tabs, fwdimg, fc0_w, fc0_b, flag);
    k_fc0<<<2048, 256, 0, stream>>>(x, grd, (const unsigned short*)(fwdimg + 3328), hA, flag);

    for (int l = 0; l < 4; ++l){
        k_fwd<<<4096, 256, 0, stream>>>(hA, hft, (const unsigned short*)fwdimg);
        k_mixm<<<576, 256, 0, stream>>>((const unsigned short*)hft, sc_w1, sc_w2, mixed, l, flag);
        k_wc <<<1280, 256, 0, stream>>>(hA, wc_w, wc_b, l, flag);
        k_invm<<<4096, 256, 0, stream>>>(mixed, tabs, hA, l);
    }

    k_pe  <<<256*49, 256, 0, stream>>>(hA, pe1_w, pe1_b, pe2_w, pe2_b, p49, flag);
    k_sent<<<256, 64, 0, stream>>>(se, sp_w1, sp_b1, sp_w2, sp_b2, sp_w3, sp_b3, semb, flag);
    k_xp  <<<256, 64, 0, stream>>>(p49, xp_w1, xp_b1, xp_w2, xp_b2, xp_w3, xp_b3, xemb, flag);
    k_puA <<<256, 256, 0, stream>>>(xemb, semb, pu_w1, pu_b1, pu_w2, pu_b2, h2buf, flag);
    k_puB <<<1280, 256, 0, stream>>>(h2buf, pu_w3, pu_b3, emb, flag);
    k_final<<<512, 256, 0, stream>>>(hA, emb, fc1_w, fc1_b, fc2_w, fc2_b, d_out, flag);
}

// Round 8
// 1109.196 us; speedup vs baseline: 1.2758x; 1.0265x over previous
//
#include <hip/hip_runtime.h>
#include <hip/hip_bf16.h>
#include <math.h>

typedef __hip_bfloat16 bf16;
typedef __bf16 bfv8 __attribute__((ext_vector_type(8)));
typedef float fv4 __attribute__((ext_vector_type(4)));

__device__ __forceinline__ float bff(const bf16 x){ return __bfloat162float(x); }
// fast gelu: 0.5 v (1 + erf(v/sqrt2)); erf via A&S 7.1.26 (|err|<1.5e-7),
// branchless, hardware v_exp/v_rcp. ~14 VALU vs ocml erff's ~30 (branchy).
__device__ __forceinline__ float gelu_f(float v){
    float x = v * 0.70710678118654752f;
    float ax = fabsf(x);
    float t = __builtin_amdgcn_rcpf(1.0f + 0.3275911f * ax);
    float y = t*(0.254829592f + t*(-0.284496736f + t*(1.421413741f +
              t*(-1.453152027f + t*1.061405429f))));
    float er = 1.0f - y * __expf(-ax*ax);
    er = (x < 0.f) ? -er : er;
    return 0.5f * v * (1.0f + er);
}
__device__ __forceinline__ float silu_f(float v){
    return v / (1.f + __expf(-v));
}
// dtype-agnostic input read: f32 ? fp32 : bf16
__device__ __forceinline__ float rdf(const void* p, size_t i, bool f32){
    return f32 ? ((const float*)p)[i] : __bfloat162float(((const bf16*)p)[i]);
}
__device__ __forceinline__ unsigned int packbf2(float a, float b){
    __hip_bfloat162 v;
    v.x = __float2bfloat16(a);
    v.y = __float2bfloat16(b);
    return *reinterpret_cast<unsigned int*>(&v);
}
__device__ __forceinline__ float2 unpackbf2(unsigned int u){
    __hip_bfloat162 v = *reinterpret_cast<__hip_bfloat162*>(&u);
    return make_float2(__bfloat162float(v.x), __bfloat162float(v.y));
}
__device__ __forceinline__ float us2f(unsigned short u){
    unsigned int x = ((unsigned int)u) << 16;
    return __uint_as_float(x);
}
__device__ __forceinline__ unsigned short f2us(float f){
    bf16 v = __float2bfloat16(f);
    return *reinterpret_cast<unsigned short*>(&v);
}

// Geometry
// B=256, C=64, H=W=34 (padded), modes: ky in {0..11, 22..33} (24), kx in 0..11 (12)
// h layout (ws, bf16): [b][c][y][x], stride c = 1156, stride b = 73984
// hft layout: [cg<16][b<256][m<288][8 bf16] ; kappa = cg*8+u, u<4: Re(c=cg*4+u),
//             u>=4: Im(c=cg*4+u-4).  Writer (k_fwd) fully coalesced per block.
// mixed layout: [b<256][m<288][o<64] packed bf16x2 dwords (r,i); writer (k_mixm)
//             owns full 256B rows per (b,m).
// tabs: [0,1632) Wfy f32 | [1632,2448) Wfx f32 |
//       [2448,3536) invBT bf16 image (68x16 dw) | [3536,4624) invW2 bf16 image (34x32 dw)
// fwd images (in emb region, dead during layer loop):
//   gB1 [row<32][64 u16] | gB2 [row<48][96 u16] | gFC0 [c<64][72 u16] @ +3328 fl |
//   gFC0b [64 f32] @ +5632 fl
// All images fragment-ready: k_fwd/k_invm/k_fc0 read MFMA fragments DIRECTLY from
// global (16B-aligned rows, pads pre-zeroed; OOB rows discarded by predicates).

// ---------------- dtype probe ----------------
__global__ __launch_bounds__(256) void k_probe(const void* x, float* flag){
    __shared__ int wild;
    int t = threadIdx.x;
    if (t == 0) wild = 0;
    __syncthreads();
    const bf16* xb = (const bf16*)x;
    for (int i = t; i < 1024; i += 256){
        float v = bff(xb[i]);
        if (!(fabsf(v) < 1e10f)) wild = 1;
    }
    __syncthreads();
    if (t == 0) flag[0] = wild ? 1.f : 0.f;
}

// ---------------- tables ----------------
__global__ __launch_bounds__(256) void k_tables(float* tabs, float* fwdimg,
                                                const void* __restrict__ fc0w,
                                                const void* __restrict__ fc0b,
                                                const float* __restrict__ flg){
    int t = threadIdx.x;
    const bool f32 = (flg[0] > 0.5f);
    unsigned int* gBT = (unsigned int*)(tabs + 2448);   // [n<68][kd<16] bf16x2
    unsigned int* gW2 = (unsigned int*)(tabs + 3536);   // [y<34][kd<32] bf16x2
    unsigned short* gB1 = (unsigned short*)fwdimg;          // [row<32][64]
    unsigned short* gB2 = (unsigned short*)(fwdimg + 1024); // [row<48][96]
    unsigned short* gF  = (unsigned short*)(fwdimg + 3328); // [c<64][72]
    float* gFb = fwdimg + 5632;                             // [64]
    const float TWO_PI = 6.283185307179586f;
    // gFC0 image: BT[c][k] from fc0_w [k=42][c=64], k-pads zeroed
    for (int i = t; i < 4608; i += 256){
        int c = i / 72, k = i - c*72;
        float v = (k < 42) ? rdf(fc0w, (size_t)k*64 + c, f32) : 0.f;
        gF[i] = f2us(v);
    }
    if (t < 64) gFb[t] = rdf(fc0b, t, f32);
    // gB1: row=2kx+s (kx<12), k=x<34: e^{-i ang} component (s=0: cos, s=1: -sin)
    for (int i = t; i < 2048; i += 256){
        int row = i >> 6, k = i & 63;
        float v = 0.f;
        if (row < 24 && k < 34){
            int kx = row >> 1, s = row & 1;
            int ph = (kx * k) % 34;
            float ang = TWO_PI * (float)ph / 34.0f;
            float sn, cs;
            sincosf(ang, &sn, &cs);
            v = (s == 0) ? cs : -sn;
        }
        gB1[i] = f2us(v);
    }
    // gB2: row=2ky+s (kyi<24), kk=2y+p<68: realified [[wr,-wi],[wi,wr]] of e^{-i ang}
    for (int i = t; i < 4608; i += 256){
        int row = i / 96, kk = i - row*96;
        float v = 0.f;
        if (kk < 68){
            int kyi = row >> 1, s = row & 1;
            int y = kk >> 1, p = kk & 1;
            int ky = (kyi < 12) ? kyi : kyi + 10;
            int ph = (ky * y) % 34;
            float ang = TWO_PI * (float)ph / 34.0f;
            float sn, cs;
            sincosf(ang, &sn, &cs);
            float wr = cs, wi = -sn;
            v = (s == 0) ? ((p == 0) ? wr : -wi) : ((p == 0) ? wi : wr);
        }
        gB2[i] = f2us(v);
    }
    // invBT image: n=2x+ri (x<34), k=2kx+ri2; v = ri==0 ? (ri2==0? C : -S) : (ri2==0? S : C)
    // where C = ck*cos(ang), S = ck*sin(ang), ang = +2pi*(kx*x mod 34)/34, ck = (kx==0?1:2)
    for (int i = t; i < 1088; i += 256){
        int n = i >> 4, kd = i & 15;
        int x = n >> 1, ri = n & 1;
        int kx = kd;
        float v0 = 0.f, v1 = 0.f;
        if (kx < 12){
            int ph = (kx * x) % 34;
            float ang = TWO_PI * (float)ph / 34.0f;
            float s, c;
            sincosf(ang, &s, &c);
            float ck = (kx == 0) ? 1.0f : 2.0f;
            float C = ck * c, S = ck * s;
            v0 = (ri == 0) ? C : S;       // ri2 = 0
            v1 = (ri == 0) ? -S : C;      // ri2 = 1
        }
        gBT[i] = packbf2(v0, v1);
    }
    // invW2 image: y<34, k=2kyi+ri; v = (1/1156)*(ri==0? cos : -sin), ang=+2pi*(ky*y mod 34)/34
    for (int i = t; i < 1088; i += 256){
        int y = i >> 5, kd = i & 31;
        int kyi = kd;
        float v0 = 0.f, v1 = 0.f;
        if (kyi < 24){
            int ky = (kyi < 12) ? kyi : kyi + 10;
            int ph = (ky * y) % 34;
            float ang = TWO_PI * (float)ph / 34.0f;
            float s, c;
            sincosf(ang, &s, &c);
            v0 = c * (1.0f/1156.0f);
            v1 = -s * (1.0f/1156.0f);
        }
        gW2[i] = packbf2(v0, v1);
    }
}

// ---------------- fc0 as MFMA GEMM: concat(x,grid) @ fc0_w + b ---------------
// grid 2048: B -> b = (B>>6)*8 + (B&7), u = (B>>3)&7  (8 chunks of b co-XCD)
// Block: px in [u*128, u*128+128); C[128px][64c], K=42 pad 64.
// Weights read DIRECTLY from gFC0 image (L2-resident, fragment-ready).
// LDS = sA only (18.4 KB) -> 8 blocks/CU. x staged as dwords (bf16 path).
// Epilogue: C -> sC[c][4rows x 34] image, coalesced 272B-run writeback per c.
__global__ __launch_bounds__(256) void k_fc0(const void* __restrict__ xin,
                                             const void* __restrict__ grd,
                                             const unsigned short* __restrict__ img,
                                             bf16* __restrict__ h,
                                             const float* __restrict__ flg){
    __shared__ unsigned short sA[128*72];   // A[p][k] stride 72; reused as sC[64][68 dw]
    const bool f32 = (flg[0] > 0.5f);
    int B = blockIdx.x;
    int b = (B >> 6)*8 + (B & 7);
    int u = (B >> 3) & 7;
    int t = threadIdx.x;
    unsigned int* sAw = (unsigned int*)sA;
    if (!f32){
        const unsigned int* xd = (const unsigned int*)xin;
        size_t base = ((size_t)b*1024 + u*128)*20;
        for (int i = t; i < 2560; i += 256){      // x rows: 20 dw/px, linear
            int p = i / 20, kd = i - p*20;
            sAw[p*36 + kd] = xd[base + i];
        }
        const unsigned int* gd = (const unsigned int*)grd;
        size_t gb = (size_t)b*1024 + (size_t)u*128;
        if (t < 128) sAw[t*36 + 20] = gd[gb + t]; // grid: 1 dw/px (k 40,41)
    } else {
        const float* xf = (const float*)xin;
        size_t base = ((size_t)b*1024 + u*128)*40;
        for (int i = t; i < 2560; i += 256){
            int p = i / 20, kd = i - p*20;
            sAw[p*36 + kd] = packbf2(xf[base + 2*i], xf[base + 2*i + 1]);
        }
        const float* gf = (const float*)grd;
        size_t gb = ((size_t)b*1024 + u*128)*2;
        if (t < 128) sAw[t*36 + 20] = packbf2(gf[gb + 2*t], gf[gb + 2*t + 1]);
    }
    for (int i = t; i < 1920; i += 256){          // zero k 42..63 (dw 21..35)
        int p = i / 15, j = i - p*15;
        sAw[p*36 + 21 + j] = 0;
    }
    __syncthreads();
    int ln = t & 15, qd = (t & 63) >> 4, wv = t >> 6;
    const float* gbias = (const float*)(img + 4608);
    // B fragments direct from gFC0 image
    bfv8 bfr[4][2];
    #pragma unroll
    for (int nt = 0; nt < 4; ++nt)
        #pragma unroll
        for (int ks = 0; ks < 2; ++ks)
            bfr[nt][ks] = *reinterpret_cast<const bfv8*>(&img[(nt*16 + ln)*72 + ks*32 + qd*8]);
    // 8 m-tiles, 2 per wave
    bfv8 a_[2][2];
    #pragma unroll
    for (int mi = 0; mi < 2; ++mi){
        int mt = wv*2 + mi;
        a_[mi][0] = *reinterpret_cast<const bfv8*>(&sA[(mt*16 + ln)*72 + qd*8]);
        a_[mi][1] = *reinterpret_cast<const bfv8*>(&sA[(mt*16 + ln)*72 + 32 + qd*8]);
    }
    fv4 acc[2][4];
    #pragma unroll
    for (int mi = 0; mi < 2; ++mi)
        #pragma unroll
        for (int nt = 0; nt < 4; ++nt){
            fv4 a = (fv4){0.f,0.f,0.f,0.f};
            a = __builtin_amdgcn_mfma_f32_16x16x32_bf16(a_[mi][0], bfr[nt][0], a, 0, 0, 0);
            a = __builtin_amdgcn_mfma_f32_16x16x32_bf16(a_[mi][1], bfr[nt][1], a, 0, 0, 0);
            acc[mi][nt] = a;
        }
    __syncthreads();
    // ---- C -> sC[c][68 dw] (4 rows x 34, x-pads zeroed) ----
    unsigned int* sCd = (unsigned int*)sA;   // [c][68 dw]
    {
        int c = t >> 2, r = t & 3;           // zero x=32,33 pad dword per (c,row)
        sCd[c*68 + r*17 + 16] = 0;
    }
    #pragma unroll
    for (int mi = 0; mi < 2; ++mi)
        #pragma unroll
        for (int nt = 0; nt < 4; ++nt){
            int c = nt*16 + ln;
            float bb = gbias[c];
            int pl = (wv*2 + mi)*16 + qd*4;  // local px, 4 consecutive, same row
            int y = pl >> 5, x = pl & 31;
            int di = c*68 + y*17 + (x >> 1);
            sCd[di]     = packbf2(acc[mi][nt][0] + bb, acc[mi][nt][1] + bb);
            sCd[di + 1] = packbf2(acc[mi][nt][2] + bb, acc[mi][nt][3] + bb);
        }
    __syncthreads();
    // ---- coalesced writeback of block-owned 272B runs ----
    unsigned int* hw = (unsigned int*)(h + (size_t)b*73984);
    for (int i = t; i < 4352; i += 256){
        int c = i / 68, d = i - c*68;
        hw[c*578 + u*68 + d] = sCd[i];
    }
    if (u == 7){                              // rows y=32,33 zero (full pad rows)
        for (int i = t; i < 2176; i += 256){
            int c = i / 34, d = i - c*34;
            hw[c*578 + 544 + d] = 0;
        }
    }
}

// ---------------- forward truncated DFT via MFMA, 4 channels per block -------
// grid 4096 = 256 b x 16 ch-groups; writes hft [cg][b][m][8bf16] (coalesced)
// F1 (x-DFT): C1[(c,y)][2kx+s] = sum_x h[c][y][x] * gB1  (K=64, x pad)
// F2 (y-DFT): C2[(c,kx)][2ky+s] = sum_{2y+p} Gx * gB2    (K=96, pad)
// B operands read DIRECTLY from global images (L2-resident, fragment-ready) —
// no per-block image rebuild; LDS 30.7 KB -> 5 blocks/CU.
__global__ __launch_bounds__(256) void k_fwd(const bf16* __restrict__ h,
                                             unsigned int* __restrict__ hft,
                                             const unsigned short* __restrict__ fwdimg){
    __shared__ unsigned short lds[15360];   // 30,720 B
    unsigned short* sA1 = lds;              // 144 rows x 72 (rows=(c*34+y), k=x pad 64)
    unsigned short* sA2 = lds + 10368;      // 48 x 104 (rows=(c*12+kx), kappa=2y+p pad 96)
    unsigned int* sA1w = (unsigned int*)sA1;
    unsigned int* sA2w = (unsigned int*)sA2;
    const unsigned short* gB1 = fwdimg;          // [row<32][64 u16]
    const unsigned short* gB2 = fwdimg + 2048;   // [row<48][96 u16]
    int blk = blockIdx.x;
    int b = blk >> 4, c0 = (blk & 15) * 4;
    int t = threadIdx.x;
    // stage h (4 planes) into sA1 rows (c*34+y), dword granularity (coalesced)
    const unsigned int* srcp = (const unsigned int*)(h + (size_t)b*73984 + (size_t)c0*1156);
    for (int i = t; i < 2312; i += 256){
        int c = i / 578; int rem = i - c*578;
        int y = rem / 17; int d = rem - y*17;
        sA1w[(c*34 + y)*36 + d] = srcp[i];
    }
    // zero x-pad dwords 17..31 of rows 0..135
    for (int i = t; i < 2040; i += 256){
        int r = i / 15, d = i - r*15;
        sA1w[r*36 + 17 + d] = 0;
    }
    // zero tail rows 136..143 entirely
    for (int i = t; i < 288; i += 256){
        int r = 136 + i / 36, d = i - (i/36)*36;
        sA1w[r*36 + d] = 0;
    }
    // zero sA2 kappa pad [68,96) = dwords 34..47 of each row
    for (int i = t; i < 672; i += 256){
        int r = i / 14, d = i - r*14;
        sA2w[r*52 + 34 + d] = 0;
    }
    __syncthreads();
    int ln = t & 15, qd = (t & 63) >> 4, wv = t >> 6;
    // ---- F1: 9 M-tiles x 2 N-tiles, K=64; wave owns one nt (static frag idx) ----
    {
        int ntw = wv & 1;
        bfv8 b1f[2];
        #pragma unroll
        for (int ks = 0; ks < 2; ++ks)
            b1f[ks] = *reinterpret_cast<const bfv8*>(&gB1[(ntw*16 + ln)*64 + ks*32 + qd*8]);
        int col = ntw*16 + ln;
        int kx = col >> 1, s = col & 1;
        for (int mt = (wv >> 1); mt < 9; mt += 2){
            fv4 acc = (fv4){0.f,0.f,0.f,0.f};
            #pragma unroll
            for (int ks = 0; ks < 2; ++ks){
                bfv8 a = *reinterpret_cast<const bfv8*>(&sA1[(mt*16 + ln)*72 + ks*32 + qd*8]);
                acc = __builtin_amdgcn_mfma_f32_16x16x32_bf16(a, b1f[ks], acc, 0, 0, 0);
            }
            if (col < 24){
                #pragma unroll
                for (int rr = 0; rr < 4; ++rr){
                    int r = mt*16 + qd*4 + rr;
                    if (r < 136){
                        int c = r / 34, y = r - c*34;
                        sA2[(c*12 + kx)*104 + 2*y + s] = f2us(acc[rr]);
                    }
                }
            }
        }
    }
    __syncthreads();
    // ---- F2: 3 M-tiles x 3 N-tiles, K=96; scatter into sC (reuse sA1) ----
    unsigned short* sC = sA1;   // [m][9]: s*4+c at stride 9 (288*9 = 2592 u16)
    for (int tau = wv; tau < 9; tau += 4){
        int mt = tau / 3, nt = tau - (tau/3)*3;
        fv4 acc = (fv4){0.f,0.f,0.f,0.f};
        #pragma unroll
        for (int ks = 0; ks < 3; ++ks){
            bfv8 a  = *reinterpret_cast<const bfv8*>(&sA2[(mt*16 + ln)*104 + ks*32 + qd*8]);
            bfv8 bb = *reinterpret_cast<const bfv8*>(&gB2[(nt*16 + ln)*96 + ks*32 + qd*8]);
            acc = __builtin_amdgcn_mfma_f32_16x16x32_bf16(a, bb, acc, 0, 0, 0);
        }
        int col = nt*16 + ln;
        int ky = col >> 1, s = col & 1;
        #pragma unroll
        for (int rr = 0; rr < 4; ++rr){
            int r = mt*16 + qd*4 + rr;
            int c = r / 12, kxx = r - c*12;
            sC[(ky*12 + kxx)*9 + s*4 + c] = f2us(acc[rr]);
        }
    }
    __syncthreads();
    // ---- fully-coalesced writeback: block owns hft[cg][b][*] = 1152 dwords ----
    unsigned int* dst = hft + ((size_t)(c0 >> 2)*256 + b)*1152;
    for (int d = t; d < 1152; d += 256){
        int m = d >> 2, j = d & 3;
        unsigned int lo = sC[m*9 + 2*j];
        unsigned int hi = sC[m*9 + 2*j + 1];
        dst[d] = lo | (hi << 16);
    }
}

// ---------------- per-mode channel mix as bf16 MFMA GEMM ---------------------
// grid 576 = 288 modes x 2 M-halves of 128; C[128,128] = A[128,128] x B[128,128]
// A kappa order: kappa = cg*8+u (u<4: Re(c=cg*4+u), u>=4: Im), B staged to match.
// XCD line-mate swizzle: m-quads (same q=m>>2, same mh) get block ids differing
// by multiples of 8 -> same XCD L2 -> hft/weight 64B lines fetched once.
__global__ __launch_bounds__(256) void k_mixm(const unsigned short* __restrict__ hft,
                                              const void* __restrict__ sc_w1,
                                              const void* __restrict__ sc_w2,
                                              unsigned int* __restrict__ mixed, int layer,
                                              const float* __restrict__ flg){
    __shared__ unsigned short sB[128*136];   // BT[n][kappa], row stride 136
    const bool f32 = (flg[0] > 0.5f);
    int B = blockIdx.x;
    int x8 = B & 7, w8 = B >> 3;
    int r4 = w8 & 3, g = w8 >> 2;     // g < 18
    int u = g*8 + x8;                 // u < 144
    int mh = u & 1;
    int m  = (u >> 1)*4 + r4;         // m < 288
    int b0 = mh * 128;
    int t = threadIdx.x;
    int kyi = m / 12, kx = m - kyi*12;
    const void* w = (kyi < 12) ? sc_w1 : sc_w2;
    int r = (kyi < 12) ? kyi : kyi - 12;
    size_t wbase = (size_t)layer * 64*64*144*2;
    for (int idx = t; idx < 4096; idx += 256){     // idx = i*64+o
        int i = idx >> 6, o = idx & 63;
        size_t off = wbase + (((size_t)idx*12 + r)*12 + kx)*2;
        float wr = rdf(w, off, f32);
        float wi = rdf(w, off+1, f32);
        int kre = ((i >> 2) << 3) + (i & 3);       // kappa of Re(c=i)
        sB[o*136 + kre]          = f2us(wr);
        sB[(o+64)*136 + kre]     = f2us(wi);
        sB[o*136 + kre + 4]      = f2us(-wi);
        sB[(o+64)*136 + kre + 4] = f2us(wr);
    }
    __syncthreads();
    int ln = t & 15, qd = (t & 63) >> 4, wv = t >> 6;
    // A fragments: A[row][kappa=ks*32+qd*8 ..+7] = hft[g=ks*4+qd][row][m][0..7]
    bfv8 af[2][4];
    int arow = b0 + wv*32 + ln;
    #pragma unroll
    for (int tm = 0; tm < 2; ++tm)
        #pragma unroll
        for (int ks = 0; ks < 4; ++ks){
            int gg = ks*4 + qd;
            af[tm][ks] = *reinterpret_cast<const bfv8*>(
                hft + (((size_t)gg*256 + arow + tm*16)*288 + m)*8);
        }
    fv4 acc[2][8];
    #pragma unroll
    for (int tm=0;tm<2;++tm)
        #pragma unroll
        for (int tn=0;tn<8;++tn) acc[tm][tn] = (fv4){0.f,0.f,0.f,0.f};
    #pragma unroll
    for (int ks = 0; ks < 4; ++ks){
        bfv8 bfr[8];
        #pragma unroll
        for (int tn = 0; tn < 8; ++tn)
            bfr[tn] = *reinterpret_cast<const bfv8*>(&sB[(tn*16 + ln)*136 + ks*32 + qd*8]);
        #pragma unroll
        for (int tm = 0; tm < 2; ++tm)
            #pragma unroll
            for (int tn = 0; tn < 8; ++tn)
                acc[tm][tn] = __builtin_amdgcn_mfma_f32_16x16x32_bf16(af[tm][ks], bfr[tn], acc[tm][tn], 0, 0, 0);
    }
    __syncthreads();
    // C -> LDS (reuse sB): C[row][col], row stride 136; C/D map row=qd*4+r, col=ln
    #pragma unroll
    for (int tm = 0; tm < 2; ++tm)
        #pragma unroll
        for (int tn = 0; tn < 8; ++tn)
            #pragma unroll
            for (int rr = 0; rr < 4; ++rr){
                int row = wv*32 + tm*16 + qd*4 + rr;
                int col = tn*16 + ln;
                sB[row*136 + col] = f2us(acc[tm][tn][rr]);
            }
    __syncthreads();
    // pack (r,i) and write mixed[b][m][o] — 256B contiguous per (b,m), coalesced
    for (int idx = t; idx < 8192; idx += 256){
        int row = idx >> 6, o = idx & 63;
        unsigned int pr = ((unsigned int)sB[row*136 + o]) |
                          (((unsigned int)sB[row*136 + o + 64]) << 16);
        mixed[((size_t)(b0 + row)*288 + m)*64 + o] = pr;
    }
}

// ---------------- pointwise 64x64 channel GEMM (wc path) as MFMA, IN PLACE ---
// grid 1280: b = blk&255, u = blk>>8 (5 px-chunks of 240; chunks of same b
// co-XCD: ids differ by 256). C[240px][64o] = A[240px][64c] x w[o][c]^T + bias.
// Per-chunk in-place: block reads/writes only its own px range (disjoint).
__global__ __launch_bounds__(256) void k_wc(bf16* __restrict__ h,
                                            const void* __restrict__ wc_w,
                                            const void* __restrict__ wc_b,
                                            int layer,
                                            const float* __restrict__ flg){
    __shared__ unsigned short sA[240*72];   // A[p][c], stride 72; reused as sC[64][240]
    __shared__ unsigned short sBT[64*72];   // BT[o][c], stride 72
    __shared__ float sb[64];
    const bool f32 = (flg[0] > 0.5f);
    int blk = blockIdx.x;
    int b = blk & 255, u = blk >> 8;
    int px0 = u*240;
    int npx = 1156 - px0; if (npx > 240) npx = 240;   // 240 or 196
    int ndp = npx >> 1;                                // 120 or 98
    int t = threadIdx.x;
    size_t wbase = (size_t)layer*4096;
    for (int i = t; i < 4096; i += 256){               // wc_w[l][o][c] -> BT[o][c]
        int o = i >> 6, c = i & 63;
        sBT[o*72 + c] = f2us(rdf(wc_w, wbase + i, f32));
    }
    if (t < 64) sb[t] = rdf(wc_b, layer*64 + t, f32);
    // stage A transposed: dword-granular reads of h (always bf16 workspace)
    const unsigned int* srcd = (const unsigned int*)(h + (size_t)b*73984);
    for (int i = t; i < 7680; i += 256){
        int c = i / 120, dp = i - c*120;
        unsigned int v = (dp < ndp) ? srcd[c*578 + (px0 >> 1) + dp] : 0u;
        sA[(2*dp)*72 + c]     = (unsigned short)(v & 0xffff);
        sA[(2*dp + 1)*72 + c] = (unsigned short)(v >> 16);
    }
    __syncthreads();
    int ln = t & 15, qd = (t & 63) >> 4, wv = t >> 6;
    bfv8 bfr[4][2];
    #pragma unroll
    for (int nt = 0; nt < 4; ++nt)
        #pragma unroll
        for (int ks = 0; ks < 2; ++ks)
            bfr[nt][ks] = *reinterpret_cast<const bfv8*>(&sBT[(nt*16 + ln)*72 + ks*32 + qd*8]);
    // 15 m-tiles: wave wv handles mt = wv + 4*mi (mi<4, skip mt>=15)
    bfv8 a_[4][2];
    #pragma unroll
    for (int mi = 0; mi < 4; ++mi){
        int mt = wv + mi*4;
        if (mt < 15){
            a_[mi][0] = *reinterpret_cast<const bfv8*>(&sA[(mt*16 + ln)*72 + qd*8]);
            a_[mi][1] = *reinterpret_cast<const bfv8*>(&sA[(mt*16 + ln)*72 + 32 + qd*8]);
        }
    }
    fv4 acc[4][4];
    #pragma unroll
    for (int mi = 0; mi < 4; ++mi){
        int mt = wv + mi*4;
        if (mt < 15){
            #pragma unroll
            for (int nt = 0; nt < 4; ++nt){
                fv4 a = (fv4){0.f,0.f,0.f,0.f};
                a = __builtin_amdgcn_mfma_f32_16x16x32_bf16(a_[mi][0], bfr[nt][0], a, 0, 0, 0);
                a = __builtin_amdgcn_mfma_f32_16x16x32_bf16(a_[mi][1], bfr[nt][1], a, 0, 0, 0);
                acc[mi][nt] = a;
            }
        }
    }
    __syncthreads();
    // C -> sC[o][240] (transpose back), bias added
    unsigned int* sCd = (unsigned int*)sA;   // [o][120 dw]
    #pragma unroll
    for (int mi = 0; mi < 4; ++mi){
        int mt = wv + mi*4;
        if (mt < 15){
            #pragma unroll
            for (int nt = 0; nt < 4; ++nt){
                int o = nt*16 + ln;
                float bb = sb[o];
                int p0 = mt*16 + qd*4;
                sCd[o*120 + (p0 >> 1)]     = packbf2(acc[mi][nt][0] + bb, acc[mi][nt][1] + bb);
                sCd[o*120 + (p0 >> 1) + 1] = packbf2(acc[mi][nt][2] + bb, acc[mi][nt][3] + bb);
            }
        }
    }
    __syncthreads();
    // coalesced in-place writeback (own px range only)
    unsigned int* dstd = (unsigned int*)(h + (size_t)b*73984);
    for (int i = t; i < 7680; i += 256){
        int o = i / 120, dp = i - o*120;
        if (dp < ndp) dstd[o*578 + (px0 >> 1) + dp] = sCd[o*120 + dp];
    }
}

// ---------------- inverse truncated DFT as MFMA GEMMs; in-place add + gelu ---
// grid 4096 = 256 b x 16 o-groups of 4, XCD line-mate swizzled:
//   B = z*32 + s*8 + x  ->  b = (z>>2)*8 + x, og = (z&3)*4 + s
//   og-quads of the same b (which share each 64B line of mixed) land on the
//   same XCD (ids differ by 8/16/24) -> line fetched once into that L2.
// B operands (invBT/invW2) are read DIRECTLY from global images (L2-resident,
// fragment-ready layout); OOB rows give garbage discarded by col/y predicates.
// LDS 36.9 KB -> 4 blocks/CU.
__global__ __launch_bounds__(256) void k_invm(const unsigned int* __restrict__ mixed,
                                              const float* __restrict__ tabs,
                                              bf16* __restrict__ hio, int layer){
    __shared__ unsigned short lds[18448];   // 36,896 B total
    unsigned short* sA  = lds;              // 96*40 (step A only; overlaps htile)
    unsigned short* sG  = lds + 4624;       // 4*48*72 (htile = lds[0..4624))
    unsigned int* ldsw  = (unsigned int*)lds;
    int B = blockIdx.x;
    int x8 = B & 7, s4 = (B >> 3) & 3, z = B >> 5;
    int b  = (z >> 2)*8 + x8;
    int o0 = ((z & 3)*4 + s4)*4;
    int t = threadIdx.x;
    const unsigned short* gBT16 = (const unsigned short*)(tabs + 2448);  // [n][32 u16]
    const unsigned short* gW216 = (const unsigned short*)(tabs + 3536);  // [y][64 u16]
    // sA from mixed[b][m][o]: 16B per (m), stride 256B (lines shared intra-XCD)
    const unsigned int* msrc = mixed + (size_t)b*18432 + o0;
    for (int i = t; i < 1152; i += 256){
        int m = i >> 2, ch = i & 3;
        int kyi = m / 12, kx = m - kyi*12;
        ((unsigned int*)sA)[(ch*24 + kyi)*20 + kx] = msrc[(size_t)m*64 + ch];
    }
    for (int i = t; i < 384; i += 256)       // zero k 24..31 (dw 12..15)
        ((unsigned int*)sA)[(i >> 2)*20 + 12 + (i & 3)] = 0;
    // sG: zero only read pads — rows x in [34,48): dw 0..31; rows x<34: dw 24..31
    for (int i = t; i < 1792; i += 256){
        int r = i >> 5;
        int ch = r / 14, x = 34 + (r - (r/14)*14);
        ((unsigned int*)sG)[(ch*48 + x)*36 + (i & 31)] = 0;
    }
    for (int i = t; i < 1088; i += 256){
        int r = i >> 3;
        int ch = r / 34, x = r - (r/34)*34;
        ((unsigned int*)sG)[(ch*48 + x)*36 + 24 + (i & 7)] = 0;
    }
    __syncthreads();
    int ln = t & 15, qd = (t & 63) >> 4, wv = t >> 6;
    // ---- step A: 30 tiles (6 M x 5 N), K=32; B-frag direct from gBT image ----
    for (int tau = wv; tau < 30; tau += 4){
        int mt = tau / 5, nt = tau - mt*5;
        bfv8 a  = *reinterpret_cast<const bfv8*>(&sA[(mt*16 + ln)*40 + qd*8]);
        bfv8 bb = *reinterpret_cast<const bfv8*>(&gBT16[(nt*16 + ln)*32 + qd*8]);
        fv4 acc = (fv4){0.f,0.f,0.f,0.f};
        acc = __builtin_amdgcn_mfma_f32_16x16x32_bf16(a, bb, acc, 0, 0, 0);
        int col = nt*16 + ln;
        if (col < 68){
            int x = col >> 1, ri = col & 1;
            #pragma unroll
            for (int rr = 0; rr < 4; ++rr){
                int row = mt*16 + qd*4 + rr;
                int ch = row / 24, kyi = row - ch*24;
                sG[(ch*48 + x)*72 + 2*kyi + ri] = f2us(acc[rr]);
            }
        }
    }
    __syncthreads();
    // ---- stage htile (4 contiguous ch-planes) into lds[0..2312) dwords ----
    const unsigned int* hsrc = (const unsigned int*)(hio + (size_t)b*73984 + (size_t)o0*1156);
    for (int i = t; i < 2312; i += 256) ldsw[i] = hsrc[i];
    __syncthreads();
    // ---- step B: wave = ch; 3x3 tiles, K=64 (2 MFMAs); A-frag direct from gW2 ----
    int ch = wv;
    #pragma unroll
    for (int mt = 0; mt < 3; ++mt){
        bfv8 a0 = *reinterpret_cast<const bfv8*>(&gW216[(mt*16 + ln)*64 + qd*8]);
        bfv8 a1 = *reinterpret_cast<const bfv8*>(&gW216[(mt*16 + ln)*64 + 32 + qd*8]);
        #pragma unroll
        for (int nt = 0; nt < 3; ++nt){
            bfv8 b0 = *reinterpret_cast<const bfv8*>(&sG[(ch*48 + nt*16 + ln)*72 + qd*8]);
            bfv8 b1 = *reinterpret_cast<const bfv8*>(&sG[(ch*48 + nt*16 + ln)*72 + 32 + qd*8]);
            fv4 acc = (fv4){0.f,0.f,0.f,0.f};
            acc = __builtin_amdgcn_mfma_f32_16x16x32_bf16(a0, b0, acc, 0, 0, 0);
            acc = __builtin_amdgcn_mfma_f32_16x16x32_bf16(a1, b1, acc, 0, 0, 0);
            int x = nt*16 + ln;
            if (x < 34){
                #pragma unroll
                for (int rr = 0; rr < 4; ++rr){
                    int y = mt*16 + qd*4 + rr;
                    if (y < 34){
                        int off = ch*1156 + y*34 + x;
                        float v = acc[rr] + us2f(lds[off]);
                        if (layer < 3) v = gelu_f(v);
                        lds[off] = f2us(v);
                    }
                }
            }
        }
    }
    __syncthreads();
    // ---- coalesced dword writeback ----
    unsigned int* hdst = (unsigned int*)(hio + (size_t)b*73984 + (size_t)o0*1156);
    for (int i = t; i < 2312; i += 256) hdst[i] = ldsw[i];
}

// ---------------- 8x8/stride4 VALID conv -> gelu -> pe2 scale ----------------
__global__ __launch_bounds__(256) void k_pe(const bf16* __restrict__ h,
                                            const void* __restrict__ pw,
                                            const void* __restrict__ pb,
                                            const void* __restrict__ p2w,
                                            const void* __restrict__ p2b,
                                            float* __restrict__ p49,
                                            const float* __restrict__ flg){
    __shared__ float red[256];
    const bool f32 = (flg[0] > 0.5f);
    int bid = blockIdx.x;          // b*49 + py*7 + px
    int b = bid / 49, r = bid - b*49;
    int py = r / 7, px = r - py*7;
    int t = threadIdx.x;
    const bf16* hb = h + (size_t)b*73984 + (py*4)*34 + px*4;
    float partial = 0.f;
    for (int tt = t; tt < 4096; tt += 256){
        int c = tt >> 6, k = tt & 63, ky = k >> 3, kx = k & 7;
        partial += bff(hb[(size_t)c*1156 + ky*34 + kx]) * rdf(pw, tt, f32);
    }
    red[t] = partial;
    __syncthreads();
    for (int s = 128; s > 0; s >>= 1){
        if (t < s) red[t] += red[t + s];
        __syncthreads();
    }
    if (t == 0){
        float v = red[0] + rdf(pb, 0, f32);
        v = gelu_f(v);
        p49[bid] = v * rdf(p2w, 0, f32) + rdf(p2b, 0, f32);
    }
}

// ---------------- sentence MLP 384->32->32->16 (relu,relu,lin) ---------------
__global__ __launch_bounds__(64) void k_sent(const void* __restrict__ se,
                                             const void* __restrict__ w1, const void* __restrict__ b1,
                                             const void* __restrict__ w2, const void* __restrict__ b2,
                                             const void* __restrict__ w3, const void* __restrict__ b3,
                                             float* __restrict__ outv,
                                             const float* __restrict__ flg){
    __shared__ float s1[32], s2[32];
    const bool f32 = (flg[0] > 0.5f);
    int b = blockIdx.x, t = threadIdx.x;
    if (t < 32){
        float acc = rdf(b1, t, f32);
        size_t rbase = (size_t)b*384;
        for (int k = 0; k < 384; ++k) acc += rdf(se, rbase + k, f32) * rdf(w1, k*32 + t, f32);
        s1[t] = fmaxf(acc, 0.f);
    }
    __syncthreads();
    if (t < 32){
        float acc = rdf(b2, t, f32);
        for (int k = 0; k < 32; ++k) acc += s1[k] * rdf(w2, k*32 + t, f32);
        s2[t] = fmaxf(acc, 0.f);
    }
    __syncthreads();
    if (t < 16){
        float acc = rdf(b3, t, f32);
        for (int k = 0; k < 32; ++k) acc += s2[k] * rdf(w3, k*16 + t, f32);
        outv[b*16 + t] = acc;
    }
}

// ---------------- xp MLP 49->32->32->16 (silu,silu,lin) ----------------------
__global__ __launch_bounds__(64) void k_xp(const float* __restrict__ p49,
                                           const void* __restrict__ w1, const void* __restrict__ b1,
                                           const void* __restrict__ w2, const void* __restrict__ b2,
                                           const void* __restrict__ w3, const void* __restrict__ b3,
                                           float* __restrict__ outv,
                                           const float* __restrict__ flg){
    __shared__ float s1[32], s2[32];
    const bool f32 = (flg[0] > 0.5f);
    int b = blockIdx.x, t = threadIdx.x;
    if (t < 32){
        float acc = rdf(b1, t, f32);
        const float* row = p49 + b*49;
        for (int k = 0; k < 49; ++k) acc += row[k] * rdf(w1, k*32 + t, f32);
        s1[t] = silu_f(acc);
    }
    __syncthreads();
    if (t < 32){
        float acc = rdf(b2, t, f32);
        for (int k = 0; k < 32; ++k) acc += s1[k] * rdf(w2, k*32 + t, f32);
        s2[t] = silu_f(acc);
    }
    __syncthreads();
    if (t < 16){
        float acc = rdf(b3, t, f32);
        for (int k = 0; k < 32; ++k) acc += s2[k] * rdf(w3, k*16 + t, f32);
        outv[b*16 + t] = acc;
    }
}

// ---------------- pu MLP part A: 32->128->256 (silu,silu) --------------------
__global__ __launch_bounds__(256) void k_puA(const float* __restrict__ xemb,
                                             const float* __restrict__ semb,
                                             const void* __restrict__ w1, const void* __restrict__ b1,
                                             const void* __restrict__ w2, const void* __restrict__ b2,
                                             float* __restrict__ h2buf,
                                             const float* __restrict__ flg){
    __shared__ float ein[32];
    __shared__ float h1[128];
    const bool f32 = (flg[0] > 0.5f);
    int b = blockIdx.x, t = threadIdx.x;
    if (t < 16) ein[t] = xemb[b*16 + t];
    else if (t < 32) ein[t] = semb[b*16 + (t - 16)];
    __syncthreads();
    if (t < 128){
        float acc = rdf(b1, t, f32);
        for (int k = 0; k < 32; ++k) acc += ein[k] * rdf(w1, k*128 + t, f32);
        h1[t] = silu_f(acc);
    }
    __syncthreads();
    {
        float acc = rdf(b2, t, f32);
        for (int k = 0; k < 128; ++k) acc += h1[k] * rdf(w2, k*256 + t, f32);
        h2buf[(size_t)b*256 + t] = silu_f(acc);
    }
}

// ---------------- pu MLP part B: 256->1156 GEMM ------------------------------
// grid 1280 = 256 b (fast) x 5 n-chunks of 232
__global__ __launch_bounds__(256) void k_puB(const float* __restrict__ h2buf,
                                             const void* __restrict__ w3, const void* __restrict__ b3,
                                             float* __restrict__ emb,
                                             const float* __restrict__ flg){
    __shared__ float sh2[256];
    const bool f32 = (flg[0] > 0.5f);
    int blk = blockIdx.x;
    int b = blk & 255, nc = blk >> 8;
    int t = threadIdx.x;
    sh2[t] = h2buf[(size_t)b*256 + t];
    __syncthreads();
    int e = nc*232 + t;
    if (t < 232 && e < 1156){
        float acc = rdf(b3, e, f32);
        if (f32){
            const float* wp = (const float*)w3 + e;
            #pragma unroll 4
            for (int k = 0; k < 256; ++k) acc += sh2[k] * wp[(size_t)k*1156];
        } else {
            const bf16* wp = (const bf16*)w3 + e;
            #pragma unroll 4
            for (int k = 0; k < 256; ++k) acc += sh2[k] * bff(wp[(size_t)k*1156]);
        }
        emb[(size_t)b*1156 + e] = acc;
    }
}

// ---------------- final: crop, concat emb, fc1(MFMA)+gelu, fc2(MFMA) ---------
// grid 512 = 256 b x 2 halves; 8 iters of 2 rows (64 px).
// fc1: C[64px,128j] = A[px,c<64] x w1 (K=64) + rank-1 emb add; fc2: K=128, N=16(4)
__global__ __launch_bounds__(256, 3) void k_final(const bf16* __restrict__ h,
                                                  const float* __restrict__ emb,
                                                  const void* __restrict__ w1, const void* __restrict__ b1,
                                                  const void* __restrict__ w2, const void* __restrict__ b2,
                                                  void* __restrict__ out,
                                                  const float* __restrict__ flg){
    __shared__ unsigned short sw1t[128*72];   // w1T[j][c], stride 72 (16B-aligned rows)
    __shared__ unsigned short sw2t[16*136];   // w2T[n][j], rows 4..15 zero
    __shared__ float sw1e[128];               // w1[64][j] (emb channel)
    __shared__ float sb1[128];
    __shared__ float sb2[4];
    __shared__ unsigned short spx[64*66];     // input[c][px], stride 66 (odd dwords)
    __shared__ float sembp[64];               // emb[px]
    __shared__ unsigned short sh2[128*66];    // hid[j][px], stride 66
    const bool f32 = (flg[0] > 0.5f);
    int blk = blockIdx.x;
    int b = blk >> 1, half = blk & 1;
    int t = threadIdx.x;
    for (int i = t; i < 8320; i += 256){       // w1 [c=65][j=128]
        int c = i >> 7, j = i & 127;
        float v = rdf(w1, i, f32);
        if (c < 64) sw1t[j*72 + c] = f2us(v);
        else sw1e[j] = v;
    }
    if (t < 128) sb1[t] = rdf(b1, t, f32);
    for (int i = t; i < 2176; i += 256){       // w2 [j=128][k=4] -> w2T[n][j]
        int n = i / 136, j = i - n*136;
        float v = (n < 4 && j < 128) ? rdf(w2, j*4 + n, f32) : 0.f;
        sw2t[i] = f2us(v);
    }
    if (t < 4) sb2[t] = rdf(b2, t, f32);
    __syncthreads();
    int ln = t & 15, qd = (t & 63) >> 4, wv = t >> 6;
    // hoist B fragments (weights) into registers
    bfv8 bw1[8][2];
    #pragma unroll
    for (int tn = 0; tn < 8; ++tn)
        #pragma unroll
        for (int ks = 0; ks < 2; ++ks)
            bw1[tn][ks] = *reinterpret_cast<const bfv8*>(&sw1t[(tn*16 + ln)*72 + ks*32 + qd*8]);
    bfv8 bw2[4];
    #pragma unroll
    for (int ks = 0; ks < 4; ++ks)
        bw2[ks] = *reinterpret_cast<const bfv8*>(&sw2t[ln*136 + ks*32 + qd*8]);
    const bf16* hb = h + (size_t)b*73984;
    const float* eb = emb + (size_t)b*1156;
    for (int it = 0; it < 8; ++it){
        int y0 = half*16 + it*2;               // 2 rows = 64 px
        __syncthreads();
        for (int e = t; e < 2048; e += 256){   // stage spx[c][px] c-major
            int c = e >> 5, d = e & 31;
            int px = d*2;
            int y = y0 + (px >> 5), x = px & 31;
            float v0 = bff(hb[(size_t)c*1156 + y*34 + x]);
            int px1 = px + 1;
            int y1 = y0 + (px1 >> 5), x1 = px1 & 31;
            float v1 = bff(hb[(size_t)c*1156 + y1*34 + x1]);
            ((unsigned int*)spx)[c*33 + d] = packbf2(v0, v1);
        }
        if (t < 64){
            int y = y0 + (t >> 5), x = t & 31;
            sembp[t] = eb[y*34 + x];
        }
        __syncthreads();
        // fc1 MFMA: wave wv owns mtile wv (px = wv*16 + ...)
        fv4 acc[8];
        #pragma unroll
        for (int tn = 0; tn < 8; ++tn) acc[tn] = (fv4){0.f,0.f,0.f,0.f};
        #pragma unroll
        for (int ks = 0; ks < 2; ++ks){
            union { bfv8 v; unsigned short s[8]; } af;
            #pragma unroll
            for (int j = 0; j < 8; ++j)
                af.s[j] = spx[(ks*32 + qd*8 + j)*66 + wv*16 + ln];
            #pragma unroll
            for (int tn = 0; tn < 8; ++tn)
                acc[tn] = __builtin_amdgcn_mfma_f32_16x16x32_bf16(af.v, bw1[tn][ks], acc[tn], 0, 0, 0);
        }
        float ev[4];
        #pragma unroll
        for (int rr = 0; rr < 4; ++rr) ev[rr] = sembp[wv*16 + qd*4 + rr];
        #pragma unroll
        for (int tn = 0; tn < 8; ++tn){
            int col = tn*16 + ln;
            float we = sw1e[col];
            float bb1 = sb1[col];
            #pragma unroll
            for (int rr = 0; rr < 4; ++rr){
                float v = acc[tn][rr] + ev[rr]*we + bb1;
                sh2[col*66 + wv*16 + qd*4 + rr] = f2us(gelu_f(v));
            }
        }
        __syncthreads();
        // fc2 MFMA: K=128, N=16 (4 valid)
        fv4 a2 = (fv4){0.f,0.f,0.f,0.f};
        #pragma unroll
        for (int ks = 0; ks < 4; ++ks){
            union { bfv8 v; unsigned short s[8]; } af;
            #pragma unroll
            for (int j = 0; j < 8; ++j)
                af.s[j] = sh2[(ks*32 + qd*8 + j)*66 + wv*16 + ln];
            a2 = __builtin_amdgcn_mfma_f32_16x16x32_bf16(af.v, bw2[ks], a2, 0, 0, 0);
        }
        if (ln < 4){
            float bb2 = sb2[ln];
            #pragma unroll
            for (int rr = 0; rr < 4; ++rr){
                int pxl = wv*16 + qd*4 + rr;
                int y = y0 + (pxl >> 5), x = pxl & 31;
                size_t o = ((size_t)(b*32 + y)*32 + x)*4 + ln;
                float v = a2[rr] + bb2;
                if (f32) ((float*)out)[o] = v;
                else     ((bf16*)out)[o] = __float2bfloat16(v);
            }
        }
    }
}

extern "C" void kernel_launch(void* const* d_in, const int* in_sizes, int n_in,
                              void* d_out, int out_size, void* d_ws, size_t ws_size,
                              hipStream_t stream) {
    (void)in_sizes; (void)n_in; (void)out_size; (void)ws_size;
    const void* x     = d_in[0];
    const void* grd   = d_in[1];
    const void* se    = d_in[2];
    const void* fc0_w = d_in[3];
    const void* fc0_b = d_in[4];
    const void* sc_w1 = d_in[5];
    const void* sc_w2 = d_in[6];
    const void* wc_w  = d_in[7];
    const void* wc_b  = d_in[8];
    const void* pe1_w = d_in[9];
    const void* pe1_b = d_in[10];
    const void* pe2_w = d_in[11];
    const void* pe2_b = d_in[12];
    const void* sp_w1 = d_in[13];
    const void* sp_b1 = d_in[14];
    const void* sp_w2 = d_in[15];
    const void* sp_b2 = d_in[16];
    const void* sp_w3 = d_in[17];
    const void* sp_b3 = d_in[18];
    const void* xp_w1 = d_in[19];
    const void* xp_b1 = d_in[20];
    const void* xp_w2 = d_in[21];
    const void* xp_b2 = d_in[22];
    const void* xp_w3 = d_in[23];
    const void* xp_b3 = d_in[24];
    const void* pu_w1 = d_in[25];
    const void* pu_b1 = d_in[26];
    const void* pu_w2 = d_in[27];
    const void* pu_b2 = d_in[28];
    const void* pu_w3 = d_in[29];
    const void* pu_b3 = d_in[30];
    const void* fc1_w = d_in[31];
    const void* fc1_b = d_in[32];
    const void* fc2_w = d_in[33];
    const void* fc2_b = d_in[34];

    // workspace layout (float-unit offsets); total ~77 MB
    float* ws    = (float*)d_ws;
    bf16*  hA    = (bf16*)ws;                              // 18,939,904 bf16
    unsigned int* hft   = (unsigned int*)(ws + 9469952);   // 4,718,592 dwords (hft cg-panels)
    unsigned int* mixed = (unsigned int*)(ws + 14188544);  // 4,718,592 dwords ([b][m][o])
    float* tabs  = ws + 18907136;                          // 4,896 (DFT tables + inv images)
    float* p49   = ws + 18912032;                          // 12,544
    float* semb  = ws + 18924576;                          // 4,096
    float* xemb  = ws + 18928672;                          // 4,096
    float* emb   = ws + 18932768;                          // 295,936
    float* flag  = ws + 19228704;                          // 1
    float* h2buf = (float*)hft;                            // reuse: hft dead after layer loop
    // fwd B-images + fc0 weight image live in emb region (dead during layer
    // loop; k_puB writes emb only after the last k_invm; rebuilt each replay)
    float* fwdimg = emb;                                   // 5,696 floats

    k_probe<<<1, 256, 0, stream>>>(x, flag);
    k_tables<<<1, 256, 0, stream>>>(tabs, fwdimg, fc0_w, fc0_b, flag);
    k_fc0<<<2048, 256, 0, stream>>>(x, grd, (const unsigned short*)(fwdimg + 3328), hA, flag);

    for (int l = 0; l < 4; ++l){
        k_fwd<<<4096, 256, 0, stream>>>(hA, hft, (const unsigned short*)fwdimg);
        k_mixm<<<576, 256, 0, stream>>>((const unsigned short*)hft, sc_w1, sc_w2, mixed, l, flag);
        k_wc <<<1280, 256, 0, stream>>>(hA, wc_w, wc_b, l, flag);
        k_invm<<<4096, 256, 0, stream>>>(mixed, tabs, hA, l);
    }

    k_pe  <<<256*49, 256, 0, stream>>>(hA, pe1_w, pe1_b, pe2_w, pe2_b, p49, flag);
    k_sent<<<256, 64, 0, stream>>>(se, sp_w1, sp_b1, sp_w2, sp_b2, sp_w3, sp_b3, semb, flag);
    k_xp  <<<256, 64, 0, stream>>>(p49, xp_w1, xp_b1, xp_w2, xp_b2, xp_w3, xp_b3, xemb, flag);
    k_puA <<<256, 256, 0, stream>>>(xemb, semb, pu_w1, pu_b1, pu_w2, pu_b2, h2buf, flag);
    k_puB <<<1280, 256, 0, stream>>>(h2buf, pu_w3, pu_b3, emb, flag);
    k_final<<<512, 256, 0, stream>>>(hA, emb, fc1_w, fc1_b, fc2_w, fc2_b, d_out, flag);
}

// Round 9
// 1059.918 us; speedup vs baseline: 1.3351x; 1.0465x over previous
//
#include <hip/hip_runtime.h>
#include <hip/hip_bf16.h>
#include <math.h>

typedef __hip_bfloat16 bf16;
typedef __bf16 bfv8 __attribute__((ext_vector_type(8)));
typedef float fv4 __attribute__((ext_vector_type(4)));

__device__ __forceinline__ float bff(const bf16 x){ return __bfloat162float(x); }
// fast gelu: 0.5 v (1 + erf(v/sqrt2)); erf via A&S 7.1.26 (|err|<1.5e-7),
// branchless, hardware v_exp/v_rcp. ~14 VALU vs ocml erff's ~30 (branchy).
__device__ __forceinline__ float gelu_f(float v){
    float x = v * 0.70710678118654752f;
    float ax = fabsf(x);
    float t = __builtin_amdgcn_rcpf(1.0f + 0.3275911f * ax);
    float y = t*(0.254829592f + t*(-0.284496736f + t*(1.421413741f +
              t*(-1.453152027f + t*1.061405429f))));
    float er = 1.0f - y * __expf(-ax*ax);
    er = (x < 0.f) ? -er : er;
    return 0.5f * v * (1.0f + er);
}
__device__ __forceinline__ float silu_f(float v){
    return v / (1.f + __expf(-v));
}
// dtype-agnostic input read: f32 ? fp32 : bf16
__device__ __forceinline__ float rdf(const void* p, size_t i, bool f32){
    return f32 ? ((const float*)p)[i] : __bfloat162float(((const bf16*)p)[i]);
}
__device__ __forceinline__ unsigned int packbf2(float a, float b){
    __hip_bfloat162 v;
    v.x = __float2bfloat16(a);
    v.y = __float2bfloat16(b);
    return *reinterpret_cast<unsigned int*>(&v);
}
__device__ __forceinline__ float2 unpackbf2(unsigned int u){
    __hip_bfloat162 v = *reinterpret_cast<__hip_bfloat162*>(&u);
    return make_float2(__bfloat162float(v.x), __bfloat162float(v.y));
}
__device__ __forceinline__ float us2f(unsigned short u){
    unsigned int x = ((unsigned int)u) << 16;
    return __uint_as_float(x);
}
__device__ __forceinline__ unsigned short f2us(float f){
    bf16 v = __float2bfloat16(f);
    return *reinterpret_cast<unsigned short*>(&v);
}

// Geometry
// B=256, C=64, H=W=34 (padded), modes: ky in {0..11, 22..33} (24), kx in 0..11 (12)
// h layout (ws, bf16): [b][c][y][x], stride c = 1156, stride b = 73984
// hft layout: [cg<16][b<256][m<288][8 bf16] ; kappa = cg*8+u, u<4: Re(c=cg*4+u),
//             u>=4: Im(c=cg*4+u-4).  Writer (k_fwd) fully coalesced per block.
// mixed layout: [b<256][m<288][o<64] packed bf16x2 dwords (r,i); writer (k_mixm)
//             owns full 256B rows per (b,m).
// tabs: [0,1632) Wfy f32 | [1632,2448) Wfx f32 |
//       [2448,3536) invBT bf16 image (68x16 dw) | [3536,4624) invW2 bf16 image (34x32 dw)
// fwd images (in emb region, dead during layer loop):
//   gB1 [row<32][64 u16] | gB2 [row<48][96 u16] | gFC0 [c<64][72 u16] @ +3328 fl |
//   gFC0b [64 f32] @ +5632 fl
// All images fragment-ready: k_fwd/k_invm/k_fc0 read MFMA fragments DIRECTLY from
// global (16B-aligned rows, pads pre-zeroed; OOB rows discarded by predicates).

// ---------------- dtype probe ----------------
__global__ __launch_bounds__(256) void k_probe(const void* x, float* flag){
    __shared__ int wild;
    int t = threadIdx.x;
    if (t == 0) wild = 0;
    __syncthreads();
    const bf16* xb = (const bf16*)x;
    for (int i = t; i < 1024; i += 256){
        float v = bff(xb[i]);
        if (!(fabsf(v) < 1e10f)) wild = 1;
    }
    __syncthreads();
    if (t == 0) flag[0] = wild ? 1.f : 0.f;
}

// ---------------- tables ----------------
__global__ __launch_bounds__(256) void k_tables(float* tabs, float* fwdimg,
                                                const void* __restrict__ fc0w,
                                                const void* __restrict__ fc0b,
                                                const float* __restrict__ flg){
    int t = threadIdx.x;
    const bool f32 = (flg[0] > 0.5f);
    unsigned int* gBT = (unsigned int*)(tabs + 2448);   // [n<68][kd<16] bf16x2
    unsigned int* gW2 = (unsigned int*)(tabs + 3536);   // [y<34][kd<32] bf16x2
    unsigned short* gB1 = (unsigned short*)fwdimg;          // [row<32][64]
    unsigned short* gB2 = (unsigned short*)(fwdimg + 1024); // [row<48][96]
    unsigned short* gF  = (unsigned short*)(fwdimg + 3328); // [c<64][72]
    float* gFb = fwdimg + 5632;                             // [64]
    const float TWO_PI = 6.283185307179586f;
    // gFC0 image: BT[c][k] from fc0_w [k=42][c=64], k-pads zeroed
    for (int i = t; i < 4608; i += 256){
        int c = i / 72, k = i - c*72;
        float v = (k < 42) ? rdf(fc0w, (size_t)k*64 + c, f32) : 0.f;
        gF[i] = f2us(v);
    }
    if (t < 64) gFb[t] = rdf(fc0b, t, f32);
    // gB1: row=2kx+s (kx<12), k=x<34: e^{-i ang} component (s=0: cos, s=1: -sin)
    for (int i = t; i < 2048; i += 256){
        int row = i >> 6, k = i & 63;
        float v = 0.f;
        if (row < 24 && k < 34){
            int kx = row >> 1, s = row & 1;
            int ph = (kx * k) % 34;
            float ang = TWO_PI * (float)ph / 34.0f;
            float sn, cs;
            sincosf(ang, &sn, &cs);
            v = (s == 0) ? cs : -sn;
        }
        gB1[i] = f2us(v);
    }
    // gB2: row=2ky+s (kyi<24), kk=2y+p<68: realified [[wr,-wi],[wi,wr]] of e^{-i ang}
    for (int i = t; i < 4608; i += 256){
        int row = i / 96, kk = i - row*96;
        float v = 0.f;
        if (kk < 68){
            int kyi = row >> 1, s = row & 1;
            int y = kk >> 1, p = kk & 1;
            int ky = (kyi < 12) ? kyi : kyi + 10;
            int ph = (ky * y) % 34;
            float ang = TWO_PI * (float)ph / 34.0f;
            float sn, cs;
            sincosf(ang, &sn, &cs);
            float wr = cs, wi = -sn;
            v = (s == 0) ? ((p == 0) ? wr : -wi) : ((p == 0) ? wi : wr);
        }
        gB2[i] = f2us(v);
    }
    // invBT image: n=2x+ri (x<34), k=2kx+ri2; v = ri==0 ? (ri2==0? C : -S) : (ri2==0? S : C)
    // where C = ck*cos(ang), S = ck*sin(ang), ang = +2pi*(kx*x mod 34)/34, ck = (kx==0?1:2)
    for (int i = t; i < 1088; i += 256){
        int n = i >> 4, kd = i & 15;
        int x = n >> 1, ri = n & 1;
        int kx = kd;
        float v0 = 0.f, v1 = 0.f;
        if (kx < 12){
            int ph = (kx * x) % 34;
            float ang = TWO_PI * (float)ph / 34.0f;
            float s, c;
            sincosf(ang, &s, &c);
            float ck = (kx == 0) ? 1.0f : 2.0f;
            float C = ck * c, S = ck * s;
            v0 = (ri == 0) ? C : S;       // ri2 = 0
            v1 = (ri == 0) ? -S : C;      // ri2 = 1
        }
        gBT[i] = packbf2(v0, v1);
    }
    // invW2 image: y<34, k=2kyi+ri; v = (1/1156)*(ri==0? cos : -sin), ang=+2pi*(ky*y mod 34)/34
    for (int i = t; i < 1088; i += 256){
        int y = i >> 5, kd = i & 31;
        int kyi = kd;
        float v0 = 0.f, v1 = 0.f;
        if (kyi < 24){
            int ky = (kyi < 12) ? kyi : kyi + 10;
            int ph = (ky * y) % 34;
            float ang = TWO_PI * (float)ph / 34.0f;
            float s, c;
            sincosf(ang, &s, &c);
            v0 = c * (1.0f/1156.0f);
            v1 = -s * (1.0f/1156.0f);
        }
        gW2[i] = packbf2(v0, v1);
    }
}

// ---------------- fc0 as MFMA GEMM: concat(x,grid) @ fc0_w + b ---------------
// grid 2048: B -> b = (B>>6)*8 + (B&7), u = (B>>3)&7  (8 chunks of b co-XCD)
// Block: px in [u*128, u*128+128); C[128px][64c], K=42 pad 64.
// Weights read DIRECTLY from gFC0 image (L2-resident, fragment-ready).
// LDS = sA only (18.4 KB) -> 8 blocks/CU. x staged as dwords (bf16 path).
// Epilogue: C -> sC[c][4rows x 34] image, coalesced 272B-run writeback per c.
__global__ __launch_bounds__(256) void k_fc0(const void* __restrict__ xin,
                                             const void* __restrict__ grd,
                                             const unsigned short* __restrict__ img,
                                             bf16* __restrict__ h,
                                             const float* __restrict__ flg){
    __shared__ unsigned short sA[128*72];   // A[p][k] stride 72; reused as sC[64][68 dw]
    const bool f32 = (flg[0] > 0.5f);
    int B = blockIdx.x;
    int b = (B >> 6)*8 + (B & 7);
    int u = (B >> 3) & 7;
    int t = threadIdx.x;
    unsigned int* sAw = (unsigned int*)sA;
    if (!f32){
        const unsigned int* xd = (const unsigned int*)xin;
        size_t base = ((size_t)b*1024 + u*128)*20;
        for (int i = t; i < 2560; i += 256){      // x rows: 20 dw/px, linear
            int p = i / 20, kd = i - p*20;
            sAw[p*36 + kd] = xd[base + i];
        }
        const unsigned int* gd = (const unsigned int*)grd;
        size_t gb = (size_t)b*1024 + (size_t)u*128;
        if (t < 128) sAw[t*36 + 20] = gd[gb + t]; // grid: 1 dw/px (k 40,41)
    } else {
        const float* xf = (const float*)xin;
        size_t base = ((size_t)b*1024 + u*128)*40;
        for (int i = t; i < 2560; i += 256){
            int p = i / 20, kd = i - p*20;
            sAw[p*36 + kd] = packbf2(xf[base + 2*i], xf[base + 2*i + 1]);
        }
        const float* gf = (const float*)grd;
        size_t gb = ((size_t)b*1024 + u*128)*2;
        if (t < 128) sAw[t*36 + 20] = packbf2(gf[gb + 2*t], gf[gb + 2*t + 1]);
    }
    for (int i = t; i < 1920; i += 256){          // zero k 42..63 (dw 21..35)
        int p = i / 15, j = i - p*15;
        sAw[p*36 + 21 + j] = 0;
    }
    __syncthreads();
    int ln = t & 15, qd = (t & 63) >> 4, wv = t >> 6;
    const float* gbias = (const float*)(img + 4608);
    // B fragments direct from gFC0 image
    bfv8 bfr[4][2];
    #pragma unroll
    for (int nt = 0; nt < 4; ++nt)
        #pragma unroll
        for (int ks = 0; ks < 2; ++ks)
            bfr[nt][ks] = *reinterpret_cast<const bfv8*>(&img[(nt*16 + ln)*72 + ks*32 + qd*8]);
    // 8 m-tiles, 2 per wave
    bfv8 a_[2][2];
    #pragma unroll
    for (int mi = 0; mi < 2; ++mi){
        int mt = wv*2 + mi;
        a_[mi][0] = *reinterpret_cast<const bfv8*>(&sA[(mt*16 + ln)*72 + qd*8]);
        a_[mi][1] = *reinterpret_cast<const bfv8*>(&sA[(mt*16 + ln)*72 + 32 + qd*8]);
    }
    fv4 acc[2][4];
    #pragma unroll
    for (int mi = 0; mi < 2; ++mi)
        #pragma unroll
        for (int nt = 0; nt < 4; ++nt){
            fv4 a = (fv4){0.f,0.f,0.f,0.f};
            a = __builtin_amdgcn_mfma_f32_16x16x32_bf16(a_[mi][0], bfr[nt][0], a, 0, 0, 0);
            a = __builtin_amdgcn_mfma_f32_16x16x32_bf16(a_[mi][1], bfr[nt][1], a, 0, 0, 0);
            acc[mi][nt] = a;
        }
    __syncthreads();
    // ---- C -> sC[c][68 dw] (4 rows x 34, x-pads zeroed) ----
    unsigned int* sCd = (unsigned int*)sA;   // [c][68 dw]
    {
        int c = t >> 2, r = t & 3;           // zero x=32,33 pad dword per (c,row)
        sCd[c*68 + r*17 + 16] = 0;
    }
    #pragma unroll
    for (int mi = 0; mi < 2; ++mi)
        #pragma unroll
        for (int nt = 0; nt < 4; ++nt){
            int c = nt*16 + ln;
            float bb = gbias[c];
            int pl = (wv*2 + mi)*16 + qd*4;  // local px, 4 consecutive, same row
            int y = pl >> 5, x = pl & 31;
            int di = c*68 + y*17 + (x >> 1);
            sCd[di]     = packbf2(acc[mi][nt][0] + bb, acc[mi][nt][1] + bb);
            sCd[di + 1] = packbf2(acc[mi][nt][2] + bb, acc[mi][nt][3] + bb);
        }
    __syncthreads();
    // ---- coalesced writeback of block-owned 272B runs ----
    unsigned int* hw = (unsigned int*)(h + (size_t)b*73984);
    for (int i = t; i < 4352; i += 256){
        int c = i / 68, d = i - c*68;
        hw[c*578 + u*68 + d] = sCd[i];
    }
    if (u == 7){                              // rows y=32,33 zero (full pad rows)
        for (int i = t; i < 2176; i += 256){
            int c = i / 34, d = i - c*34;
            hw[c*578 + 544 + d] = 0;
        }
    }
}

// ---------------- forward truncated DFT via MFMA, 4 channels per block -------
// grid 4096 = 256 b x 16 ch-groups; writes hft [cg][b][m][8bf16] (coalesced)
// F1 (x-DFT): C1[(c,y)][2kx+s] = sum_x h[c][y][x] * gB1  (K=64, x pad)
// F2 (y-DFT): C2[(c,kx)][2ky+s] = sum_{2y+p} Gx * gB2    (K=96, pad)
// B operands read DIRECTLY from global images (L2-resident, fragment-ready) —
// no per-block image rebuild; LDS 30.7 KB -> 5 blocks/CU.
__global__ __launch_bounds__(256) void k_fwd(const bf16* __restrict__ h,
                                             unsigned int* __restrict__ hft,
                                             const unsigned short* __restrict__ fwdimg){
    __shared__ unsigned short lds[15360];   // 30,720 B
    unsigned short* sA1 = lds;              // 144 rows x 72 (rows=(c*34+y), k=x pad 64)
    unsigned short* sA2 = lds + 10368;      // 48 x 104 (rows=(c*12+kx), kappa=2y+p pad 96)
    unsigned int* sA1w = (unsigned int*)sA1;
    unsigned int* sA2w = (unsigned int*)sA2;
    const unsigned short* gB1 = fwdimg;          // [row<32][64 u16]
    const unsigned short* gB2 = fwdimg + 2048;   // [row<48][96 u16]
    int blk = blockIdx.x;
    int b = blk >> 4, c0 = (blk & 15) * 4;
    int t = threadIdx.x;
    // stage h (4 planes) into sA1 rows (c*34+y), dword granularity (coalesced)
    const unsigned int* srcp = (const unsigned int*)(h + (size_t)b*73984 + (size_t)c0*1156);
    for (int i = t; i < 2312; i += 256){
        int c = i / 578; int rem = i - c*578;
        int y = rem / 17; int d = rem - y*17;
        sA1w[(c*34 + y)*36 + d] = srcp[i];
    }
    // zero x-pad dwords 17..31 of rows 0..135
    for (int i = t; i < 2040; i += 256){
        int r = i / 15, d = i - r*15;
        sA1w[r*36 + 17 + d] = 0;
    }
    // zero tail rows 136..143 entirely
    for (int i = t; i < 288; i += 256){
        int r = 136 + i / 36, d = i - (i/36)*36;
        sA1w[r*36 + d] = 0;
    }
    // zero sA2 kappa pad [68,96) = dwords 34..47 of each row
    for (int i = t; i < 672; i += 256){
        int r = i / 14, d = i - r*14;
        sA2w[r*52 + 34 + d] = 0;
    }
    __syncthreads();
    int ln = t & 15, qd = (t & 63) >> 4, wv = t >> 6;
    // ---- F1: 9 M-tiles x 2 N-tiles, K=64; wave owns one nt (static frag idx) ----
    {
        int ntw = wv & 1;
        bfv8 b1f[2];
        #pragma unroll
        for (int ks = 0; ks < 2; ++ks)
            b1f[ks] = *reinterpret_cast<const bfv8*>(&gB1[(ntw*16 + ln)*64 + ks*32 + qd*8]);
        int col = ntw*16 + ln;
        int kx = col >> 1, s = col & 1;
        for (int mt = (wv >> 1); mt < 9; mt += 2){
            fv4 acc = (fv4){0.f,0.f,0.f,0.f};
            #pragma unroll
            for (int ks = 0; ks < 2; ++ks){
                bfv8 a = *reinterpret_cast<const bfv8*>(&sA1[(mt*16 + ln)*72 + ks*32 + qd*8]);
                acc = __builtin_amdgcn_mfma_f32_16x16x32_bf16(a, b1f[ks], acc, 0, 0, 0);
            }
            if (col < 24){
                #pragma unroll
                for (int rr = 0; rr < 4; ++rr){
                    int r = mt*16 + qd*4 + rr;
                    if (r < 136){
                        int c = r / 34, y = r - c*34;
                        sA2[(c*12 + kx)*104 + 2*y + s] = f2us(acc[rr]);
                    }
                }
            }
        }
    }
    __syncthreads();
    // ---- F2: 3 M-tiles x 3 N-tiles, K=96; scatter into sC (reuse sA1) ----
    unsigned short* sC = sA1;   // [m][9]: s*4+c at stride 9 (288*9 = 2592 u16)
    for (int tau = wv; tau < 9; tau += 4){
        int mt = tau / 3, nt = tau - (tau/3)*3;
        fv4 acc = (fv4){0.f,0.f,0.f,0.f};
        #pragma unroll
        for (int ks = 0; ks < 3; ++ks){
            bfv8 a  = *reinterpret_cast<const bfv8*>(&sA2[(mt*16 + ln)*104 + ks*32 + qd*8]);
            bfv8 bb = *reinterpret_cast<const bfv8*>(&gB2[(nt*16 + ln)*96 + ks*32 + qd*8]);
            acc = __builtin_amdgcn_mfma_f32_16x16x32_bf16(a, bb, acc, 0, 0, 0);
        }
        int col = nt*16 + ln;
        int ky = col >> 1, s = col & 1;
        #pragma unroll
        for (int rr = 0; rr < 4; ++rr){
            int r = mt*16 + qd*4 + rr;
            int c = r / 12, kxx = r - c*12;
            sC[(ky*12 + kxx)*9 + s*4 + c] = f2us(acc[rr]);
        }
    }
    __syncthreads();
    // ---- fully-coalesced writeback: block owns hft[cg][b][*] = 1152 dwords ----
    unsigned int* dst = hft + ((size_t)(c0 >> 2)*256 + b)*1152;
    for (int d = t; d < 1152; d += 256){
        int m = d >> 2, j = d & 3;
        unsigned int lo = sC[m*9 + 2*j];
        unsigned int hi = sC[m*9 + 2*j + 1];
        dst[d] = lo | (hi << 16);
    }
}

// ---------------- per-mode channel mix as bf16 MFMA GEMM ---------------------
// grid 576 = 288 modes x 2 M-halves of 128; C[128,128] = A[128,128] x B[128,128]
// A kappa order: kappa = cg*8+u (u<4: Re(c=cg*4+u), u>=4: Im), B staged to match.
// XCD line-mate swizzle: m-quads (same q=m>>2, same mh) get block ids differing
// by multiples of 8 -> same XCD L2 -> hft/weight 64B lines fetched once.
__global__ __launch_bounds__(256) void k_mixm(const unsigned short* __restrict__ hft,
                                              const void* __restrict__ sc_w1,
                                              const void* __restrict__ sc_w2,
                                              unsigned int* __restrict__ mixed, int layer,
                                              const float* __restrict__ flg){
    __shared__ unsigned short sB[128*136];   // BT[n][kappa], row stride 136
    const bool f32 = (flg[0] > 0.5f);
    int B = blockIdx.x;
    int x8 = B & 7, w8 = B >> 3;
    int r4 = w8 & 3, g = w8 >> 2;     // g < 18
    int u = g*8 + x8;                 // u < 144
    int mh = u & 1;
    int m  = (u >> 1)*4 + r4;         // m < 288
    int b0 = mh * 128;
    int t = threadIdx.x;
    int kyi = m / 12, kx = m - kyi*12;
    const void* w = (kyi < 12) ? sc_w1 : sc_w2;
    int r = (kyi < 12) ? kyi : kyi - 12;
    size_t wbase = (size_t)layer * 64*64*144*2;
    for (int idx = t; idx < 4096; idx += 256){     // idx = i*64+o
        int i = idx >> 6, o = idx & 63;
        size_t off = wbase + (((size_t)idx*12 + r)*12 + kx)*2;
        float wr = rdf(w, off, f32);
        float wi = rdf(w, off+1, f32);
        int kre = ((i >> 2) << 3) + (i & 3);       // kappa of Re(c=i)
        sB[o*136 + kre]          = f2us(wr);
        sB[(o+64)*136 + kre]     = f2us(wi);
        sB[o*136 + kre + 4]      = f2us(-wi);
        sB[(o+64)*136 + kre + 4] = f2us(wr);
    }
    __syncthreads();
    int ln = t & 15, qd = (t & 63) >> 4, wv = t >> 6;
    // A fragments: A[row][kappa=ks*32+qd*8 ..+7] = hft[g=ks*4+qd][row][m][0..7]
    bfv8 af[2][4];
    int arow = b0 + wv*32 + ln;
    #pragma unroll
    for (int tm = 0; tm < 2; ++tm)
        #pragma unroll
        for (int ks = 0; ks < 4; ++ks){
            int gg = ks*4 + qd;
            af[tm][ks] = *reinterpret_cast<const bfv8*>(
                hft + (((size_t)gg*256 + arow + tm*16)*288 + m)*8);
        }
    fv4 acc[2][8];
    #pragma unroll
    for (int tm=0;tm<2;++tm)
        #pragma unroll
        for (int tn=0;tn<8;++tn) acc[tm][tn] = (fv4){0.f,0.f,0.f,0.f};
    #pragma unroll
    for (int ks = 0; ks < 4; ++ks){
        bfv8 bfr[8];
        #pragma unroll
        for (int tn = 0; tn < 8; ++tn)
            bfr[tn] = *reinterpret_cast<const bfv8*>(&sB[(tn*16 + ln)*136 + ks*32 + qd*8]);
        #pragma unroll
        for (int tm = 0; tm < 2; ++tm)
            #pragma unroll
            for (int tn = 0; tn < 8; ++tn)
                acc[tm][tn] = __builtin_amdgcn_mfma_f32_16x16x32_bf16(af[tm][ks], bfr[tn], acc[tm][tn], 0, 0, 0);
    }
    __syncthreads();
    // C -> LDS (reuse sB): C[row][col], row stride 136; C/D map row=qd*4+r, col=ln
    #pragma unroll
    for (int tm = 0; tm < 2; ++tm)
        #pragma unroll
        for (int tn = 0; tn < 8; ++tn)
            #pragma unroll
            for (int rr = 0; rr < 4; ++rr){
                int row = wv*32 + tm*16 + qd*4 + rr;
                int col = tn*16 + ln;
                sB[row*136 + col] = f2us(acc[tm][tn][rr]);
            }
    __syncthreads();
    // pack (r,i) and write mixed[b][m][o] — 256B contiguous per (b,m), coalesced
    for (int idx = t; idx < 8192; idx += 256){
        int row = idx >> 6, o = idx & 63;
        unsigned int pr = ((unsigned int)sB[row*136 + o]) |
                          (((unsigned int)sB[row*136 + o + 64]) << 16);
        mixed[((size_t)(b0 + row)*288 + m)*64 + o] = pr;
    }
}

// ---------------- pointwise 64x64 channel GEMM (wc path) as MFMA, IN PLACE ---
// grid 1280: b = blk&255, u = blk>>8 (5 px-chunks of 240; chunks of same b
// co-XCD: ids differ by 256). C[240px][64o] = A[240px][64c] x w[o][c]^T + bias.
// Per-chunk in-place: block reads/writes only its own px range (disjoint).
__global__ __launch_bounds__(256) void k_wc(bf16* __restrict__ h,
                                            const void* __restrict__ wc_w,
                                            const void* __restrict__ wc_b,
                                            int layer,
                                            const float* __restrict__ flg){
    __shared__ unsigned short sA[240*72];   // A[p][c], stride 72; reused as sC[64][240]
    __shared__ unsigned short sBT[64*72];   // BT[o][c], stride 72
    __shared__ float sb[64];
    const bool f32 = (flg[0] > 0.5f);
    int blk = blockIdx.x;
    int b = blk & 255, u = blk >> 8;
    int px0 = u*240;
    int npx = 1156 - px0; if (npx > 240) npx = 240;   // 240 or 196
    int ndp = npx >> 1;                                // 120 or 98
    int t = threadIdx.x;
    size_t wbase = (size_t)layer*4096;
    for (int i = t; i < 4096; i += 256){               // wc_w[l][o][c] -> BT[o][c]
        int o = i >> 6, c = i & 63;
        sBT[o*72 + c] = f2us(rdf(wc_w, wbase + i, f32));
    }
    if (t < 64) sb[t] = rdf(wc_b, layer*64 + t, f32);
    // stage A transposed: dword-granular reads of h (always bf16 workspace)
    const unsigned int* srcd = (const unsigned int*)(h + (size_t)b*73984);
    for (int i = t; i < 7680; i += 256){
        int c = i / 120, dp = i - c*120;
        unsigned int v = (dp < ndp) ? srcd[c*578 + (px0 >> 1) + dp] : 0u;
        sA[(2*dp)*72 + c]     = (unsigned short)(v & 0xffff);
        sA[(2*dp + 1)*72 + c] = (unsigned short)(v >> 16);
    }
    __syncthreads();
    int ln = t & 15, qd = (t & 63) >> 4, wv = t >> 6;
    bfv8 bfr[4][2];
    #pragma unroll
    for (int nt = 0; nt < 4; ++nt)
        #pragma unroll
        for (int ks = 0; ks < 2; ++ks)
            bfr[nt][ks] = *reinterpret_cast<const bfv8*>(&sBT[(nt*16 + ln)*72 + ks*32 + qd*8]);
    // 15 m-tiles: wave wv handles mt = wv + 4*mi (mi<4, skip mt>=15)
    bfv8 a_[4][2];
    #pragma unroll
    for (int mi = 0; mi < 4; ++mi){
        int mt = wv + mi*4;
        if (mt < 15){
            a_[mi][0] = *reinterpret_cast<const bfv8*>(&sA[(mt*16 + ln)*72 + qd*8]);
            a_[mi][1] = *reinterpret_cast<const bfv8*>(&sA[(mt*16 + ln)*72 + 32 + qd*8]);
        }
    }
    fv4 acc[4][4];
    #pragma unroll
    for (int mi = 0; mi < 4; ++mi){
        int mt = wv + mi*4;
        if (mt < 15){
            #pragma unroll
            for (int nt = 0; nt < 4; ++nt){
                fv4 a = (fv4){0.f,0.f,0.f,0.f};
                a = __builtin_amdgcn_mfma_f32_16x16x32_bf16(a_[mi][0], bfr[nt][0], a, 0, 0, 0);
                a = __builtin_amdgcn_mfma_f32_16x16x32_bf16(a_[mi][1], bfr[nt][1], a, 0, 0, 0);
                acc[mi][nt] = a;
            }
        }
    }
    __syncthreads();
    // C -> sC[o][240] (transpose back), bias added
    unsigned int* sCd = (unsigned int*)sA;   // [o][120 dw]
    #pragma unroll
    for (int mi = 0; mi < 4; ++mi){
        int mt = wv + mi*4;
        if (mt < 15){
            #pragma unroll
            for (int nt = 0; nt < 4; ++nt){
                int o = nt*16 + ln;
                float bb = sb[o];
                int p0 = mt*16 + qd*4;
                sCd[o*120 + (p0 >> 1)]     = packbf2(acc[mi][nt][0] + bb, acc[mi][nt][1] + bb);
                sCd[o*120 + (p0 >> 1) + 1] = packbf2(acc[mi][nt][2] + bb, acc[mi][nt][3] + bb);
            }
        }
    }
    __syncthreads();
    // coalesced in-place writeback (own px range only)
    unsigned int* dstd = (unsigned int*)(h + (size_t)b*73984);
    for (int i = t; i < 7680; i += 256){
        int o = i / 120, dp = i - o*120;
        if (dp < ndp) dstd[o*578 + (px0 >> 1) + dp] = sCd[o*120 + dp];
    }
}

// ---------------- inverse truncated DFT as MFMA GEMMs; in-place add + gelu ---
// grid 4096 = 256 b x 16 o-groups of 4, XCD line-mate swizzled:
//   B = z*32 + s*8 + x  ->  b = (z>>2)*8 + x, og = (z&3)*4 + s
//   og-quads of the same b (which share each 64B line of mixed) land on the
//   same XCD (ids differ by 8/16/24) -> line fetched once into that L2.
// B operands (invBT/invW2) are read DIRECTLY from global images (L2-resident,
// fragment-ready layout); OOB rows give garbage discarded by col/y predicates.
// LDS 36.9 KB -> 4 blocks/CU.
__global__ __launch_bounds__(256) void k_invm(const unsigned int* __restrict__ mixed,
                                              const float* __restrict__ tabs,
                                              bf16* __restrict__ hio, int layer){
    __shared__ unsigned short lds[18448];   // 36,896 B total
    unsigned short* sA  = lds;              // 96*40 (step A only; overlaps htile)
    unsigned short* sG  = lds + 4624;       // 4*48*72 (htile = lds[0..4624))
    unsigned int* ldsw  = (unsigned int*)lds;
    int B = blockIdx.x;
    int x8 = B & 7, s4 = (B >> 3) & 3, z = B >> 5;
    int b  = (z >> 2)*8 + x8;
    int o0 = ((z & 3)*4 + s4)*4;
    int t = threadIdx.x;
    const unsigned short* gBT16 = (const unsigned short*)(tabs + 2448);  // [n][32 u16]
    const unsigned short* gW216 = (const unsigned short*)(tabs + 3536);  // [y][64 u16]
    // sA from mixed[b][m][o]: 16B per (m), stride 256B (lines shared intra-XCD)
    const unsigned int* msrc = mixed + (size_t)b*18432 + o0;
    for (int i = t; i < 1152; i += 256){
        int m = i >> 2, ch = i & 3;
        int kyi = m / 12, kx = m - kyi*12;
        ((unsigned int*)sA)[(ch*24 + kyi)*20 + kx] = msrc[(size_t)m*64 + ch];
    }
    for (int i = t; i < 384; i += 256)       // zero k 24..31 (dw 12..15)
        ((unsigned int*)sA)[(i >> 2)*20 + 12 + (i & 3)] = 0;
    // sG: zero only read pads — rows x in [34,48): dw 0..31; rows x<34: dw 24..31
    for (int i = t; i < 1792; i += 256){
        int r = i >> 5;
        int ch = r / 14, x = 34 + (r - (r/14)*14);
        ((unsigned int*)sG)[(ch*48 + x)*36 + (i & 31)] = 0;
    }
    for (int i = t; i < 1088; i += 256){
        int r = i >> 3;
        int ch = r / 34, x = r - (r/34)*34;
        ((unsigned int*)sG)[(ch*48 + x)*36 + 24 + (i & 7)] = 0;
    }
    __syncthreads();
    int ln = t & 15, qd = (t & 63) >> 4, wv = t >> 6;
    // ---- step A: 30 tiles (6 M x 5 N), K=32; B-frag direct from gBT image ----
    for (int tau = wv; tau < 30; tau += 4){
        int mt = tau / 5, nt = tau - mt*5;
        bfv8 a  = *reinterpret_cast<const bfv8*>(&sA[(mt*16 + ln)*40 + qd*8]);
        bfv8 bb = *reinterpret_cast<const bfv8*>(&gBT16[(nt*16 + ln)*32 + qd*8]);
        fv4 acc = (fv4){0.f,0.f,0.f,0.f};
        acc = __builtin_amdgcn_mfma_f32_16x16x32_bf16(a, bb, acc, 0, 0, 0);
        int col = nt*16 + ln;
        if (col < 68){
            int x = col >> 1, ri = col & 1;
            #pragma unroll
            for (int rr = 0; rr < 4; ++rr){
                int row = mt*16 + qd*4 + rr;
                int ch = row / 24, kyi = row - ch*24;
                sG[(ch*48 + x)*72 + 2*kyi + ri] = f2us(acc[rr]);
            }
        }
    }
    __syncthreads();
    // ---- stage htile (4 contiguous ch-planes) into lds[0..2312) dwords ----
    const unsigned int* hsrc = (const unsigned int*)(hio + (size_t)b*73984 + (size_t)o0*1156);
    for (int i = t; i < 2312; i += 256) ldsw[i] = hsrc[i];
    __syncthreads();
    // ---- step B: wave = ch; 3x3 tiles, K=64 (2 MFMAs); A-frag direct from gW2 ----
    int ch = wv;
    #pragma unroll
    for (int mt = 0; mt < 3; ++mt){
        bfv8 a0 = *reinterpret_cast<const bfv8*>(&gW216[(mt*16 + ln)*64 + qd*8]);
        bfv8 a1 = *reinterpret_cast<const bfv8*>(&gW216[(mt*16 + ln)*64 + 32 + qd*8]);
        #pragma unroll
        for (int nt = 0; nt < 3; ++nt){
            bfv8 b0 = *reinterpret_cast<const bfv8*>(&sG[(ch*48 + nt*16 + ln)*72 + qd*8]);
            bfv8 b1 = *reinterpret_cast<const bfv8*>(&sG[(ch*48 + nt*16 + ln)*72 + 32 + qd*8]);
            fv4 acc = (fv4){0.f,0.f,0.f,0.f};
            acc = __builtin_amdgcn_mfma_f32_16x16x32_bf16(a0, b0, acc, 0, 0, 0);
            acc = __builtin_amdgcn_mfma_f32_16x16x32_bf16(a1, b1, acc, 0, 0, 0);
            int x = nt*16 + ln;
            if (x < 34){
                #pragma unroll
                for (int rr = 0; rr < 4; ++rr){
                    int y = mt*16 + qd*4 + rr;
                    if (y < 34){
                        int off = ch*1156 + y*34 + x;
                        float v = acc[rr] + us2f(lds[off]);
                        if (layer < 3) v = gelu_f(v);
                        lds[off] = f2us(v);
                    }
                }
            }
        }
    }
    __syncthreads();
    // ---- coalesced dword writeback ----
    unsigned int* hdst = (unsigned int*)(hio + (size_t)b*73984 + (size_t)o0*1156);
    for (int i = t; i < 2312; i += 256) hdst[i] = ldsw[i];
}

// ---------------- 8x8/stride4 VALID conv -> gelu -> pe2 scale ----------------
__global__ __launch_bounds__(256) void k_pe(const bf16* __restrict__ h,
                                            const void* __restrict__ pw,
                                            const void* __restrict__ pb,
                                            const void* __restrict__ p2w,
                                            const void* __restrict__ p2b,
                                            float* __restrict__ p49,
                                            const float* __restrict__ flg){
    __shared__ float red[256];
    const bool f32 = (flg[0] > 0.5f);
    int bid = blockIdx.x;          // b*49 + py*7 + px
    int b = bid / 49, r = bid - b*49;
    int py = r / 7, px = r - py*7;
    int t = threadIdx.x;
    const bf16* hb = h + (size_t)b*73984 + (py*4)*34 + px*4;
    float partial = 0.f;
    for (int tt = t; tt < 4096; tt += 256){
        int c = tt >> 6, k = tt & 63, ky = k >> 3, kx = k & 7;
        partial += bff(hb[(size_t)c*1156 + ky*34 + kx]) * rdf(pw, tt, f32);
    }
    red[t] = partial;
    __syncthreads();
    for (int s = 128; s > 0; s >>= 1){
        if (t < s) red[t] += red[t + s];
        __syncthreads();
    }
    if (t == 0){
        float v = red[0] + rdf(pb, 0, f32);
        v = gelu_f(v);
        p49[bid] = v * rdf(p2w, 0, f32) + rdf(p2b, 0, f32);
    }
}

// ---------------- sentence MLP 384->32->32->16 (relu,relu,lin) ---------------
// 256 threads: split-K layer 1 (8 groups x 32 outs, coalesced w1 reads, LDS
// reduce) — replaces the 384-iter serial loop that was pure L2-latency-bound.
__global__ __launch_bounds__(256) void k_sent(const void* __restrict__ se,
                                             const void* __restrict__ w1, const void* __restrict__ b1,
                                             const void* __restrict__ w2, const void* __restrict__ b2,
                                             const void* __restrict__ w3, const void* __restrict__ b3,
                                             float* __restrict__ outv,
                                             const float* __restrict__ flg){
    __shared__ float sse[384];
    __shared__ float red[256];
    __shared__ float s1[32], s2[32];
    const bool f32 = (flg[0] > 0.5f);
    int b = blockIdx.x, t = threadIdx.x;
    for (int i = t; i < 384; i += 256) sse[i] = rdf(se, (size_t)b*384 + i, f32);
    __syncthreads();
    {
        int o = t & 31, g = t >> 5;          // 8 k-groups of 48
        float acc = 0.f;
        #pragma unroll 4
        for (int k = g*48; k < g*48 + 48; ++k)
            acc += sse[k] * rdf(w1, (size_t)k*32 + o, f32);
        red[t] = acc;
    }
    __syncthreads();
    if (t < 32){
        float a = rdf(b1, t, f32);
        #pragma unroll
        for (int g = 0; g < 8; ++g) a += red[g*32 + t];
        s1[t] = fmaxf(a, 0.f);
    }
    __syncthreads();
    if (t < 32){
        float acc = rdf(b2, t, f32);
        for (int k = 0; k < 32; ++k) acc += s1[k] * rdf(w2, k*32 + t, f32);
        s2[t] = fmaxf(acc, 0.f);
    }
    __syncthreads();
    if (t < 16){
        float acc = rdf(b3, t, f32);
        for (int k = 0; k < 32; ++k) acc += s2[k] * rdf(w3, k*16 + t, f32);
        outv[b*16 + t] = acc;
    }
}

// ---------------- xp MLP 49->32->32->16 (silu,silu,lin) ----------------------
// 256 threads, split-K layer 1 (8 groups, stride-8 over k<49), LDS reduce.
__global__ __launch_bounds__(256) void k_xp(const float* __restrict__ p49,
                                           const void* __restrict__ w1, const void* __restrict__ b1,
                                           const void* __restrict__ w2, const void* __restrict__ b2,
                                           const void* __restrict__ w3, const void* __restrict__ b3,
                                           float* __restrict__ outv,
                                           const float* __restrict__ flg){
    __shared__ float sp[49];
    __shared__ float red[256];
    __shared__ float s1[32], s2[32];
    const bool f32 = (flg[0] > 0.5f);
    int b = blockIdx.x, t = threadIdx.x;
    if (t < 49) sp[t] = p49[b*49 + t];
    __syncthreads();
    {
        int o = t & 31, g = t >> 5;
        float acc = 0.f;
        for (int k = g; k < 49; k += 8)
            acc += sp[k] * rdf(w1, (size_t)k*32 + o, f32);
        red[t] = acc;
    }
    __syncthreads();
    if (t < 32){
        float a = rdf(b1, t, f32);
        #pragma unroll
        for (int g = 0; g < 8; ++g) a += red[g*32 + t];
        s1[t] = silu_f(a);
    }
    __syncthreads();
    if (t < 32){
        float acc = rdf(b2, t, f32);
        for (int k = 0; k < 32; ++k) acc += s1[k] * rdf(w2, k*32 + t, f32);
        s2[t] = silu_f(acc);
    }
    __syncthreads();
    if (t < 16){
        float acc = rdf(b3, t, f32);
        for (int k = 0; k < 32; ++k) acc += s2[k] * rdf(w3, k*16 + t, f32);
        outv[b*16 + t] = acc;
    }
}

// ---------------- pu MLP part A: 32->128->256 (silu,silu) --------------------
__global__ __launch_bounds__(256) void k_puA(const float* __restrict__ xemb,
                                             const float* __restrict__ semb,
                                             const void* __restrict__ w1, const void* __restrict__ b1,
                                             const void* __restrict__ w2, const void* __restrict__ b2,
                                             float* __restrict__ h2buf,
                                             const float* __restrict__ flg){
    __shared__ float ein[32];
    __shared__ float h1[128];
    const bool f32 = (flg[0] > 0.5f);
    int b = blockIdx.x, t = threadIdx.x;
    if (t < 16) ein[t] = xemb[b*16 + t];
    else if (t < 32) ein[t] = semb[b*16 + (t - 16)];
    __syncthreads();
    if (t < 128){
        float acc = rdf(b1, t, f32);
        for (int k = 0; k < 32; ++k) acc += ein[k] * rdf(w1, k*128 + t, f32);
        h1[t] = silu_f(acc);
    }
    __syncthreads();
    {
        float acc = rdf(b2, t, f32);
        for (int k = 0; k < 128; ++k) acc += h1[k] * rdf(w2, k*256 + t, f32);
        h2buf[(size_t)b*256 + t] = silu_f(acc);
    }
}

// ---------------- pu MLP part B: 256->1156 GEMM ------------------------------
// grid 1280 = 256 b (fast) x 5 n-chunks of 232
__global__ __launch_bounds__(256) void k_puB(const float* __restrict__ h2buf,
                                             const void* __restrict__ w3, const void* __restrict__ b3,
                                             float* __restrict__ emb,
                                             const float* __restrict__ flg){
    __shared__ float sh2[256];
    const bool f32 = (flg[0] > 0.5f);
    int blk = blockIdx.x;
    int b = blk & 255, nc = blk >> 8;
    int t = threadIdx.x;
    sh2[t] = h2buf[(size_t)b*256 + t];
    __syncthreads();
    int e = nc*232 + t;
    if (t < 232 && e < 1156){
        float acc = rdf(b3, e, f32);
        if (f32){
            const float* wp = (const float*)w3 + e;
            #pragma unroll 4
            for (int k = 0; k < 256; ++k) acc += sh2[k] * wp[(size_t)k*1156];
        } else {
            const bf16* wp = (const bf16*)w3 + e;
            #pragma unroll 4
            for (int k = 0; k < 256; ++k) acc += sh2[k] * bff(wp[(size_t)k*1156]);
        }
        emb[(size_t)b*1156 + e] = acc;
    }
}

// ---------------- final: crop, concat emb, fc1(MFMA)+gelu, fc2(MFMA) ---------
// grid 512 = 256 b x 2 halves; 8 iters of 2 rows (64 px).
// fc1: C[64px,128j] = A[px,c<64] x w1 (K=64) + rank-1 emb add; fc2: K=128, N=16(4)
__global__ __launch_bounds__(256, 3) void k_final(const bf16* __restrict__ h,
                                                  const float* __restrict__ emb,
                                                  const void* __restrict__ w1, const void* __restrict__ b1,
                                                  const void* __restrict__ w2, const void* __restrict__ b2,
                                                  void* __restrict__ out,
                                                  const float* __restrict__ flg){
    __shared__ unsigned short sw1t[128*72];   // w1T[j][c], stride 72 (16B-aligned rows)
    __shared__ unsigned short sw2t[16*136];   // w2T[n][j], rows 4..15 zero
    __shared__ float sw1e[128];               // w1[64][j] (emb channel)
    __shared__ float sb1[128];
    __shared__ float sb2[4];
    __shared__ unsigned short spx[64*66];     // input[c][px], stride 66 (odd dwords)
    __shared__ float sembp[64];               // emb[px]
    __shared__ unsigned short sh2[128*66];    // hid[j][px], stride 66
    const bool f32 = (flg[0] > 0.5f);
    int blk = blockIdx.x;
    int b = blk >> 1, half = blk & 1;
    int t = threadIdx.x;
    for (int i = t; i < 8320; i += 256){       // w1 [c=65][j=128]
        int c = i >> 7, j = i & 127;
        float v = rdf(w1, i, f32);
        if (c < 64) sw1t[j*72 + c] = f2us(v);
        else sw1e[j] = v;
    }
    if (t < 128) sb1[t] = rdf(b1, t, f32);
    for (int i = t; i < 2176; i += 256){       // w2 [j=128][k=4] -> w2T[n][j]
        int n = i / 136, j = i - n*136;
        float v = (n < 4 && j < 128) ? rdf(w2, j*4 + n, f32) : 0.f;
        sw2t[i] = f2us(v);
    }
    if (t < 4) sb2[t] = rdf(b2, t, f32);
    __syncthreads();
    int ln = t & 15, qd = (t & 63) >> 4, wv = t >> 6;
    // hoist B fragments (weights) into registers
    bfv8 bw1[8][2];
    #pragma unroll
    for (int tn = 0; tn < 8; ++tn)
        #pragma unroll
        for (int ks = 0; ks < 2; ++ks)
            bw1[tn][ks] = *reinterpret_cast<const bfv8*>(&sw1t[(tn*16 + ln)*72 + ks*32 + qd*8]);
    bfv8 bw2[4];
    #pragma unroll
    for (int ks = 0; ks < 4; ++ks)
        bw2[ks] = *reinterpret_cast<const bfv8*>(&sw2t[ln*136 + ks*32 + qd*8]);
    const bf16* hb = h + (size_t)b*73984;
    const float* eb = emb + (size_t)b*1156;
    for (int it = 0; it < 8; ++it){
        int y0 = half*16 + it*2;               // 2 rows = 64 px
        __syncthreads();
        for (int e = t; e < 2048; e += 256){   // stage spx[c][px] c-major
            int c = e >> 5, d = e & 31;
            int px = d*2;
            int y = y0 + (px >> 5), x = px & 31;
            float v0 = bff(hb[(size_t)c*1156 + y*34 + x]);
            int px1 = px + 1;
            int y1 = y0 + (px1 >> 5), x1 = px1 & 31;
            float v1 = bff(hb[(size_t)c*1156 + y1*34 + x1]);
            ((unsigned int*)spx)[c*33 + d] = packbf2(v0, v1);
        }
        if (t < 64){
            int y = y0 + (t >> 5), x = t & 31;
            sembp[t] = eb[y*34 + x];
        }
        __syncthreads();
        // fc1 MFMA: wave wv owns mtile wv (px = wv*16 + ...)
        fv4 acc[8];
        #pragma unroll
        for (int tn = 0; tn < 8; ++tn) acc[tn] = (fv4){0.f,0.f,0.f,0.f};
        #pragma unroll
        for (int ks = 0; ks < 2; ++ks){
            union { bfv8 v; unsigned short s[8]; } af;
            #pragma unroll
            for (int j = 0; j < 8; ++j)
                af.s[j] = spx[(ks*32 + qd*8 + j)*66 + wv*16 + ln];
            #pragma unroll
            for (int tn = 0; tn < 8; ++tn)
                acc[tn] = __builtin_amdgcn_mfma_f32_16x16x32_bf16(af.v, bw1[tn][ks], acc[tn], 0, 0, 0);
        }
        float ev[4];
        #pragma unroll
        for (int rr = 0; rr < 4; ++rr) ev[rr] = sembp[wv*16 + qd*4 + rr];
        #pragma unroll
        for (int tn = 0; tn < 8; ++tn){
            int col = tn*16 + ln;
            float we = sw1e[col];
            float bb1 = sb1[col];
            #pragma unroll
            for (int rr = 0; rr < 4; ++rr){
                float v = acc[tn][rr] + ev[rr]*we + bb1;
                sh2[col*66 + wv*16 + qd*4 + rr] = f2us(gelu_f(v));
            }
        }
        __syncthreads();
        // fc2 MFMA: K=128, N=16 (4 valid)
        fv4 a2 = (fv4){0.f,0.f,0.f,0.f};
        #pragma unroll
        for (int ks = 0; ks < 4; ++ks){
            union { bfv8 v; unsigned short s[8]; } af;
            #pragma unroll
            for (int j = 0; j < 8; ++j)
                af.s[j] = sh2[(ks*32 + qd*8 + j)*66 + wv*16 + ln];
            a2 = __builtin_amdgcn_mfma_f32_16x16x32_bf16(af.v, bw2[ks], a2, 0, 0, 0);
        }
        if (ln < 4){
            float bb2 = sb2[ln];
            #pragma unroll
            for (int rr = 0; rr < 4; ++rr){
                int pxl = wv*16 + qd*4 + rr;
                int y = y0 + (pxl >> 5), x = pxl & 31;
                size_t o = ((size_t)(b*32 + y)*32 + x)*4 + ln;
                float v = a2[rr] + bb2;
                if (f32) ((float*)out)[o] = v;
                else     ((bf16*)out)[o] = __float2bfloat16(v);
            }
        }
    }
}

extern "C" void kernel_launch(void* const* d_in, const int* in_sizes, int n_in,
                              void* d_out, int out_size, void* d_ws, size_t ws_size,
                              hipStream_t stream) {
    (void)in_sizes; (void)n_in; (void)out_size; (void)ws_size;
    const void* x     = d_in[0];
    const void* grd   = d_in[1];
    const void* se    = d_in[2];
    const void* fc0_w = d_in[3];
    const void* fc0_b = d_in[4];
    const void* sc_w1 = d_in[5];
    const void* sc_w2 = d_in[6];
    const void* wc_w  = d_in[7];
    const void* wc_b  = d_in[8];
    const void* pe1_w = d_in[9];
    const void* pe1_b = d_in[10];
    const void* pe2_w = d_in[11];
    const void* pe2_b = d_in[12];
    const void* sp_w1 = d_in[13];
    const void* sp_b1 = d_in[14];
    const void* sp_w2 = d_in[15];
    const void* sp_b2 = d_in[16];
    const void* sp_w3 = d_in[17];
    const void* sp_b3 = d_in[18];
    const void* xp_w1 = d_in[19];
    const void* xp_b1 = d_in[20];
    const void* xp_w2 = d_in[21];
    const void* xp_b2 = d_in[22];
    const void* xp_w3 = d_in[23];
    const void* xp_b3 = d_in[24];
    const void* pu_w1 = d_in[25];
    const void* pu_b1 = d_in[26];
    const void* pu_w2 = d_in[27];
    const void* pu_b2 = d_in[28];
    const void* pu_w3 = d_in[29];
    const void* pu_b3 = d_in[30];
    const void* fc1_w = d_in[31];
    const void* fc1_b = d_in[32];
    const void* fc2_w = d_in[33];
    const void* fc2_b = d_in[34];

    // workspace layout (float-unit offsets); total ~77 MB
    float* ws    = (float*)d_ws;
    bf16*  hA    = (bf16*)ws;                              // 18,939,904 bf16
    unsigned int* hft   = (unsigned int*)(ws + 9469952);   // 4,718,592 dwords (hft cg-panels)
    unsigned int* mixed = (unsigned int*)(ws + 14188544);  // 4,718,592 dwords ([b][m][o])
    float* tabs  = ws + 18907136;                          // 4,896 (DFT tables + inv images)
    float* p49   = ws + 18912032;                          // 12,544
    float* semb  = ws + 18924576;                          // 4,096
    float* xemb  = ws + 18928672;                          // 4,096
    float* emb   = ws + 18932768;                          // 295,936
    float* flag  = ws + 19228704;                          // 1
    float* h2buf = (float*)hft;                            // reuse: hft dead after layer loop
    // fwd B-images + fc0 weight image live in emb region (dead during layer
    // loop; k_puB writes emb only after the last k_invm; rebuilt each replay)
    float* fwdimg = emb;                                   // 5,696 floats

    k_probe<<<1, 256, 0, stream>>>(x, flag);
    k_tables<<<1, 256, 0, stream>>>(tabs, fwdimg, fc0_w, fc0_b, flag);
    k_fc0<<<2048, 256, 0, stream>>>(x, grd, (const unsigned short*)(fwdimg + 3328), hA, flag);

    for (int l = 0; l < 4; ++l){
        k_fwd<<<4096, 256, 0, stream>>>(hA, hft, (const unsigned short*)fwdimg);
        k_mixm<<<576, 256, 0, stream>>>((const unsigned short*)hft, sc_w1, sc_w2, mixed, l, flag);
        k_wc <<<1280, 256, 0, stream>>>(hA, wc_w, wc_b, l, flag);
        k_invm<<<4096, 256, 0, stream>>>(mixed, tabs, hA, l);
    }

    k_pe  <<<256*49, 256, 0, stream>>>(hA, pe1_w, pe1_b, pe2_w, pe2_b, p49, flag);
    k_sent<<<256, 256, 0, stream>>>(se, sp_w1, sp_b1, sp_w2, sp_b2, sp_w3, sp_b3, semb, flag);
    k_xp  <<<256, 256, 0, stream>>>(p49, xp_w1, xp_b1, xp_w2, xp_b2, xp_w3, xp_b3, xemb, flag);
    k_puA <<<256, 256, 0, stream>>>(xemb, semb, pu_w1, pu_b1, pu_w2, pu_b2, h2buf, flag);
    k_puB <<<1280, 256, 0, stream>>>(h2buf, pu_w3, pu_b3, emb, flag);
    k_final<<<512, 256, 0, stream>>>(hA, emb, fc1_w, fc1_b, fc2_w, fc2_b, d_out, flag);
}

// Round 11
// 1002.389 us; speedup vs baseline: 1.4118x; 1.0574x over previous
//
#include <hip/hip_runtime.h>
#include <hip/hip_bf16.h>
#include <math.h>

typedef __hip_bfloat16 bf16;
typedef __bf16 bfv8 __attribute__((ext_vector_type(8)));
typedef float fv4 __attribute__((ext_vector_type(4)));

__device__ __forceinline__ float bff(const bf16 x){ return __bfloat162float(x); }
// fast gelu: 0.5 v (1 + erf(v/sqrt2)); erf via A&S 7.1.26 (|err|<1.5e-7),
// branchless, hardware v_exp/v_rcp. ~14 VALU vs ocml erff's ~30 (branchy).
__device__ __forceinline__ float gelu_f(float v){
    float x = v * 0.70710678118654752f;
    float ax = fabsf(x);
    float t = __builtin_amdgcn_rcpf(1.0f + 0.3275911f * ax);
    float y = t*(0.254829592f + t*(-0.284496736f + t*(1.421413741f +
              t*(-1.453152027f + t*1.061405429f))));
    float er = 1.0f - y * __expf(-ax*ax);
    er = (x < 0.f) ? -er : er;
    return 0.5f * v * (1.0f + er);
}
__device__ __forceinline__ float silu_f(float v){
    return v / (1.f + __expf(-v));
}
// dtype-agnostic input read: f32 ? fp32 : bf16
__device__ __forceinline__ float rdf(const void* p, size_t i, bool f32){
    return f32 ? ((const float*)p)[i] : __bfloat162float(((const bf16*)p)[i]);
}
__device__ __forceinline__ unsigned int packbf2(float a, float b){
    __hip_bfloat162 v;
    v.x = __float2bfloat16(a);
    v.y = __float2bfloat16(b);
    return *reinterpret_cast<unsigned int*>(&v);
}
__device__ __forceinline__ float2 unpackbf2(unsigned int u){
    __hip_bfloat162 v = *reinterpret_cast<__hip_bfloat162*>(&u);
    return make_float2(__bfloat162float(v.x), __bfloat162float(v.y));
}
__device__ __forceinline__ float us2f(unsigned short u){
    unsigned int x = ((unsigned int)u) << 16;
    return __uint_as_float(x);
}
__device__ __forceinline__ unsigned short f2us(float f){
    bf16 v = __float2bfloat16(f);
    return *reinterpret_cast<unsigned short*>(&v);
}

// Geometry
// B=256, C=64, H=W=34 (padded), modes: ky in {0..11, 22..33} (24), kx in 0..11 (12)
// h layout (ws, bf16): [b][c][y][x], stride c = 1156, stride b = 73984
// hft layout: [cg<16][b<256][m<288][8 bf16] ; kappa = cg*8+u, u<4: Re(c=cg*4+u),
//             u>=4: Im(c=cg*4+u-4).  Writer (k_fwd) fully coalesced per block.
// mixed layout: [b<256][m<288][o<64] packed bf16x2 dwords (r,i); writer (k_mixm)
//             owns full 256B rows per (b,m).
// tabs: [0,1632) Wfy f32 | [1632,2448) Wfx f32 |
//       [2448,3536) invBT bf16 image (68x16 dw) | [3536,4624) invW2 bf16 image (34x32 dw)
// fwd images (in emb region, dead during layer loop):
//   gB1 [row<32][64 u16] | gB2 [row<48][96 u16] | gFC0 [c<64][72 u16] @ +3328 fl |
//   gFC0b [64 f32] @ +5632 fl
// All images fragment-ready: k_fwd/k_invm/k_fc0 read MFMA fragments DIRECTLY from
// global (16B-aligned rows, pads pre-zeroed; OOB rows discarded by predicates).

// ---------------- dtype probe ----------------
__global__ __launch_bounds__(256) void k_probe(const void* x, float* flag){
    __shared__ int wild;
    int t = threadIdx.x;
    if (t == 0) wild = 0;
    __syncthreads();
    const bf16* xb = (const bf16*)x;
    for (int i = t; i < 1024; i += 256){
        float v = bff(xb[i]);
        if (!(fabsf(v) < 1e10f)) wild = 1;
    }
    __syncthreads();
    if (t == 0) flag[0] = wild ? 1.f : 0.f;
}

// ---------------- tables ----------------
__global__ __launch_bounds__(256) void k_tables(float* tabs, float* fwdimg,
                                                const void* __restrict__ fc0w,
                                                const void* __restrict__ fc0b,
                                                const float* __restrict__ flg){
    int t = threadIdx.x;
    const bool f32 = (flg[0] > 0.5f);
    unsigned int* gBT = (unsigned int*)(tabs + 2448);   // [n<68][kd<16] bf16x2
    unsigned int* gW2 = (unsigned int*)(tabs + 3536);   // [y<34][kd<32] bf16x2
    unsigned short* gB1 = (unsigned short*)fwdimg;          // [row<32][64]
    unsigned short* gB2 = (unsigned short*)(fwdimg + 1024); // [row<48][96]
    unsigned short* gF  = (unsigned short*)(fwdimg + 3328); // [c<64][72]
    float* gFb = fwdimg + 5632;                             // [64]
    const float TWO_PI = 6.283185307179586f;
    // gFC0 image: BT[c][k] from fc0_w [k=42][c=64], k-pads zeroed
    for (int i = t; i < 4608; i += 256){
        int c = i / 72, k = i - c*72;
        float v = (k < 42) ? rdf(fc0w, (size_t)k*64 + c, f32) : 0.f;
        gF[i] = f2us(v);
    }
    if (t < 64) gFb[t] = rdf(fc0b, t, f32);
    // gB1: row=2kx+s (kx<12), k=x<34: e^{-i ang} component (s=0: cos, s=1: -sin)
    for (int i = t; i < 2048; i += 256){
        int row = i >> 6, k = i & 63;
        float v = 0.f;
        if (row < 24 && k < 34){
            int kx = row >> 1, s = row & 1;
            int ph = (kx * k) % 34;
            float ang = TWO_PI * (float)ph / 34.0f;
            float sn, cs;
            sincosf(ang, &sn, &cs);
            v = (s == 0) ? cs : -sn;
        }
        gB1[i] = f2us(v);
    }
    // gB2: row=2ky+s (kyi<24), kk=2y+p<68: realified [[wr,-wi],[wi,wr]] of e^{-i ang}
    for (int i = t; i < 4608; i += 256){
        int row = i / 96, kk = i - row*96;
        float v = 0.f;
        if (kk < 68){
            int kyi = row >> 1, s = row & 1;
            int y = kk >> 1, p = kk & 1;
            int ky = (kyi < 12) ? kyi : kyi + 10;
            int ph = (ky * y) % 34;
            float ang = TWO_PI * (float)ph / 34.0f;
            float sn, cs;
            sincosf(ang, &sn, &cs);
            float wr = cs, wi = -sn;
            v = (s == 0) ? ((p == 0) ? wr : -wi) : ((p == 0) ? wi : wr);
        }
        gB2[i] = f2us(v);
    }
    // invBT image: n=2x+ri (x<34), k=2kx+ri2; v = ri==0 ? (ri2==0? C : -S) : (ri2==0? S : C)
    // where C = ck*cos(ang), S = ck*sin(ang), ang = +2pi*(kx*x mod 34)/34, ck = (kx==0?1:2)
    for (int i = t; i < 1088; i += 256){
        int n = i >> 4, kd = i & 15;
        int x = n >> 1, ri = n & 1;
        int kx = kd;
        float v0 = 0.f, v1 = 0.f;
        if (kx < 12){
            int ph = (kx * x) % 34;
            float ang = TWO_PI * (float)ph / 34.0f;
            float s, c;
            sincosf(ang, &s, &c);
            float ck = (kx == 0) ? 1.0f : 2.0f;
            float C = ck * c, S = ck * s;
            v0 = (ri == 0) ? C : S;       // ri2 = 0
            v1 = (ri == 0) ? -S : C;      // ri2 = 1
        }
        gBT[i] = packbf2(v0, v1);
    }
    // invW2 image: y<34, k=2kyi+ri; v = (1/1156)*(ri==0? cos : -sin), ang=+2pi*(ky*y mod 34)/34
    for (int i = t; i < 1088; i += 256){
        int y = i >> 5, kd = i & 31;
        int kyi = kd;
        float v0 = 0.f, v1 = 0.f;
        if (kyi < 24){
            int ky = (kyi < 12) ? kyi : kyi + 10;
            int ph = (ky * y) % 34;
            float ang = TWO_PI * (float)ph / 34.0f;
            float s, c;
            sincosf(ang, &s, &c);
            v0 = c * (1.0f/1156.0f);
            v1 = -s * (1.0f/1156.0f);
        }
        gW2[i] = packbf2(v0, v1);
    }
}

// ---------------- fc0 as MFMA GEMM: concat(x,grid) @ fc0_w + b ---------------
// grid 2048: B -> b = (B>>6)*8 + (B&7), u = (B>>3)&7  (8 chunks of b co-XCD)
// Block: px in [u*128, u*128+128); C[128px][64c], K=42 pad 64.
// Weights read DIRECTLY from gFC0 image (L2-resident, fragment-ready).
// LDS = sA only (18.4 KB) -> 8 blocks/CU. x staged as dwords (bf16 path).
// Epilogue: C -> sC[c][4rows x 34] image, coalesced 272B-run writeback per c.
__global__ __launch_bounds__(256) void k_fc0(const void* __restrict__ xin,
                                             const void* __restrict__ grd,
                                             const unsigned short* __restrict__ img,
                                             bf16* __restrict__ h,
                                             const float* __restrict__ flg){
    __shared__ unsigned short sA[128*72];   // A[p][k] stride 72; reused as sC[64][68 dw]
    const bool f32 = (flg[0] > 0.5f);
    int B = blockIdx.x;
    int b = (B >> 6)*8 + (B & 7);
    int u = (B >> 3) & 7;
    int t = threadIdx.x;
    unsigned int* sAw = (unsigned int*)sA;
    if (!f32){
        const unsigned int* xd = (const unsigned int*)xin;
        size_t base = ((size_t)b*1024 + u*128)*20;
        for (int i = t; i < 2560; i += 256){      // x rows: 20 dw/px, linear
            int p = i / 20, kd = i - p*20;
            sAw[p*36 + kd] = xd[base + i];
        }
        const unsigned int* gd = (const unsigned int*)grd;
        size_t gb = (size_t)b*1024 + (size_t)u*128;
        if (t < 128) sAw[t*36 + 20] = gd[gb + t]; // grid: 1 dw/px (k 40,41)
    } else {
        const float* xf = (const float*)xin;
        size_t base = ((size_t)b*1024 + u*128)*40;
        for (int i = t; i < 2560; i += 256){
            int p = i / 20, kd = i - p*20;
            sAw[p*36 + kd] = packbf2(xf[base + 2*i], xf[base + 2*i + 1]);
        }
        const float* gf = (const float*)grd;
        size_t gb = ((size_t)b*1024 + u*128)*2;
        if (t < 128) sAw[t*36 + 20] = packbf2(gf[gb + 2*t], gf[gb + 2*t + 1]);
    }
    for (int i = t; i < 1920; i += 256){          // zero k 42..63 (dw 21..35)
        int p = i / 15, j = i - p*15;
        sAw[p*36 + 21 + j] = 0;
    }
    __syncthreads();
    int ln = t & 15, qd = (t & 63) >> 4, wv = t >> 6;
    const float* gbias = (const float*)(img + 4608);
    // B fragments direct from gFC0 image
    bfv8 bfr[4][2];
    #pragma unroll
    for (int nt = 0; nt < 4; ++nt)
        #pragma unroll
        for (int ks = 0; ks < 2; ++ks)
            bfr[nt][ks] = *reinterpret_cast<const bfv8*>(&img[(nt*16 + ln)*72 + ks*32 + qd*8]);
    // 8 m-tiles, 2 per wave
    bfv8 a_[2][2];
    #pragma unroll
    for (int mi = 0; mi < 2; ++mi){
        int mt = wv*2 + mi;
        a_[mi][0] = *reinterpret_cast<const bfv8*>(&sA[(mt*16 + ln)*72 + qd*8]);
        a_[mi][1] = *reinterpret_cast<const bfv8*>(&sA[(mt*16 + ln)*72 + 32 + qd*8]);
    }
    fv4 acc[2][4];
    #pragma unroll
    for (int mi = 0; mi < 2; ++mi)
        #pragma unroll
        for (int nt = 0; nt < 4; ++nt){
            fv4 a = (fv4){0.f,0.f,0.f,0.f};
            a = __builtin_amdgcn_mfma_f32_16x16x32_bf16(a_[mi][0], bfr[nt][0], a, 0, 0, 0);
            a = __builtin_amdgcn_mfma_f32_16x16x32_bf16(a_[mi][1], bfr[nt][1], a, 0, 0, 0);
            acc[mi][nt] = a;
        }
    __syncthreads();
    // ---- C -> sC[c][68 dw] (4 rows x 34, x-pads zeroed) ----
    unsigned int* sCd = (unsigned int*)sA;   // [c][68 dw]
    {
        int c = t >> 2, r = t & 3;           // zero x=32,33 pad dword per (c,row)
        sCd[c*68 + r*17 + 16] = 0;
    }
    #pragma unroll
    for (int mi = 0; mi < 2; ++mi)
        #pragma unroll
        for (int nt = 0; nt < 4; ++nt){
            int c = nt*16 + ln;
            float bb = gbias[c];
            int pl = (wv*2 + mi)*16 + qd*4;  // local px, 4 consecutive, same row
            int y = pl >> 5, x = pl & 31;
            int di = c*68 + y*17 + (x >> 1);
            sCd[di]     = packbf2(acc[mi][nt][0] + bb, acc[mi][nt][1] + bb);
            sCd[di + 1] = packbf2(acc[mi][nt][2] + bb, acc[mi][nt][3] + bb);
        }
    __syncthreads();
    // ---- coalesced writeback of block-owned 272B runs ----
    unsigned int* hw = (unsigned int*)(h + (size_t)b*73984);
    for (int i = t; i < 4352; i += 256){
        int c = i / 68, d = i - c*68;
        hw[c*578 + u*68 + d] = sCd[i];
    }
    if (u == 7){                              // rows y=32,33 zero (full pad rows)
        for (int i = t; i < 2176; i += 256){
            int c = i / 34, d = i - c*34;
            hw[c*578 + 544 + d] = 0;
        }
    }
}

// ---------------- forward truncated DFT via MFMA, 4 channels per block -------
// grid 4096 = 256 b x 16 ch-groups; writes hft [cg][b][m][8bf16] (coalesced)
// F1 (x-DFT): C1[(c,y)][2kx+s] = sum_x h[c][y][x] * gB1  (K=64, x pad)
// F2 (y-DFT): C2[(c,kx)][2ky+s] = sum_{2y+p} Gx * gB2    (K=96, pad)
// B operands read DIRECTLY from global images (L2-resident, fragment-ready) —
// no per-block image rebuild; LDS 30.7 KB -> 5 blocks/CU.
__global__ __launch_bounds__(256) void k_fwd(const bf16* __restrict__ h,
                                             unsigned int* __restrict__ hft,
                                             const unsigned short* __restrict__ fwdimg){
    __shared__ unsigned short lds[15360];   // 30,720 B
    unsigned short* sA1 = lds;              // 144 rows x 72 (rows=(c*34+y), k=x pad 64)
    unsigned short* sA2 = lds + 10368;      // 48 x 104 (rows=(c*12+kx), kappa=2y+p pad 96)
    unsigned int* sA1w = (unsigned int*)sA1;
    unsigned int* sA2w = (unsigned int*)sA2;
    const unsigned short* gB1 = fwdimg;          // [row<32][64 u16]
    const unsigned short* gB2 = fwdimg + 2048;   // [row<48][96 u16]
    int blk = blockIdx.x;
    int b = blk >> 4, c0 = (blk & 15) * 4;
    int t = threadIdx.x;
    // stage h (4 planes) into sA1 rows (c*34+y), dword granularity (coalesced)
    const unsigned int* srcp = (const unsigned int*)(h + (size_t)b*73984 + (size_t)c0*1156);
    for (int i = t; i < 2312; i += 256){
        int c = i / 578; int rem = i - c*578;
        int y = rem / 17; int d = rem - y*17;
        sA1w[(c*34 + y)*36 + d] = srcp[i];
    }
    // zero x-pad dwords 17..31 of rows 0..135
    for (int i = t; i < 2040; i += 256){
        int r = i / 15, d = i - r*15;
        sA1w[r*36 + 17 + d] = 0;
    }
    // zero tail rows 136..143 entirely
    for (int i = t; i < 288; i += 256){
        int r = 136 + i / 36, d = i - (i/36)*36;
        sA1w[r*36 + d] = 0;
    }
    // zero sA2 kappa pad [68,96) = dwords 34..47 of each row
    for (int i = t; i < 672; i += 256){
        int r = i / 14, d = i - r*14;
        sA2w[r*52 + 34 + d] = 0;
    }
    __syncthreads();
    int ln = t & 15, qd = (t & 63) >> 4, wv = t >> 6;
    // ---- F1: 9 M-tiles x 2 N-tiles, K=64; wave owns one nt (static frag idx) ----
    {
        int ntw = wv & 1;
        bfv8 b1f[2];
        #pragma unroll
        for (int ks = 0; ks < 2; ++ks)
            b1f[ks] = *reinterpret_cast<const bfv8*>(&gB1[(ntw*16 + ln)*64 + ks*32 + qd*8]);
        int col = ntw*16 + ln;
        int kx = col >> 1, s = col & 1;
        for (int mt = (wv >> 1); mt < 9; mt += 2){
            fv4 acc = (fv4){0.f,0.f,0.f,0.f};
            #pragma unroll
            for (int ks = 0; ks < 2; ++ks){
                bfv8 a = *reinterpret_cast<const bfv8*>(&sA1[(mt*16 + ln)*72 + ks*32 + qd*8]);
                acc = __builtin_amdgcn_mfma_f32_16x16x32_bf16(a, b1f[ks], acc, 0, 0, 0);
            }
            if (col < 24){
                #pragma unroll
                for (int rr = 0; rr < 4; ++rr){
                    int r = mt*16 + qd*4 + rr;
                    if (r < 136){
                        int c = r / 34, y = r - c*34;
                        sA2[(c*12 + kx)*104 + 2*y + s] = f2us(acc[rr]);
                    }
                }
            }
        }
    }
    __syncthreads();
    // ---- F2: 3 M-tiles x 3 N-tiles, K=96; scatter into sC (reuse sA1) ----
    unsigned short* sC = sA1;   // [m][9]: s*4+c at stride 9 (288*9 = 2592 u16)
    for (int tau = wv; tau < 9; tau += 4){
        int mt = tau / 3, nt = tau - (tau/3)*3;
        fv4 acc = (fv4){0.f,0.f,0.f,0.f};
        #pragma unroll
        for (int ks = 0; ks < 3; ++ks){
            bfv8 a  = *reinterpret_cast<const bfv8*>(&sA2[(mt*16 + ln)*104 + ks*32 + qd*8]);
            bfv8 bb = *reinterpret_cast<const bfv8*>(&gB2[(nt*16 + ln)*96 + ks*32 + qd*8]);
            acc = __builtin_amdgcn_mfma_f32_16x16x32_bf16(a, bb, acc, 0, 0, 0);
        }
        int col = nt*16 + ln;
        int ky = col >> 1, s = col & 1;
        #pragma unroll
        for (int rr = 0; rr < 4; ++rr){
            int r = mt*16 + qd*4 + rr;
            int c = r / 12, kxx = r - c*12;
            sC[(ky*12 + kxx)*9 + s*4 + c] = f2us(acc[rr]);
        }
    }
    __syncthreads();
    // ---- fully-coalesced writeback: block owns hft[cg][b][*] = 1152 dwords ----
    unsigned int* dst = hft + ((size_t)(c0 >> 2)*256 + b)*1152;
    for (int d = t; d < 1152; d += 256){
        int m = d >> 2, j = d & 3;
        unsigned int lo = sC[m*9 + 2*j];
        unsigned int hi = sC[m*9 + 2*j + 1];
        dst[d] = lo | (hi << 16);
    }
}

// ---------------- per-mode channel mix as bf16 MFMA GEMM ---------------------
// grid 576 = 288 modes x 2 M-halves of 128; C[128,128] = A[128,128] x B[128,128]
// A kappa order: kappa = cg*8+u (u<4: Re(c=cg*4+u), u>=4: Im), B staged to match.
// XCD line-mate swizzle: m-quads (same q=m>>2, same mh) get block ids differing
// by multiples of 8 -> same XCD L2 -> hft/weight 64B lines fetched once.
__global__ __launch_bounds__(256) void k_mixm(const unsigned short* __restrict__ hft,
                                              const void* __restrict__ sc_w1,
                                              const void* __restrict__ sc_w2,
                                              unsigned int* __restrict__ mixed, int layer,
                                              const float* __restrict__ flg){
    __shared__ unsigned short sB[128*136];   // BT[n][kappa], row stride 136
    const bool f32 = (flg[0] > 0.5f);
    int B = blockIdx.x;
    int x8 = B & 7, w8 = B >> 3;
    int r4 = w8 & 3, g = w8 >> 2;     // g < 18
    int u = g*8 + x8;                 // u < 144
    int mh = u & 1;
    int m  = (u >> 1)*4 + r4;         // m < 288
    int b0 = mh * 128;
    int t = threadIdx.x;
    int kyi = m / 12, kx = m - kyi*12;
    const void* w = (kyi < 12) ? sc_w1 : sc_w2;
    int r = (kyi < 12) ? kyi : kyi - 12;
    size_t wbase = (size_t)layer * 64*64*144*2;
    for (int idx = t; idx < 4096; idx += 256){     // idx = i*64+o
        int i = idx >> 6, o = idx & 63;
        size_t off = wbase + (((size_t)idx*12 + r)*12 + kx)*2;
        float wr = rdf(w, off, f32);
        float wi = rdf(w, off+1, f32);
        int kre = ((i >> 2) << 3) + (i & 3);       // kappa of Re(c=i)
        sB[o*136 + kre]          = f2us(wr);
        sB[(o+64)*136 + kre]     = f2us(wi);
        sB[o*136 + kre + 4]      = f2us(-wi);
        sB[(o+64)*136 + kre + 4] = f2us(wr);
    }
    __syncthreads();
    int ln = t & 15, qd = (t & 63) >> 4, wv = t >> 6;
    // A fragments: A[row][kappa=ks*32+qd*8 ..+7] = hft[g=ks*4+qd][row][m][0..7]
    bfv8 af[2][4];
    int arow = b0 + wv*32 + ln;
    #pragma unroll
    for (int tm = 0; tm < 2; ++tm)
        #pragma unroll
        for (int ks = 0; ks < 4; ++ks){
            int gg = ks*4 + qd;
            af[tm][ks] = *reinterpret_cast<const bfv8*>(
                hft + (((size_t)gg*256 + arow + tm*16)*288 + m)*8);
        }
    fv4 acc[2][8];
    #pragma unroll
    for (int tm=0;tm<2;++tm)
        #pragma unroll
        for (int tn=0;tn<8;++tn) acc[tm][tn] = (fv4){0.f,0.f,0.f,0.f};
    #pragma unroll
    for (int ks = 0; ks < 4; ++ks){
        bfv8 bfr[8];
        #pragma unroll
        for (int tn = 0; tn < 8; ++tn)
            bfr[tn] = *reinterpret_cast<const bfv8*>(&sB[(tn*16 + ln)*136 + ks*32 + qd*8]);
        #pragma unroll
        for (int tm = 0; tm < 2; ++tm)
            #pragma unroll
            for (int tn = 0; tn < 8; ++tn)
                acc[tm][tn] = __builtin_amdgcn_mfma_f32_16x16x32_bf16(af[tm][ks], bfr[tn], acc[tm][tn], 0, 0, 0);
    }
    __syncthreads();
    // C -> LDS (reuse sB): C[row][col], row stride 136; C/D map row=qd*4+r, col=ln
    #pragma unroll
    for (int tm = 0; tm < 2; ++tm)
        #pragma unroll
        for (int tn = 0; tn < 8; ++tn)
            #pragma unroll
            for (int rr = 0; rr < 4; ++rr){
                int row = wv*32 + tm*16 + qd*4 + rr;
                int col = tn*16 + ln;
                sB[row*136 + col] = f2us(acc[tm][tn][rr]);
            }
    __syncthreads();
    // pack (r,i) and write mixed[b][m][o] — 256B contiguous per (b,m), coalesced
    for (int idx = t; idx < 8192; idx += 256){
        int row = idx >> 6, o = idx & 63;
        unsigned int pr = ((unsigned int)sB[row*136 + o]) |
                          (((unsigned int)sB[row*136 + o + 64]) << 16);
        mixed[((size_t)(b0 + row)*288 + m)*64 + o] = pr;
    }
}

// ---------------- pointwise 64x64 channel GEMM (wc path) as MFMA, IN PLACE ---
// grid 1280: b = blk&255, u = blk>>8 (5 px-chunks of 240; chunks of same b
// co-XCD: ids differ by 256). C[240px][64o] = A[240px][64c] x w[o][c]^T + bias.
// Per-chunk in-place: block reads/writes only its own px range (disjoint).
__global__ __launch_bounds__(256) void k_wc(bf16* __restrict__ h,
                                            const void* __restrict__ wc_w,
                                            const void* __restrict__ wc_b,
                                            int layer,
                                            const float* __restrict__ flg){
    __shared__ unsigned short sA[240*72];   // A[p][c], stride 72; reused as sC[64][240]
    __shared__ unsigned short sBT[64*72];   // BT[o][c], stride 72
    __shared__ float sb[64];
    const bool f32 = (flg[0] > 0.5f);
    int blk = blockIdx.x;
    int b = blk & 255, u = blk >> 8;
    int px0 = u*240;
    int npx = 1156 - px0; if (npx > 240) npx = 240;   // 240 or 196
    int ndp = npx >> 1;                                // 120 or 98
    int t = threadIdx.x;
    size_t wbase = (size_t)layer*4096;
    for (int i = t; i < 4096; i += 256){               // wc_w[l][o][c] -> BT[o][c]
        int o = i >> 6, c = i & 63;
        sBT[o*72 + c] = f2us(rdf(wc_w, wbase + i, f32));
    }
    if (t < 64) sb[t] = rdf(wc_b, layer*64 + t, f32);
    // stage A transposed: dword-granular reads of h (always bf16 workspace)
    const unsigned int* srcd = (const unsigned int*)(h + (size_t)b*73984);
    for (int i = t; i < 7680; i += 256){
        int c = i / 120, dp = i - c*120;
        unsigned int v = (dp < ndp) ? srcd[c*578 + (px0 >> 1) + dp] : 0u;
        sA[(2*dp)*72 + c]     = (unsigned short)(v & 0xffff);
        sA[(2*dp + 1)*72 + c] = (unsigned short)(v >> 16);
    }
    __syncthreads();
    int ln = t & 15, qd = (t & 63) >> 4, wv = t >> 6;
    bfv8 bfr[4][2];
    #pragma unroll
    for (int nt = 0; nt < 4; ++nt)
        #pragma unroll
        for (int ks = 0; ks < 2; ++ks)
            bfr[nt][ks] = *reinterpret_cast<const bfv8*>(&sBT[(nt*16 + ln)*72 + ks*32 + qd*8]);
    // 15 m-tiles: wave wv handles mt = wv + 4*mi (mi<4, skip mt>=15)
    bfv8 a_[4][2];
    #pragma unroll
    for (int mi = 0; mi < 4; ++mi){
        int mt = wv + mi*4;
        if (mt < 15){
            a_[mi][0] = *reinterpret_cast<const bfv8*>(&sA[(mt*16 + ln)*72 + qd*8]);
            a_[mi][1] = *reinterpret_cast<const bfv8*>(&sA[(mt*16 + ln)*72 + 32 + qd*8]);
        }
    }
    fv4 acc[4][4];
    #pragma unroll
    for (int mi = 0; mi < 4; ++mi){
        int mt = wv + mi*4;
        if (mt < 15){
            #pragma unroll
            for (int nt = 0; nt < 4; ++nt){
                fv4 a = (fv4){0.f,0.f,0.f,0.f};
                a = __builtin_amdgcn_mfma_f32_16x16x32_bf16(a_[mi][0], bfr[nt][0], a, 0, 0, 0);
                a = __builtin_amdgcn_mfma_f32_16x16x32_bf16(a_[mi][1], bfr[nt][1], a, 0, 0, 0);
                acc[mi][nt] = a;
            }
        }
    }
    __syncthreads();
    // C -> sC[o][240] (transpose back), bias added
    unsigned int* sCd = (unsigned int*)sA;   // [o][120 dw]
    #pragma unroll
    for (int mi = 0; mi < 4; ++mi){
        int mt = wv + mi*4;
        if (mt < 15){
            #pragma unroll
            for (int nt = 0; nt < 4; ++nt){
                int o = nt*16 + ln;
                float bb = sb[o];
                int p0 = mt*16 + qd*4;
                sCd[o*120 + (p0 >> 1)]     = packbf2(acc[mi][nt][0] + bb, acc[mi][nt][1] + bb);
                sCd[o*120 + (p0 >> 1) + 1] = packbf2(acc[mi][nt][2] + bb, acc[mi][nt][3] + bb);
            }
        }
    }
    __syncthreads();
    // coalesced in-place writeback (own px range only)
    unsigned int* dstd = (unsigned int*)(h + (size_t)b*73984);
    for (int i = t; i < 7680; i += 256){
        int o = i / 120, dp = i - o*120;
        if (dp < ndp) dstd[o*578 + (px0 >> 1) + dp] = sCd[o*120 + dp];
    }
}

// ---------------- inverse truncated DFT as MFMA GEMMs; fused add + gelu -----
// grid 4096 = 256 b x 16 o-groups of 4, XCD line-mate swizzled (as before).
// Step B accumulates in REGISTERS (accB[3][3]); raw f32 results scattered to
// the dead sG region in plane-linear layout; epilogue is a single coalesced
// global-read htile -> add -> gelu -> global-write loop (no divergent gelu,
// no LDS htile staging). sG stripe shrunk 48->36 rows (overshoot rows read
// neighbor-stripe data whose MFMA output columns are discarded); x-row pads
// NOT zeroed (garbage flows only to discarded columns).
// LDS 30,144 B -> 5 blocks/CU.
__global__ __launch_bounds__(256, 5) void k_invm(const unsigned int* __restrict__ mixed,
                                              const float* __restrict__ tabs,
                                              bf16* __restrict__ hio, int layer){
    __shared__ unsigned short lds[15072];   // 30,144 B
    unsigned short* sA   = lds;             // 96 x 40 (step A input)
    unsigned short* sG16 = lds + 3840;      // [ch][36 rows x 72] step-A output
    unsigned int* ldsw   = (unsigned int*)lds;
    unsigned int* sGd    = ldsw + 1920;
    float* rawf          = (float*)(ldsw + 1920);  // post-B: [ch][1156] f32
    int B = blockIdx.x;
    int x8 = B & 7, s4 = (B >> 3) & 3, z = B >> 5;
    int b  = (z >> 2)*8 + x8;
    int o0 = ((z & 3)*4 + s4)*4;
    int t = threadIdx.x;
    const unsigned short* gBT16 = (const unsigned short*)(tabs + 2448);  // [n][32 u16]
    const unsigned short* gW216 = (const unsigned short*)(tabs + 3536);  // [y][64 u16]
    // sA from mixed[b][m][o]: 16B per (m), stride 256B (lines shared intra-XCD)
    const unsigned int* msrc = mixed + (size_t)b*18432 + o0;
    for (int i = t; i < 1152; i += 256){
        int m = i >> 2, ch = i & 3;
        int kyi = m / 12, kx = m - kyi*12;
        ((unsigned int*)sA)[(ch*24 + kyi)*20 + kx] = msrc[(size_t)m*64 + ch];
    }
    for (int i = t; i < 384; i += 256)       // zero sA k 24..31 (dw 12..15)
        ((unsigned int*)sA)[(i >> 2)*20 + 12 + (i & 3)] = 0;
    // sG kappa pads (dw 24..31) of valid rows only (K-elements must be zero)
    for (int i = t; i < 1088; i += 256){
        int r = i >> 3;
        int ch = r / 34, x = r - ch*34;
        sGd[(ch*36 + x)*36 + 24 + (i & 7)] = 0;
    }
    __syncthreads();
    int ln = t & 15, qd = (t & 63) >> 4, wv = t >> 6;
    // ---- step A: 30 tiles (6 M x 5 N), K=32; B-frag direct from gBT image ----
    for (int tau = wv; tau < 30; tau += 4){
        int mt = tau / 5, nt = tau - mt*5;
        bfv8 a  = *reinterpret_cast<const bfv8*>(&sA[(mt*16 + ln)*40 + qd*8]);
        bfv8 bb = *reinterpret_cast<const bfv8*>(&gBT16[(nt*16 + ln)*32 + qd*8]);
        fv4 acc = (fv4){0.f,0.f,0.f,0.f};
        acc = __builtin_amdgcn_mfma_f32_16x16x32_bf16(a, bb, acc, 0, 0, 0);
        int col = nt*16 + ln;
        if (col < 68){
            int x = col >> 1, ri = col & 1;
            #pragma unroll
            for (int rr = 0; rr < 4; ++rr){
                int row = mt*16 + qd*4 + rr;
                int ch = row / 24, kyi = row - ch*24;
                sG16[(ch*36 + x)*72 + 2*kyi + ri] = f2us(acc[rr]);
            }
        }
    }
    __syncthreads();
    // ---- step B: wave = ch; 3x3 tiles, K=64; accumulate in registers ----
    int ch = wv;
    fv4 accB[3][3];
    #pragma unroll
    for (int mt = 0; mt < 3; ++mt){
        bfv8 a0 = *reinterpret_cast<const bfv8*>(&gW216[(mt*16 + ln)*64 + qd*8]);
        bfv8 a1 = *reinterpret_cast<const bfv8*>(&gW216[(mt*16 + ln)*64 + 32 + qd*8]);
        #pragma unroll
        for (int nt = 0; nt < 3; ++nt){
            bfv8 b0 = *reinterpret_cast<const bfv8*>(&sG16[(ch*36 + nt*16 + ln)*72 + qd*8]);
            bfv8 b1 = *reinterpret_cast<const bfv8*>(&sG16[(ch*36 + nt*16 + ln)*72 + 32 + qd*8]);
            fv4 acc = (fv4){0.f,0.f,0.f,0.f};
            acc = __builtin_amdgcn_mfma_f32_16x16x32_bf16(a0, b0, acc, 0, 0, 0);
            acc = __builtin_amdgcn_mfma_f32_16x16x32_bf16(a1, b1, acc, 0, 0, 0);
            accB[mt][nt] = acc;
        }
    }
    __syncthreads();   // all sG reads done -> safe to overwrite with rawf
    // ---- scatter raw f32 results plane-linear (bare stores, no gelu) ----
    #pragma unroll
    for (int mt = 0; mt < 3; ++mt)
        #pragma unroll
        for (int nt = 0; nt < 3; ++nt){
            int x = nt*16 + ln;
            if (x < 34){
                #pragma unroll
                for (int rr = 0; rr < 4; ++rr){
                    int y = mt*16 + qd*4 + rr;
                    if (y < 34) rawf[ch*1156 + y*34 + x] = accB[mt][nt][rr];
                }
            }
        }
    __syncthreads();
    // ---- coalesced fused epilogue: h = gelu(h + x1), direct global RMW ----
    const unsigned int* hsrc = (const unsigned int*)(hio + (size_t)b*73984 + (size_t)o0*1156);
    unsigned int* hdst = (unsigned int*)(hio + (size_t)b*73984 + (size_t)o0*1156);
    for (int i = t; i < 2312; i += 256){
        float2 rv = *reinterpret_cast<const float2*>(&rawf[2*i]);
        float2 hv = unpackbf2(hsrc[i]);
        float v0 = rv.x + hv.x, v1 = rv.y + hv.y;
        if (layer < 3){ v0 = gelu_f(v0); v1 = gelu_f(v1); }
        hdst[i] = packbf2(v0, v1);
    }
}

// ---------------- 8x8/stride4 VALID conv -> gelu -> pe2 scale ----------------
__global__ __launch_bounds__(256) void k_pe(const bf16* __restrict__ h,
                                            const void* __restrict__ pw,
                                            const void* __restrict__ pb,
                                            const void* __restrict__ p2w,
                                            const void* __restrict__ p2b,
                                            float* __restrict__ p49,
                                            const float* __restrict__ flg){
    __shared__ float red[256];
    const bool f32 = (flg[0] > 0.5f);
    int bid = blockIdx.x;          // b*49 + py*7 + px
    int b = bid / 49, r = bid - b*49;
    int py = r / 7, px = r - py*7;
    int t = threadIdx.x;
    const bf16* hb = h + (size_t)b*73984 + (py*4)*34 + px*4;
    float partial = 0.f;
    for (int tt = t; tt < 4096; tt += 256){
        int c = tt >> 6, k = tt & 63, ky = k >> 3, kx = k & 7;
        partial += bff(hb[(size_t)c*1156 + ky*34 + kx]) * rdf(pw, tt, f32);
    }
    red[t] = partial;
    __syncthreads();
    for (int s = 128; s > 0; s >>= 1){
        if (t < s) red[t] += red[t + s];
        __syncthreads();
    }
    if (t == 0){
        float v = red[0] + rdf(pb, 0, f32);
        v = gelu_f(v);
        p49[bid] = v * rdf(p2w, 0, f32) + rdf(p2b, 0, f32);
    }
}

// ---------------- sentence MLP 384->32->32->16 (relu,relu,lin) ---------------
// 256 threads: split-K layer 1 (8 groups x 32 outs, coalesced w1 reads, LDS
// reduce) — replaces the 384-iter serial loop that was pure L2-latency-bound.
__global__ __launch_bounds__(256) void k_sent(const void* __restrict__ se,
                                             const void* __restrict__ w1, const void* __restrict__ b1,
                                             const void* __restrict__ w2, const void* __restrict__ b2,
                                             const void* __restrict__ w3, const void* __restrict__ b3,
                                             float* __restrict__ outv,
                                             const float* __restrict__ flg){
    __shared__ float sse[384];
    __shared__ float red[256];
    __shared__ float s1[32], s2[32];
    const bool f32 = (flg[0] > 0.5f);
    int b = blockIdx.x, t = threadIdx.x;
    for (int i = t; i < 384; i += 256) sse[i] = rdf(se, (size_t)b*384 + i, f32);
    __syncthreads();
    {
        int o = t & 31, g = t >> 5;          // 8 k-groups of 48
        float acc = 0.f;
        #pragma unroll 4
        for (int k = g*48; k < g*48 + 48; ++k)
            acc += sse[k] * rdf(w1, (size_t)k*32 + o, f32);
        red[t] = acc;
    }
    __syncthreads();
    if (t < 32){
        float a = rdf(b1, t, f32);
        #pragma unroll
        for (int g = 0; g < 8; ++g) a += red[g*32 + t];
        s1[t] = fmaxf(a, 0.f);
    }
    __syncthreads();
    if (t < 32){
        float acc = rdf(b2, t, f32);
        for (int k = 0; k < 32; ++k) acc += s1[k] * rdf(w2, k*32 + t, f32);
        s2[t] = fmaxf(acc, 0.f);
    }
    __syncthreads();
    if (t < 16){
        float acc = rdf(b3, t, f32);
        for (int k = 0; k < 32; ++k) acc += s2[k] * rdf(w3, k*16 + t, f32);
        outv[b*16 + t] = acc;
    }
}

// ---------------- xp MLP 49->32->32->16 (silu,silu,lin) ----------------------
// 256 threads, split-K layer 1 (8 groups, stride-8 over k<49), LDS reduce.
__global__ __launch_bounds__(256) void k_xp(const float* __restrict__ p49,
                                           const void* __restrict__ w1, const void* __restrict__ b1,
                                           const void* __restrict__ w2, const void* __restrict__ b2,
                                           const void* __restrict__ w3, const void* __restrict__ b3,
                                           float* __restrict__ outv,
                                           const float* __restrict__ flg){
    __shared__ float sp[49];
    __shared__ float red[256];
    __shared__ float s1[32], s2[32];
    const bool f32 = (flg[0] > 0.5f);
    int b = blockIdx.x, t = threadIdx.x;
    if (t < 49) sp[t] = p49[b*49 + t];
    __syncthreads();
    {
        int o = t & 31, g = t >> 5;
        float acc = 0.f;
        for (int k = g; k < 49; k += 8)
            acc += sp[k] * rdf(w1, (size_t)k*32 + o, f32);
        red[t] = acc;
    }
    __syncthreads();
    if (t < 32){
        float a = rdf(b1, t, f32);
        #pragma unroll
        for (int g = 0; g < 8; ++g) a += red[g*32 + t];
        s1[t] = silu_f(a);
    }
    __syncthreads();
    if (t < 32){
        float acc = rdf(b2, t, f32);
        for (int k = 0; k < 32; ++k) acc += s1[k] * rdf(w2, k*32 + t, f32);
        s2[t] = silu_f(acc);
    }
    __syncthreads();
    if (t < 16){
        float acc = rdf(b3, t, f32);
        for (int k = 0; k < 32; ++k) acc += s2[k] * rdf(w3, k*16 + t, f32);
        outv[b*16 + t] = acc;
    }
}

// ---------------- pu MLP part A: 32->128->256 (silu,silu) --------------------
__global__ __launch_bounds__(256) void k_puA(const float* __restrict__ xemb,
                                             const float* __restrict__ semb,
                                             const void* __restrict__ w1, const void* __restrict__ b1,
                                             const void* __restrict__ w2, const void* __restrict__ b2,
                                             float* __restrict__ h2buf,
                                             const float* __restrict__ flg){
    __shared__ float ein[32];
    __shared__ float h1[128];
    const bool f32 = (flg[0] > 0.5f);
    int b = blockIdx.x, t = threadIdx.x;
    if (t < 16) ein[t] = xemb[b*16 + t];
    else if (t < 32) ein[t] = semb[b*16 + (t - 16)];
    __syncthreads();
    if (t < 128){
        float acc = rdf(b1, t, f32);
        for (int k = 0; k < 32; ++k) acc += ein[k] * rdf(w1, k*128 + t, f32);
        h1[t] = silu_f(acc);
    }
    __syncthreads();
    {
        float acc = rdf(b2, t, f32);
        for (int k = 0; k < 128; ++k) acc += h1[k] * rdf(w2, k*256 + t, f32);
        h2buf[(size_t)b*256 + t] = silu_f(acc);
    }
}

// ---------------- pu MLP part B: 256->1156 GEMM ------------------------------
// grid 1280 = 256 b (fast) x 5 n-chunks of 232
__global__ __launch_bounds__(256) void k_puB(const float* __restrict__ h2buf,
                                             const void* __restrict__ w3, const void* __restrict__ b3,
                                             float* __restrict__ emb,
                                             const float* __restrict__ flg){
    __shared__ float sh2[256];
    const bool f32 = (flg[0] > 0.5f);
    int blk = blockIdx.x;
    int b = blk & 255, nc = blk >> 8;
    int t = threadIdx.x;
    sh2[t] = h2buf[(size_t)b*256 + t];
    __syncthreads();
    int e = nc*232 + t;
    if (t < 232 && e < 1156){
        float acc = rdf(b3, e, f32);
        if (f32){
            const float* wp = (const float*)w3 + e;
            #pragma unroll 4
            for (int k = 0; k < 256; ++k) acc += sh2[k] * wp[(size_t)k*1156];
        } else {
            const bf16* wp = (const bf16*)w3 + e;
            #pragma unroll 4
            for (int k = 0; k < 256; ++k) acc += sh2[k] * bff(wp[(size_t)k*1156]);
        }
        emb[(size_t)b*1156 + e] = acc;
    }
}

// ---------------- final: crop, concat emb, fc1(MFMA)+gelu, fc2(MFMA) ---------
// grid 512 = 256 b x 2 halves; 8 iters of 2 rows (64 px).
// fc1: C[64px,128j] = A[px,c<64] x w1 (K=64) + rank-1 emb add; fc2: K=128, N=16(4)
__global__ __launch_bounds__(256, 3) void k_final(const bf16* __restrict__ h,
                                                  const float* __restrict__ emb,
                                                  const void* __restrict__ w1, const void* __restrict__ b1,
                                                  const void* __restrict__ w2, const void* __restrict__ b2,
                                                  void* __restrict__ out,
                                                  const float* __restrict__ flg){
    __shared__ unsigned short sw1t[128*72];   // w1T[j][c], stride 72 (16B-aligned rows)
    __shared__ unsigned short sw2t[16*136];   // w2T[n][j], rows 4..15 zero
    __shared__ float sw1e[128];               // w1[64][j] (emb channel)
    __shared__ float sb1[128];
    __shared__ float sb2[4];
    __shared__ unsigned short spx[64*66];     // input[c][px], stride 66 (odd dwords)
    __shared__ float sembp[64];               // emb[px]
    __shared__ unsigned short sh2[128*66];    // hid[j][px], stride 66
    const bool f32 = (flg[0] > 0.5f);
    int blk = blockIdx.x;
    int b = blk >> 1, half = blk & 1;
    int t = threadIdx.x;
    for (int i = t; i < 8320; i += 256){       // w1 [c=65][j=128]
        int c = i >> 7, j = i & 127;
        float v = rdf(w1, i, f32);
        if (c < 64) sw1t[j*72 + c] = f2us(v);
        else sw1e[j] = v;
    }
    if (t < 128) sb1[t] = rdf(b1, t, f32);
    for (int i = t; i < 2176; i += 256){       // w2 [j=128][k=4] -> w2T[n][j]
        int n = i / 136, j = i - n*136;
        float v = (n < 4 && j < 128) ? rdf(w2, j*4 + n, f32) : 0.f;
        sw2t[i] = f2us(v);
    }
    if (t < 4) sb2[t] = rdf(b2, t, f32);
    __syncthreads();
    int ln = t & 15, qd = (t & 63) >> 4, wv = t >> 6;
    // hoist B fragments (weights) into registers
    bfv8 bw1[8][2];
    #pragma unroll
    for (int tn = 0; tn < 8; ++tn)
        #pragma unroll
        for (int ks = 0; ks < 2; ++ks)
            bw1[tn][ks] = *reinterpret_cast<const bfv8*>(&sw1t[(tn*16 + ln)*72 + ks*32 + qd*8]);
    bfv8 bw2[4];
    #pragma unroll
    for (int ks = 0; ks < 4; ++ks)
        bw2[ks] = *reinterpret_cast<const bfv8*>(&sw2t[ln*136 + ks*32 + qd*8]);
    const bf16* hb = h + (size_t)b*73984;
    const float* eb = emb + (size_t)b*1156;
    for (int it = 0; it < 8; ++it){
        int y0 = half*16 + it*2;               // 2 rows = 64 px
        __syncthreads();
        for (int e = t; e < 2048; e += 256){   // stage spx[c][px] c-major
            int c = e >> 5, d = e & 31;
            int px = d*2;
            int y = y0 + (px >> 5), x = px & 31;
            float v0 = bff(hb[(size_t)c*1156 + y*34 + x]);
            int px1 = px + 1;
            int y1 = y0 + (px1 >> 5), x1 = px1 & 31;
            float v1 = bff(hb[(size_t)c*1156 + y1*34 + x1]);
            ((unsigned int*)spx)[c*33 + d] = packbf2(v0, v1);
        }
        if (t < 64){
            int y = y0 + (t >> 5), x = t & 31;
            sembp[t] = eb[y*34 + x];
        }
        __syncthreads();
        // fc1 MFMA: wave wv owns mtile wv (px = wv*16 + ...)
        fv4 acc[8];
        #pragma unroll
        for (int tn = 0; tn < 8; ++tn) acc[tn] = (fv4){0.f,0.f,0.f,0.f};
        #pragma unroll
        for (int ks = 0; ks < 2; ++ks){
            union { bfv8 v; unsigned short s[8]; } af;
            #pragma unroll
            for (int j = 0; j < 8; ++j)
                af.s[j] = spx[(ks*32 + qd*8 + j)*66 + wv*16 + ln];
            #pragma unroll
            for (int tn = 0; tn < 8; ++tn)
                acc[tn] = __builtin_amdgcn_mfma_f32_16x16x32_bf16(af.v, bw1[tn][ks], acc[tn], 0, 0, 0);
        }
        float ev[4];
        #pragma unroll
        for (int rr = 0; rr < 4; ++rr) ev[rr] = sembp[wv*16 + qd*4 + rr];
        #pragma unroll
        for (int tn = 0; tn < 8; ++tn){
            int col = tn*16 + ln;
            float we = sw1e[col];
            float bb1 = sb1[col];
            #pragma unroll
            for (int rr = 0; rr < 4; ++rr){
                float v = acc[tn][rr] + ev[rr]*we + bb1;
                sh2[col*66 + wv*16 + qd*4 + rr] = f2us(gelu_f(v));
            }
        }
        __syncthreads();
        // fc2 MFMA: K=128, N=16 (4 valid)
        fv4 a2 = (fv4){0.f,0.f,0.f,0.f};
        #pragma unroll
        for (int ks = 0; ks < 4; ++ks){
            union { bfv8 v; unsigned short s[8]; } af;
            #pragma unroll
            for (int j = 0; j < 8; ++j)
                af.s[j] = sh2[(ks*32 + qd*8 + j)*66 + wv*16 + ln];
            a2 = __builtin_amdgcn_mfma_f32_16x16x32_bf16(af.v, bw2[ks], a2, 0, 0, 0);
        }
        if (ln < 4){
            float bb2 = sb2[ln];
            #pragma unroll
            for (int rr = 0; rr < 4; ++rr){
                int pxl = wv*16 + qd*4 + rr;
                int y = y0 + (pxl >> 5), x = pxl & 31;
                size_t o = ((size_t)(b*32 + y)*32 + x)*4 + ln;
                float v = a2[rr] + bb2;
                if (f32) ((float*)out)[o] = v;
                else     ((bf16*)out)[o] = __float2bfloat16(v);
            }
        }
    }
}

extern "C" void kernel_launch(void* const* d_in, const int* in_sizes, int n_in,
                              void* d_out, int out_size, void* d_ws, size_t ws_size,
                              hipStream_t stream) {
    (void)in_sizes; (void)n_in; (void)out_size; (void)ws_size;
    const void* x     = d_in[0];
    const void* grd   = d_in[1];
    const void* se    = d_in[2];
    const void* fc0_w = d_in[3];
    const void* fc0_b = d_in[4];
    const void* sc_w1 = d_in[5];
    const void* sc_w2 = d_in[6];
    const void* wc_w  = d_in[7];
    const void* wc_b  = d_in[8];
    const void* pe1_w = d_in[9];
    const void* pe1_b = d_in[10];
    const void* pe2_w = d_in[11];
    const void* pe2_b = d_in[12];
    const void* sp_w1 = d_in[13];
    const void* sp_b1 = d_in[14];
    const void* sp_w2 = d_in[15];
    const void* sp_b2 = d_in[16];
    const void* sp_w3 = d_in[17];
    const void* sp_b3 = d_in[18];
    const void* xp_w1 = d_in[19];
    const void* xp_b1 = d_in[20];
    const void* xp_w2 = d_in[21];
    const void* xp_b2 = d_in[22];
    const void* xp_w3 = d_in[23];
    const void* xp_b3 = d_in[24];
    const void* pu_w1 = d_in[25];
    const void* pu_b1 = d_in[26];
    const void* pu_w2 = d_in[27];
    const void* pu_b2 = d_in[28];
    const void* pu_w3 = d_in[29];
    const void* pu_b3 = d_in[30];
    const void* fc1_w = d_in[31];
    const void* fc1_b = d_in[32];
    const void* fc2_w = d_in[33];
    const void* fc2_b = d_in[34];

    // workspace layout (float-unit offsets); total ~77 MB
    float* ws    = (float*)d_ws;
    bf16*  hA    = (bf16*)ws;                              // 18,939,904 bf16
    unsigned int* hft   = (unsigned int*)(ws + 9469952);   // 4,718,592 dwords (hft cg-panels)
    unsigned int* mixed = (unsigned int*)(ws + 14188544);  // 4,718,592 dwords ([b][m][o])
    float* tabs  = ws + 18907136;                          // 4,896 (DFT tables + inv images)
    float* p49   = ws + 18912032;                          // 12,544
    float* semb  = ws + 18924576;                          // 4,096
    float* xemb  = ws + 18928672;                          // 4,096
    float* emb   = ws + 18932768;                          // 295,936
    float* flag  = ws + 19228704;                          // 1
    float* h2buf = (float*)hft;                            // reuse: hft dead after layer loop
    // fwd B-images + fc0 weight image live in emb region (dead during layer
    // loop; k_puB writes emb only after the last k_invm; rebuilt each replay)
    float* fwdimg = emb;                                   // 5,696 floats

    k_probe<<<1, 256, 0, stream>>>(x, flag);
    k_tables<<<1, 256, 0, stream>>>(tabs, fwdimg, fc0_w, fc0_b, flag);
    k_fc0<<<2048, 256, 0, stream>>>(x, grd, (const unsigned short*)(fwdimg + 3328), hA, flag);

    for (int l = 0; l < 4; ++l){
        k_fwd<<<4096, 256, 0, stream>>>(hA, hft, (const unsigned short*)fwdimg);
        k_mixm<<<576, 256, 0, stream>>>((const unsigned short*)hft, sc_w1, sc_w2, mixed, l, flag);
        k_wc <<<1280, 256, 0, stream>>>(hA, wc_w, wc_b, l, flag);
        k_invm<<<4096, 256, 0, stream>>>(mixed, tabs, hA, l);
    }

    k_pe  <<<256*49, 256, 0, stream>>>(hA, pe1_w, pe1_b, pe2_w, pe2_b, p49, flag);
    k_sent<<<256, 256, 0, stream>>>(se, sp_w1, sp_b1, sp_w2, sp_b2, sp_w3, sp_b3, semb, flag);
    k_xp  <<<256, 256, 0, stream>>>(p49, xp_w1, xp_b1, xp_w2, xp_b2, xp_w3, xp_b3, xemb, flag);
    k_puA <<<256, 256, 0, stream>>>(xemb, semb, pu_w1, pu_b1, pu_w2, pu_b2, h2buf, flag);
    k_puB <<<1280, 256, 0, stream>>>(h2buf, pu_w3, pu_b3, emb, flag);
    k_final<<<512, 256, 0, stream>>>(hA, emb, fc1_w, fc1_b, fc2_w, fc2_b, d_out, flag);
}